// Round 1
// baseline (2639.864 us; speedup 1.0000x reference)
//
#include <hip/hip_runtime.h>
#include <math.h>

// ---------------- CSR build ----------------
__global__ void count_kernel(const int* __restrict__ ei, int E, int N, int* __restrict__ counts) {
  int e = blockIdx.x * 256 + threadIdx.x;
  if (e >= E + N) return;
  int d = (e < E) ? ei[E + e] : (e - E);   // row1 = dst
  atomicAdd(&counts[d], 1);
}

__global__ void scan_kernel(const int* __restrict__ counts, int* __restrict__ offsets,
                            int* __restrict__ cursor, int n) {
  __shared__ int wsum[16];
  int tid = threadIdx.x;                 // blockDim = 1024
  int lane = tid & 63, wid = tid >> 6;
  int carry = 0;
  for (int base = 0; base < n; base += 1024) {
    int i = base + tid;
    int v = (i < n) ? counts[i] : 0;
    int x = v;
    #pragma unroll
    for (int off = 1; off < 64; off <<= 1) {
      int t = __shfl_up(x, off);
      if (lane >= off) x += t;
    }
    if (lane == 63) wsum[wid] = x;
    __syncthreads();
    if (wid == 0) {
      int w = (lane < 16) ? wsum[lane] : 0;
      #pragma unroll
      for (int off = 1; off < 16; off <<= 1) {
        int t = __shfl_up(w, off);
        if (lane >= off) w += t;
      }
      if (lane < 16) wsum[lane] = w;
    }
    __syncthreads();
    int wpre = (wid > 0) ? wsum[wid - 1] : 0;
    int total = wsum[15];
    if (i < n) {
      int excl = carry + wpre + x - v;
      offsets[i] = excl;
      cursor[i] = excl;
    }
    __syncthreads();                      // protect wsum before next chunk
    carry += total;
  }
  if (tid == 0) offsets[n] = carry;
}

__global__ void scatter_kernel(const int* __restrict__ ei, int E, int N,
                               int* __restrict__ cursor, int* __restrict__ eidx) {
  int e = blockIdx.x * 256 + threadIdx.x;
  if (e >= E + N) return;
  int d = (e < E) ? ei[E + e] : (e - E);
  int pos = atomicAdd(&cursor[d], 1);
  eidx[pos] = e;
}

// ---------------- fp32 tiled GEMM: out[M,Nc] = A[M,K] @ W[K,Nc] ----------------
// K multiple of 32, Nc multiple of 64. Row guard on M only.
__global__ __launch_bounds__(256) void gemm_kernel(const float* __restrict__ A,
                                                   const float* __restrict__ W,
                                                   float* __restrict__ out,
                                                   int M, int K, int Nc) {
  __shared__ float As[32][68];  // transposed A tile: As[k][m], pad 68 keeps float4-aligned + conflict-free
  __shared__ float Ws[32][68];
  int bm = blockIdx.x * 64;
  int bn = blockIdx.y * 64;
  int tid = threadIdx.x;
  int tx = tid & 15, ty = tid >> 4;
  float acc[4][4] = {};
  for (int k0 = 0; k0 < K; k0 += 32) {
    #pragma unroll
    for (int i = 0; i < 8; ++i) {
      int li = tid + i * 256;
      int r = li >> 5, kk = li & 31;
      int gr = bm + r;
      As[kk][r] = (gr < M) ? A[(size_t)gr * K + k0 + kk] : 0.f;
    }
    #pragma unroll
    for (int i = 0; i < 8; ++i) {
      int li = tid + i * 256;
      int kk = li >> 6, c = li & 63;
      Ws[kk][c] = W[(size_t)(k0 + kk) * Nc + bn + c];
    }
    __syncthreads();
    #pragma unroll
    for (int kk = 0; kk < 32; ++kk) {
      float4 av = *(const float4*)&As[kk][ty * 4];
      float4 wv = *(const float4*)&Ws[kk][tx * 4];
      float a[4] = {av.x, av.y, av.z, av.w};
      float w[4] = {wv.x, wv.y, wv.z, wv.w};
      #pragma unroll
      for (int i = 0; i < 4; ++i)
        #pragma unroll
        for (int j = 0; j < 4; ++j) acc[i][j] += a[i] * w[j];
    }
    __syncthreads();
  }
  #pragma unroll
  for (int i = 0; i < 4; ++i) {
    int gr = bm + ty * 4 + i;
    if (gr < M) {
      float4 o = make_float4(acc[i][0], acc[i][1], acc[i][2], acc[i][3]);
      *(float4*)&out[(size_t)gr * Nc + bn + tx * 4] = o;
    }
  }
}

// ---------------- per-node alpha_src/alpha_dst ----------------
template <int H>
__global__ void alpha_kernel(const float* __restrict__ h, const float* __restrict__ a_s,
                             const float* __restrict__ a_d, float* __restrict__ asrc,
                             float* __restrict__ adst, int n) {
  int wid = threadIdx.x >> 6, lane = threadIdx.x & 63;
  int node = blockIdx.x * 4 + wid;
  if (node >= n) return;
  const float* row = h + (size_t)node * (H * 64);
  #pragma unroll
  for (int hh = 0; hh < H; ++hh) {
    float v = row[hh * 64 + lane];
    float vs = v * a_s[hh * 64 + lane];
    float vd = v * a_d[hh * 64 + lane];
    #pragma unroll
    for (int off = 32; off; off >>= 1) {
      vs += __shfl_down(vs, off);
      vd += __shfl_down(vd, off);
    }
    if (lane == 0) {
      asrc[node * H + hh] = vs;
      adst[node * H + hh] = vd;
    }
  }
}

// ---------------- segment softmax + weighted aggregation (CSR gather) ----------------
template <int H, int NPB>   // blockDim = H*64*NPB = 256
__global__ void agg_kernel(const float* __restrict__ h, const float* __restrict__ asrc,
                           const float* __restrict__ adst, const int* __restrict__ offsets,
                           const int* __restrict__ eidx, const int* __restrict__ srcarr,
                           int E, const float* __restrict__ bias, float* __restrict__ out,
                           int n) {
  int sub = threadIdx.x / (H * 64);
  int t = threadIdx.x % (H * 64);
  int head = t >> 6;
  int c = t & 63;
  int node = blockIdx.x * NPB + sub;
  if (node >= n) return;
  int start = offsets[node], end = offsets[node + 1];
  float adst_h = adst[node * H + head];
  float m = -1e30f;
  for (int i = start; i < end; ++i) {
    int e = eidx[i];
    int s = (e < E) ? srcarr[e] : (e - E);
    float sc = asrc[s * H + head] + adst_h;
    sc = (sc >= 0.f) ? sc : 0.2f * sc;
    m = fmaxf(m, sc);
  }
  float sum = 0.f, acc = 0.f;
  for (int i = start; i < end; ++i) {
    int e = eidx[i];
    int s = (e < E) ? srcarr[e] : (e - E);
    float sc = asrc[s * H + head] + adst_h;
    sc = (sc >= 0.f) ? sc : 0.2f * sc;
    float p = expf(sc - m);
    sum += p;
    acc += p * h[(size_t)s * (H * 64) + head * 64 + c];
  }
  out[(size_t)node * (H * 64) + t] = acc / sum + bias[t];
}

// ---------------- LayerNorm + ELU (in place) ----------------
template <int D>
__global__ void ln_elu_kernel(float* __restrict__ x, const float* __restrict__ g,
                              const float* __restrict__ b, int n) {
  int wid = threadIdx.x >> 6, lane = threadIdx.x & 63;
  int node = blockIdx.x * 4 + wid;
  if (node >= n) return;
  float* row = x + (size_t)node * D;
  constexpr int PER = D / 64;
  float v[PER];
  float s = 0.f;
  #pragma unroll
  for (int i = 0; i < PER; ++i) {
    v[i] = row[i * 64 + lane];
    s += v[i];
  }
  #pragma unroll
  for (int off = 32; off; off >>= 1) s += __shfl_xor(s, off);
  float mu = s / D;
  float var = 0.f;
  #pragma unroll
  for (int i = 0; i < PER; ++i) {
    float d = v[i] - mu;
    var += d * d;
  }
  #pragma unroll
  for (int off = 32; off; off >>= 1) var += __shfl_xor(var, off);
  var /= D;
  float r = rsqrtf(var + 1e-5f);
  #pragma unroll
  for (int i = 0; i < PER; ++i) {
    float y = (v[i] - mu) * r * g[i * 64 + lane] + b[i * 64 + lane];
    y = (y > 0.f) ? y : expm1f(y);
    row[i * 64 + lane] = y;
  }
}

// ---------------- global mean pool ----------------
__global__ void pool_kernel(const float* __restrict__ h, const int* __restrict__ batch,
                            float* __restrict__ sums, float* __restrict__ cnt, int n) {
  int wid = threadIdx.x >> 6, lane = threadIdx.x & 63;
  int node = blockIdx.x * 4 + wid;
  if (node >= n) return;
  int g = batch[node];
  atomicAdd(&sums[g * 64 + lane], h[(size_t)node * 64 + lane]);
  if (lane == 0) atomicAdd(&cnt[g], 1.0f);
}

// ---------------- MLP head ----------------
__global__ void head1_kernel(const float* __restrict__ sums, const float* __restrict__ cnt,
                             const float* __restrict__ Wg, const float* __restrict__ bg,
                             float* __restrict__ z1) {
  __shared__ float gm[64];
  int g = blockIdx.x;
  float c = fmaxf(cnt[g], 1.0f);
  if (threadIdx.x < 64) gm[threadIdx.x] = sums[g * 64 + threadIdx.x] / c;
  __syncthreads();
  int j = threadIdx.x;  // 128 threads
  float acc = bg[j];
  for (int k = 0; k < 64; ++k) acc += gm[k] * Wg[k * 128 + j];
  z1[g * 128 + j] = fmaxf(acc, 0.f);
}

__global__ void head2_kernel(const float* __restrict__ z1, const float* __restrict__ Wg2,
                             const float* __restrict__ bg2, float* __restrict__ z2) {
  __shared__ float zz[128];
  int g = blockIdx.x;
  int t = threadIdx.x;  // 64 threads
  zz[t] = z1[g * 128 + t];
  zz[t + 64] = z1[g * 128 + 64 + t];
  __syncthreads();
  float acc = bg2[t];
  for (int k = 0; k < 128; ++k) acc += zz[k] * Wg2[k * 64 + t];
  z2[g * 64 + t] = fmaxf(acc, 0.f);
}

__global__ void head3_kernel(const float* __restrict__ z2, const float* __restrict__ Wo,
                             const float* __restrict__ bo, float* __restrict__ out) {
  int t = threadIdx.x;  // 320 threads: g = t/5, j = t%5
  if (t >= 320) return;
  int g = t / 5, j = t % 5;
  float acc = bo[j];
  const float* row = z2 + g * 64;
  for (int k = 0; k < 64; ++k) acc += row[k] * Wo[k * 5 + j];
  out[g * 5 + j] = acc;
}

// ---------------- launch ----------------
extern "C" void kernel_launch(void* const* d_in, const int* in_sizes, int n_in,
                              void* d_out, int out_size, void* d_ws, size_t ws_size,
                              hipStream_t stream) {
  const float* x   = (const float*)d_in[0];
  const int* ei    = (const int*)d_in[1];
  const int* batch = (const int*)d_in[2];
  const float* W1  = (const float*)d_in[3];
  const float* a1s = (const float*)d_in[4];
  const float* a1d = (const float*)d_in[5];
  const float* b1  = (const float*)d_in[6];
  const float* g1  = (const float*)d_in[7];
  const float* be1 = (const float*)d_in[8];
  const float* W2  = (const float*)d_in[9];
  const float* a2s = (const float*)d_in[10];
  const float* a2d = (const float*)d_in[11];
  const float* b2  = (const float*)d_in[12];
  const float* g2  = (const float*)d_in[13];
  const float* be2 = (const float*)d_in[14];
  const float* W3  = (const float*)d_in[15];
  const float* a3s = (const float*)d_in[16];
  const float* a3d = (const float*)d_in[17];
  const float* b3  = (const float*)d_in[18];
  const float* g3  = (const float*)d_in[19];
  const float* be3 = (const float*)d_in[20];
  const float* Wg  = (const float*)d_in[21];
  const float* bg  = (const float*)d_in[22];
  const float* Wg2 = (const float*)d_in[23];
  const float* bg2 = (const float*)d_in[24];
  const float* Wo  = (const float*)d_in[25];
  const float* bo  = (const float*)d_in[26];

  const int N = in_sizes[2];
  const int E = in_sizes[1] / 2;
  const int ET = E + N;  // with self-loops
  const int G = 64;

  // workspace carve-up (256B aligned)
  char* ws = (char*)d_ws;
  size_t off = 0;
  auto carve = [&](size_t bytes) {
    void* p = ws + off;
    off = (off + bytes + 255) & ~(size_t)255;
    return p;
  };
  int* counts   = (int*)carve((size_t)N * 4);
  int* offsets  = (int*)carve((size_t)(N + 1) * 4);
  int* cursor   = (int*)carve((size_t)N * 4);
  int* eidx     = (int*)carve((size_t)ET * 4);
  float* asrc   = (float*)carve((size_t)N * 4 * 4);
  float* adst   = (float*)carve((size_t)N * 4 * 4);
  float* bufA   = (float*)carve((size_t)N * 256 * 4);
  float* bufB   = (float*)carve((size_t)N * 256 * 4);
  float* buf3   = (float*)carve((size_t)N * 64 * 4);
  float* sums   = (float*)carve((size_t)G * 64 * 4);
  float* cnt    = (float*)carve((size_t)G * 4);
  float* z1     = (float*)carve((size_t)G * 128 * 4);
  float* z2     = (float*)carve((size_t)G * 64 * 4);
  (void)ws_size;

  const int egrid = (ET + 255) / 256;
  const int ngrid4 = (N + 3) / 4;
  const dim3 gemm_grid_256((N + 63) / 64, 4);
  const dim3 gemm_grid_64((N + 63) / 64, 1);

  // --- CSR (dst-sorted edge list), rebuilt every call ---
  hipMemsetAsync(counts, 0, (size_t)N * 4, stream);
  count_kernel<<<egrid, 256, 0, stream>>>(ei, E, N, counts);
  scan_kernel<<<1, 1024, 0, stream>>>(counts, offsets, cursor, N);
  scatter_kernel<<<egrid, 256, 0, stream>>>(ei, E, N, cursor, eidx);

  // --- layer 1 ---
  gemm_kernel<<<gemm_grid_256, 256, 0, stream>>>(x, W1, bufA, N, 128, 256);
  alpha_kernel<4><<<ngrid4, 256, 0, stream>>>(bufA, a1s, a1d, asrc, adst, N);
  agg_kernel<4, 1><<<N, 256, 0, stream>>>(bufA, asrc, adst, offsets, eidx, ei, E, b1, bufB, N);
  ln_elu_kernel<256><<<ngrid4, 256, 0, stream>>>(bufB, g1, be1, N);

  // --- layer 2 ---
  gemm_kernel<<<gemm_grid_256, 256, 0, stream>>>(bufB, W2, bufA, N, 256, 256);
  alpha_kernel<4><<<ngrid4, 256, 0, stream>>>(bufA, a2s, a2d, asrc, adst, N);
  agg_kernel<4, 1><<<N, 256, 0, stream>>>(bufA, asrc, adst, offsets, eidx, ei, E, b2, bufB, N);
  ln_elu_kernel<256><<<ngrid4, 256, 0, stream>>>(bufB, g2, be2, N);

  // --- layer 3 (H=1, C=64) ---
  gemm_kernel<<<gemm_grid_64, 256, 0, stream>>>(bufB, W3, bufA, N, 256, 64);
  alpha_kernel<1><<<ngrid4, 256, 0, stream>>>(bufA, a3s, a3d, asrc, adst, N);
  agg_kernel<1, 4><<<ngrid4, 256, 0, stream>>>(bufA, asrc, adst, offsets, eidx, ei, E, b3, buf3, N);
  ln_elu_kernel<64><<<ngrid4, 256, 0, stream>>>(buf3, g3, be3, N);

  // --- pool + head ---
  hipMemsetAsync(sums, 0, (size_t)G * 64 * 4, stream);
  hipMemsetAsync(cnt, 0, (size_t)G * 4, stream);
  pool_kernel<<<ngrid4, 256, 0, stream>>>(buf3, batch, sums, cnt, N);
  head1_kernel<<<G, 128, 0, stream>>>(sums, cnt, Wg, bg, z1);
  head2_kernel<<<G, 64, 0, stream>>>(z1, Wg2, bg2, z2);
  head3_kernel<<<1, 320, 0, stream>>>(z2, Wo, bo, (float*)d_out);
}

// Round 2
// 1166.088 us; speedup vs baseline: 2.2639x; 2.2639x over previous
//
#include <hip/hip_runtime.h>
#include <math.h>

// ---------------- CSR build ----------------
__global__ void count_kernel(const int* __restrict__ ei, int E, int N, int* __restrict__ counts) {
  int e = blockIdx.x * 256 + threadIdx.x;
  if (e >= E + N) return;
  int d = (e < E) ? ei[E + e] : (e - E);   // row1 = dst
  atomicAdd(&counts[d], 1);
}

__global__ void scan_kernel(const int* __restrict__ counts, int* __restrict__ offsets,
                            int* __restrict__ cursor, int n) {
  __shared__ int wsum[16];
  int tid = threadIdx.x;                 // blockDim = 1024
  int lane = tid & 63, wid = tid >> 6;
  int carry = 0;
  for (int base = 0; base < n; base += 1024) {
    int i = base + tid;
    int v = (i < n) ? counts[i] : 0;
    int x = v;
    #pragma unroll
    for (int off = 1; off < 64; off <<= 1) {
      int t = __shfl_up(x, off);
      if (lane >= off) x += t;
    }
    if (lane == 63) wsum[wid] = x;
    __syncthreads();
    if (wid == 0) {
      int w = (lane < 16) ? wsum[lane] : 0;
      #pragma unroll
      for (int off = 1; off < 16; off <<= 1) {
        int t = __shfl_up(w, off);
        if (lane >= off) w += t;
      }
      if (lane < 16) wsum[lane] = w;
    }
    __syncthreads();
    int wpre = (wid > 0) ? wsum[wid - 1] : 0;
    int total = wsum[15];
    if (i < n) {
      int excl = carry + wpre + x - v;
      offsets[i] = excl;
      cursor[i] = excl;
    }
    __syncthreads();                      // protect wsum before next chunk
    carry += total;
  }
  if (tid == 0) offsets[n] = carry;
}

__global__ void scatter_kernel(const int* __restrict__ ei, int E, int N,
                               int* __restrict__ cursor, int* __restrict__ src_csr,
                               int* __restrict__ dst_csr) {
  int e = blockIdx.x * 256 + threadIdx.x;
  if (e >= E + N) return;
  int s = (e < E) ? ei[e] : (e - E);
  int d = (e < E) ? ei[E + e] : (e - E);
  int pos = atomicAdd(&cursor[d], 1);
  src_csr[pos] = s;
  dst_csr[pos] = d;
}

// ---------------- fp32 tiled GEMM: out[M,Nc] = A[M,K] @ W[K,Nc] ----------------
__global__ __launch_bounds__(256) void gemm_kernel(const float* __restrict__ A,
                                                   const float* __restrict__ W,
                                                   float* __restrict__ out,
                                                   int M, int K, int Nc) {
  __shared__ float As[32][68];
  __shared__ float Ws[32][68];
  int bm = blockIdx.x * 64;
  int bn = blockIdx.y * 64;
  int tid = threadIdx.x;
  int tx = tid & 15, ty = tid >> 4;
  float acc[4][4] = {};
  for (int k0 = 0; k0 < K; k0 += 32) {
    #pragma unroll
    for (int i = 0; i < 8; ++i) {
      int li = tid + i * 256;
      int r = li >> 5, kk = li & 31;
      int gr = bm + r;
      As[kk][r] = (gr < M) ? A[(size_t)gr * K + k0 + kk] : 0.f;
    }
    #pragma unroll
    for (int i = 0; i < 8; ++i) {
      int li = tid + i * 256;
      int kk = li >> 6, c = li & 63;
      Ws[kk][c] = W[(size_t)(k0 + kk) * Nc + bn + c];
    }
    __syncthreads();
    #pragma unroll
    for (int kk = 0; kk < 32; ++kk) {
      float4 av = *(const float4*)&As[kk][ty * 4];
      float4 wv = *(const float4*)&Ws[kk][tx * 4];
      float a[4] = {av.x, av.y, av.z, av.w};
      float w[4] = {wv.x, wv.y, wv.z, wv.w};
      #pragma unroll
      for (int i = 0; i < 4; ++i)
        #pragma unroll
        for (int j = 0; j < 4; ++j) acc[i][j] += a[i] * w[j];
    }
    __syncthreads();
  }
  #pragma unroll
  for (int i = 0; i < 4; ++i) {
    int gr = bm + ty * 4 + i;
    if (gr < M) {
      float4 o = make_float4(acc[i][0], acc[i][1], acc[i][2], acc[i][3]);
      *(float4*)&out[(size_t)gr * Nc + bn + tx * 4] = o;
    }
  }
}

// ---------------- per-node alpha_src/alpha_dst ----------------
template <int H>
__global__ void alpha_kernel(const float* __restrict__ h, const float* __restrict__ a_s,
                             const float* __restrict__ a_d, float* __restrict__ asrc,
                             float* __restrict__ adst, int n) {
  int wid = threadIdx.x >> 6, lane = threadIdx.x & 63;
  int node = blockIdx.x * 4 + wid;
  if (node >= n) return;
  const float* row = h + (size_t)node * (H * 64);
  #pragma unroll
  for (int hh = 0; hh < H; ++hh) {
    float v = row[hh * 64 + lane];
    float vs = v * a_s[hh * 64 + lane];
    float vd = v * a_d[hh * 64 + lane];
    #pragma unroll
    for (int off = 32; off; off >>= 1) {
      vs += __shfl_down(vs, off);
      vd += __shfl_down(vd, off);
    }
    if (lane == 0) {
      asrc[node * H + hh] = vs;
      adst[node * H + hh] = vd;
    }
  }
}

// ---------------- per-edge exp(leaky(score)) in CSR order ----------------
// No segment-max subtraction: scores are O(1), exp is safe, normalization is
// mathematically identical (alpha = ex/sum(ex)).
template <int H>
__global__ void edge_score_kernel(const float* __restrict__ asrc, const float* __restrict__ adst,
                                  const int* __restrict__ src_csr, const int* __restrict__ dst_csr,
                                  int ET, float* __restrict__ pexp) {
  int i = blockIdx.x * 256 + threadIdx.x;
  if (i >= ET) return;
  int s = src_csr[i], d = dst_csr[i];
  if (H == 4) {
    float4 as = ((const float4*)asrc)[s];
    float4 ad = ((const float4*)adst)[d];
    float4 e;
    float sc;
    sc = as.x + ad.x; sc = (sc >= 0.f) ? sc : 0.2f * sc; e.x = __expf(sc);
    sc = as.y + ad.y; sc = (sc >= 0.f) ? sc : 0.2f * sc; e.y = __expf(sc);
    sc = as.z + ad.z; sc = (sc >= 0.f) ? sc : 0.2f * sc; e.z = __expf(sc);
    sc = as.w + ad.w; sc = (sc >= 0.f) ? sc : 0.2f * sc; e.w = __expf(sc);
    ((float4*)pexp)[i] = e;
  } else {
    float sc = asrc[s] + adst[d];
    sc = (sc >= 0.f) ? sc : 0.2f * sc;
    pexp[i] = __expf(sc);
  }
}

// ---------------- aggregation, H=4: one wave per node, lane-float4 over 256 ch ----------------
__global__ __launch_bounds__(256) void agg4_kernel(const float* __restrict__ h,
                                                   const float* __restrict__ pexp,
                                                   const int* __restrict__ offsets,
                                                   const int* __restrict__ src_csr,
                                                   const float* __restrict__ bias,
                                                   float* __restrict__ out, int n) {
  int wid = threadIdx.x >> 6, lane = threadIdx.x & 63;
  int node = blockIdx.x * 4 + wid;
  if (node >= n) return;
  int start = offsets[node], end = offsets[node + 1];
  int head = lane >> 4;                    // lane's 4 channels all in this head
  const float4* h4 = (const float4*)h;
  float4 acc = make_float4(0.f, 0.f, 0.f, 0.f);
  float denom = 0.f;
  int i = start;
  for (; i + 4 <= end; i += 4) {
    int s0 = src_csr[i], s1 = src_csr[i + 1], s2 = src_csr[i + 2], s3 = src_csr[i + 3];
    float w0 = pexp[i * 4 + head];
    float w1 = pexp[(i + 1) * 4 + head];
    float w2 = pexp[(i + 2) * 4 + head];
    float w3 = pexp[(i + 3) * 4 + head];
    float4 v0 = h4[(size_t)s0 * 64 + lane];
    float4 v1 = h4[(size_t)s1 * 64 + lane];
    float4 v2 = h4[(size_t)s2 * 64 + lane];
    float4 v3 = h4[(size_t)s3 * 64 + lane];
    denom += (w0 + w1) + (w2 + w3);
    acc.x += w0 * v0.x + w1 * v1.x + w2 * v2.x + w3 * v3.x;
    acc.y += w0 * v0.y + w1 * v1.y + w2 * v2.y + w3 * v3.y;
    acc.z += w0 * v0.z + w1 * v1.z + w2 * v2.z + w3 * v3.z;
    acc.w += w0 * v0.w + w1 * v1.w + w2 * v2.w + w3 * v3.w;
  }
  for (; i < end; ++i) {
    int s = src_csr[i];
    float w = pexp[i * 4 + head];
    float4 v = h4[(size_t)s * 64 + lane];
    denom += w;
    acc.x += w * v.x; acc.y += w * v.y; acc.z += w * v.z; acc.w += w * v.w;
  }
  float inv = 1.f / denom;
  float4 b4 = ((const float4*)bias)[lane];
  float4 o;
  o.x = acc.x * inv + b4.x;
  o.y = acc.y * inv + b4.y;
  o.z = acc.z * inv + b4.z;
  o.w = acc.w * inv + b4.w;
  ((float4*)out)[(size_t)node * 64 + lane] = o;
}

// ---------------- aggregation, H=1 C=64: one wave per node, lane = channel ----------------
__global__ __launch_bounds__(256) void agg1_kernel(const float* __restrict__ h,
                                                   const float* __restrict__ pexp,
                                                   const int* __restrict__ offsets,
                                                   const int* __restrict__ src_csr,
                                                   const float* __restrict__ bias,
                                                   float* __restrict__ out, int n) {
  int wid = threadIdx.x >> 6, lane = threadIdx.x & 63;
  int node = blockIdx.x * 4 + wid;
  if (node >= n) return;
  int start = offsets[node], end = offsets[node + 1];
  float acc = 0.f, denom = 0.f;
  int i = start;
  for (; i + 4 <= end; i += 4) {
    int s0 = src_csr[i], s1 = src_csr[i + 1], s2 = src_csr[i + 2], s3 = src_csr[i + 3];
    float w0 = pexp[i], w1 = pexp[i + 1], w2 = pexp[i + 2], w3 = pexp[i + 3];
    float v0 = h[(size_t)s0 * 64 + lane];
    float v1 = h[(size_t)s1 * 64 + lane];
    float v2 = h[(size_t)s2 * 64 + lane];
    float v3 = h[(size_t)s3 * 64 + lane];
    denom += (w0 + w1) + (w2 + w3);
    acc += w0 * v0 + w1 * v1 + w2 * v2 + w3 * v3;
  }
  for (; i < end; ++i) {
    int s = src_csr[i];
    float w = pexp[i];
    denom += w;
    acc += w * h[(size_t)s * 64 + lane];
  }
  out[(size_t)node * 64 + lane] = acc / denom + bias[lane];
}

// ---------------- LayerNorm + ELU (in place) ----------------
template <int D>
__global__ void ln_elu_kernel(float* __restrict__ x, const float* __restrict__ g,
                              const float* __restrict__ b, int n) {
  int wid = threadIdx.x >> 6, lane = threadIdx.x & 63;
  int node = blockIdx.x * 4 + wid;
  if (node >= n) return;
  float* row = x + (size_t)node * D;
  constexpr int PER = D / 64;
  float v[PER];
  float s = 0.f;
  #pragma unroll
  for (int i = 0; i < PER; ++i) {
    v[i] = row[i * 64 + lane];
    s += v[i];
  }
  #pragma unroll
  for (int off = 32; off; off >>= 1) s += __shfl_xor(s, off);
  float mu = s / D;
  float var = 0.f;
  #pragma unroll
  for (int i = 0; i < PER; ++i) {
    float d = v[i] - mu;
    var += d * d;
  }
  #pragma unroll
  for (int off = 32; off; off >>= 1) var += __shfl_xor(var, off);
  var /= D;
  float r = rsqrtf(var + 1e-5f);
  #pragma unroll
  for (int i = 0; i < PER; ++i) {
    float y = (v[i] - mu) * r * g[i * 64 + lane] + b[i * 64 + lane];
    y = (y > 0.f) ? y : expm1f(y);
    row[i * 64 + lane] = y;
  }
}

// ---------------- global mean pool ----------------
__global__ void pool_kernel(const float* __restrict__ h, const int* __restrict__ batch,
                            float* __restrict__ sums, float* __restrict__ cnt, int n) {
  int wid = threadIdx.x >> 6, lane = threadIdx.x & 63;
  int node = blockIdx.x * 4 + wid;
  if (node >= n) return;
  int g = batch[node];
  atomicAdd(&sums[g * 64 + lane], h[(size_t)node * 64 + lane]);
  if (lane == 0) atomicAdd(&cnt[g], 1.0f);
}

// ---------------- MLP head ----------------
__global__ void head1_kernel(const float* __restrict__ sums, const float* __restrict__ cnt,
                             const float* __restrict__ Wg, const float* __restrict__ bg,
                             float* __restrict__ z1) {
  __shared__ float gm[64];
  int g = blockIdx.x;
  float c = fmaxf(cnt[g], 1.0f);
  if (threadIdx.x < 64) gm[threadIdx.x] = sums[g * 64 + threadIdx.x] / c;
  __syncthreads();
  int j = threadIdx.x;  // 128 threads
  float acc = bg[j];
  for (int k = 0; k < 64; ++k) acc += gm[k] * Wg[k * 128 + j];
  z1[g * 128 + j] = fmaxf(acc, 0.f);
}

__global__ void head2_kernel(const float* __restrict__ z1, const float* __restrict__ Wg2,
                             const float* __restrict__ bg2, float* __restrict__ z2) {
  __shared__ float zz[128];
  int g = blockIdx.x;
  int t = threadIdx.x;  // 64 threads
  zz[t] = z1[g * 128 + t];
  zz[t + 64] = z1[g * 128 + 64 + t];
  __syncthreads();
  float acc = bg2[t];
  for (int k = 0; k < 128; ++k) acc += zz[k] * Wg2[k * 64 + t];
  z2[g * 64 + t] = fmaxf(acc, 0.f);
}

__global__ void head3_kernel(const float* __restrict__ z2, const float* __restrict__ Wo,
                             const float* __restrict__ bo, float* __restrict__ out) {
  int t = threadIdx.x;  // 320 threads: g = t/5, j = t%5
  if (t >= 320) return;
  int g = t / 5, j = t % 5;
  float acc = bo[j];
  const float* row = z2 + g * 64;
  for (int k = 0; k < 64; ++k) acc += row[k] * Wo[k * 5 + j];
  out[g * 5 + j] = acc;
}

// ---------------- launch ----------------
extern "C" void kernel_launch(void* const* d_in, const int* in_sizes, int n_in,
                              void* d_out, int out_size, void* d_ws, size_t ws_size,
                              hipStream_t stream) {
  const float* x   = (const float*)d_in[0];
  const int* ei    = (const int*)d_in[1];
  const int* batch = (const int*)d_in[2];
  const float* W1  = (const float*)d_in[3];
  const float* a1s = (const float*)d_in[4];
  const float* a1d = (const float*)d_in[5];
  const float* b1  = (const float*)d_in[6];
  const float* g1  = (const float*)d_in[7];
  const float* be1 = (const float*)d_in[8];
  const float* W2  = (const float*)d_in[9];
  const float* a2s = (const float*)d_in[10];
  const float* a2d = (const float*)d_in[11];
  const float* b2  = (const float*)d_in[12];
  const float* g2  = (const float*)d_in[13];
  const float* be2 = (const float*)d_in[14];
  const float* W3  = (const float*)d_in[15];
  const float* a3s = (const float*)d_in[16];
  const float* a3d = (const float*)d_in[17];
  const float* b3  = (const float*)d_in[18];
  const float* g3  = (const float*)d_in[19];
  const float* be3 = (const float*)d_in[20];
  const float* Wg  = (const float*)d_in[21];
  const float* bg  = (const float*)d_in[22];
  const float* Wg2 = (const float*)d_in[23];
  const float* bg2 = (const float*)d_in[24];
  const float* Wo  = (const float*)d_in[25];
  const float* bo  = (const float*)d_in[26];

  const int N = in_sizes[2];
  const int E = in_sizes[1] / 2;
  const int ET = E + N;  // with self-loops
  const int G = 64;

  // workspace carve-up (256B aligned)
  char* ws = (char*)d_ws;
  size_t off = 0;
  auto carve = [&](size_t bytes) {
    void* p = ws + off;
    off = (off + bytes + 255) & ~(size_t)255;
    return p;
  };
  int* counts   = (int*)carve((size_t)N * 4);
  int* offsets  = (int*)carve((size_t)(N + 1) * 4);
  int* cursor   = (int*)carve((size_t)N * 4);
  int* src_csr  = (int*)carve((size_t)ET * 4);
  int* dst_csr  = (int*)carve((size_t)ET * 4);
  float* pexp   = (float*)carve((size_t)ET * 4 * 4);
  float* asrc   = (float*)carve((size_t)N * 4 * 4);
  float* adst   = (float*)carve((size_t)N * 4 * 4);
  float* bufA   = (float*)carve((size_t)N * 256 * 4);
  float* bufB   = (float*)carve((size_t)N * 256 * 4);
  float* buf3   = (float*)carve((size_t)N * 64 * 4);
  float* sums   = (float*)carve((size_t)G * 64 * 4);
  float* cnt    = (float*)carve((size_t)G * 4);
  float* z1     = (float*)carve((size_t)G * 128 * 4);
  float* z2     = (float*)carve((size_t)G * 64 * 4);
  (void)ws_size;

  const int egrid = (ET + 255) / 256;
  const int ngrid4 = (N + 3) / 4;
  const dim3 gemm_grid_256((N + 63) / 64, 4);
  const dim3 gemm_grid_64((N + 63) / 64, 1);

  // --- CSR (dst-sorted src/dst lists), rebuilt every call ---
  hipMemsetAsync(counts, 0, (size_t)N * 4, stream);
  count_kernel<<<egrid, 256, 0, stream>>>(ei, E, N, counts);
  scan_kernel<<<1, 1024, 0, stream>>>(counts, offsets, cursor, N);
  scatter_kernel<<<egrid, 256, 0, stream>>>(ei, E, N, cursor, src_csr, dst_csr);

  // --- layer 1 ---
  gemm_kernel<<<gemm_grid_256, 256, 0, stream>>>(x, W1, bufA, N, 128, 256);
  alpha_kernel<4><<<ngrid4, 256, 0, stream>>>(bufA, a1s, a1d, asrc, adst, N);
  edge_score_kernel<4><<<egrid, 256, 0, stream>>>(asrc, adst, src_csr, dst_csr, ET, pexp);
  agg4_kernel<<<ngrid4, 256, 0, stream>>>(bufA, pexp, offsets, src_csr, b1, bufB, N);
  ln_elu_kernel<256><<<ngrid4, 256, 0, stream>>>(bufB, g1, be1, N);

  // --- layer 2 ---
  gemm_kernel<<<gemm_grid_256, 256, 0, stream>>>(bufB, W2, bufA, N, 256, 256);
  alpha_kernel<4><<<ngrid4, 256, 0, stream>>>(bufA, a2s, a2d, asrc, adst, N);
  edge_score_kernel<4><<<egrid, 256, 0, stream>>>(asrc, adst, src_csr, dst_csr, ET, pexp);
  agg4_kernel<<<ngrid4, 256, 0, stream>>>(bufA, pexp, offsets, src_csr, b2, bufB, N);
  ln_elu_kernel<256><<<ngrid4, 256, 0, stream>>>(bufB, g2, be2, N);

  // --- layer 3 (H=1, C=64) ---
  gemm_kernel<<<gemm_grid_64, 256, 0, stream>>>(bufB, W3, bufA, N, 256, 64);
  alpha_kernel<1><<<ngrid4, 256, 0, stream>>>(bufA, a3s, a3d, asrc, adst, N);
  edge_score_kernel<1><<<egrid, 256, 0, stream>>>(asrc, adst, src_csr, dst_csr, ET, pexp);
  agg1_kernel<<<ngrid4, 256, 0, stream>>>(bufA, pexp, offsets, src_csr, b3, buf3, N);
  ln_elu_kernel<64><<<ngrid4, 256, 0, stream>>>(buf3, g3, be3, N);

  // --- pool + head ---
  hipMemsetAsync(sums, 0, (size_t)G * 64 * 4, stream);
  hipMemsetAsync(cnt, 0, (size_t)G * 4, stream);
  pool_kernel<<<ngrid4, 256, 0, stream>>>(buf3, batch, sums, cnt, N);
  head1_kernel<<<G, 128, 0, stream>>>(sums, cnt, Wg, bg, z1);
  head2_kernel<<<G, 64, 0, stream>>>(z1, Wg2, bg2, z2);
  head3_kernel<<<1, 320, 0, stream>>>(z2, Wo, bo, (float*)d_out);
}

// Round 3
// 876.648 us; speedup vs baseline: 3.0113x; 1.3302x over previous
//
#include <hip/hip_runtime.h>
#include <math.h>

// ---------------- CSR build ----------------
__global__ void count_kernel(const int* __restrict__ ei, int E, int N, int* __restrict__ counts) {
  int e = blockIdx.x * 256 + threadIdx.x;
  if (e >= E + N) return;
  int d = (e < E) ? ei[E + e] : (e - E);   // row1 = dst
  atomicAdd(&counts[d], 1);
}

__global__ void scan_kernel(const int* __restrict__ counts, int* __restrict__ offsets,
                            int* __restrict__ cursor, int n) {
  __shared__ int wsum[16];
  int tid = threadIdx.x;                 // blockDim = 1024
  int lane = tid & 63, wid = tid >> 6;
  int carry = 0;
  for (int base = 0; base < n; base += 1024) {
    int i = base + tid;
    int v = (i < n) ? counts[i] : 0;
    int x = v;
    #pragma unroll
    for (int off = 1; off < 64; off <<= 1) {
      int t = __shfl_up(x, off);
      if (lane >= off) x += t;
    }
    if (lane == 63) wsum[wid] = x;
    __syncthreads();
    if (wid == 0) {
      int w = (lane < 16) ? wsum[lane] : 0;
      #pragma unroll
      for (int off = 1; off < 16; off <<= 1) {
        int t = __shfl_up(w, off);
        if (lane >= off) w += t;
      }
      if (lane < 16) wsum[lane] = w;
    }
    __syncthreads();
    int wpre = (wid > 0) ? wsum[wid - 1] : 0;
    int total = wsum[15];
    if (i < n) {
      int excl = carry + wpre + x - v;
      offsets[i] = excl;
      cursor[i] = excl;
    }
    __syncthreads();                      // protect wsum before next chunk
    carry += total;
  }
  if (tid == 0) offsets[n] = carry;
}

__global__ void scatter_kernel(const int* __restrict__ ei, int E, int N,
                               int* __restrict__ cursor, int* __restrict__ src_csr,
                               int* __restrict__ dst_csr) {
  int e = blockIdx.x * 256 + threadIdx.x;
  if (e >= E + N) return;
  int s = (e < E) ? ei[e] : (e - E);
  int d = (e < E) ? ei[E + e] : (e - E);
  int pos = atomicAdd(&cursor[d], 1);
  src_csr[pos] = s;
  dst_csr[pos] = d;
}

// ---------------- fp32 tiled GEMM: out[M,Nc] = A[M,K] @ W[K,Nc] ----------------
// BM=128, BK=16, per-thread 8x8 (split 4+4 chunks to keep LDS reads 2-way max).
// K multiple of 16, Nc multiple of BN.
template <int BN>
__global__ __launch_bounds__(256) void gemm_big_kernel(const float* __restrict__ A,
                                                       const float* __restrict__ W,
                                                       float* __restrict__ out,
                                                       int M, int K, int Nc) {
  constexpr int BM = 128, BK = 16;
  constexpr int NCH = BN / 64;               // col chunks per thread (1 or 2)
  __shared__ float As[BK][132];              // [k][row], pad 132 (=4*33, keeps 16B align)
  __shared__ float Ws[BK][BN + 4];           // [k][col]
  int bm = blockIdx.x * BM;
  int bn = blockIdx.y * BN;
  int tid = threadIdx.x;
  int tx = tid & 15, ty = tid >> 4;          // ty in 0..15
  float acc[8][NCH * 4] = {};

  for (int k0 = 0; k0 < K; k0 += BK) {
    // stage A tile (transposed): 128x16 = 512 float4s, 2 per thread
    #pragma unroll
    for (int i = 0; i < 2; ++i) {
      int li = tid + i * 256;
      int r = li >> 2, c4 = li & 3;
      int gr = bm + r;
      float4 v = make_float4(0.f, 0.f, 0.f, 0.f);
      if (gr < M) v = *(const float4*)&A[(size_t)gr * K + k0 + c4 * 4];
      As[c4 * 4 + 0][r] = v.x;
      As[c4 * 4 + 1][r] = v.y;
      As[c4 * 4 + 2][r] = v.z;
      As[c4 * 4 + 3][r] = v.w;
    }
    // stage W tile: BK*BN elems, coalesced
    #pragma unroll
    for (int i = 0; i < BK * BN / 256; ++i) {
      int li = tid + i * 256;
      int kk = li / BN, c = li % BN;
      Ws[kk][c] = W[(size_t)(k0 + kk) * Nc + bn + c];
    }
    __syncthreads();
    #pragma unroll
    for (int kk = 0; kk < BK; ++kk) {
      float a[8], w[NCH * 4];
      float4 t0 = *(const float4*)&As[kk][ty * 4];
      float4 t1 = *(const float4*)&As[kk][64 + ty * 4];
      a[0] = t0.x; a[1] = t0.y; a[2] = t0.z; a[3] = t0.w;
      a[4] = t1.x; a[5] = t1.y; a[6] = t1.z; a[7] = t1.w;
      float4 u0 = *(const float4*)&Ws[kk][tx * 4];
      w[0] = u0.x; w[1] = u0.y; w[2] = u0.z; w[3] = u0.w;
      if (NCH == 2) {
        float4 u1 = *(const float4*)&Ws[kk][64 + tx * 4];
        w[4] = u1.x; w[5] = u1.y; w[6] = u1.z; w[7] = u1.w;
      }
      #pragma unroll
      for (int i = 0; i < 8; ++i)
        #pragma unroll
        for (int j = 0; j < NCH * 4; ++j) acc[i][j] += a[i] * w[j];
    }
    __syncthreads();
  }
  #pragma unroll
  for (int rc = 0; rc < 2; ++rc)
    #pragma unroll
    for (int i = 0; i < 4; ++i) {
      int gr = bm + rc * 64 + ty * 4 + i;
      if (gr < M) {
        #pragma unroll
        for (int cc = 0; cc < NCH; ++cc) {
          float4 o = make_float4(acc[rc * 4 + i][cc * 4 + 0], acc[rc * 4 + i][cc * 4 + 1],
                                 acc[rc * 4 + i][cc * 4 + 2], acc[rc * 4 + i][cc * 4 + 3]);
          *(float4*)&out[(size_t)gr * Nc + bn + cc * 64 + tx * 4] = o;
        }
      }
    }
}

// ---------------- per-node alpha_src/alpha_dst ----------------
template <int H>
__global__ void alpha_kernel(const float* __restrict__ h, const float* __restrict__ a_s,
                             const float* __restrict__ a_d, float* __restrict__ asrc,
                             float* __restrict__ adst, int n) {
  int wid = threadIdx.x >> 6, lane = threadIdx.x & 63;
  int node = blockIdx.x * 4 + wid;
  if (node >= n) return;
  const float* row = h + (size_t)node * (H * 64);
  #pragma unroll
  for (int hh = 0; hh < H; ++hh) {
    float v = row[hh * 64 + lane];
    float vs = v * a_s[hh * 64 + lane];
    float vd = v * a_d[hh * 64 + lane];
    #pragma unroll
    for (int off = 32; off; off >>= 1) {
      vs += __shfl_down(vs, off);
      vd += __shfl_down(vd, off);
    }
    if (lane == 0) {
      asrc[node * H + hh] = vs;
      adst[node * H + hh] = vd;
    }
  }
}

// ---------------- per-edge exp(leaky(score)) in CSR order ----------------
template <int H>
__global__ void edge_score_kernel(const float* __restrict__ asrc, const float* __restrict__ adst,
                                  const int* __restrict__ src_csr, const int* __restrict__ dst_csr,
                                  int ET, float* __restrict__ pexp) {
  int i = blockIdx.x * 256 + threadIdx.x;
  if (i >= ET) return;
  int s = src_csr[i], d = dst_csr[i];
  if (H == 4) {
    float4 as = ((const float4*)asrc)[s];
    float4 ad = ((const float4*)adst)[d];
    float4 e;
    float sc;
    sc = as.x + ad.x; sc = (sc >= 0.f) ? sc : 0.2f * sc; e.x = __expf(sc);
    sc = as.y + ad.y; sc = (sc >= 0.f) ? sc : 0.2f * sc; e.y = __expf(sc);
    sc = as.z + ad.z; sc = (sc >= 0.f) ? sc : 0.2f * sc; e.z = __expf(sc);
    sc = as.w + ad.w; sc = (sc >= 0.f) ? sc : 0.2f * sc; e.w = __expf(sc);
    ((float4*)pexp)[i] = e;
  } else {
    float sc = asrc[s] + adst[d];
    sc = (sc >= 0.f) ? sc : 0.2f * sc;
    pexp[i] = __expf(sc);
  }
}

// ---------------- aggregation, H=4: one wave per node, lane-float4 over 256 ch ----------------
__global__ __launch_bounds__(256) void agg4_kernel(const float* __restrict__ h,
                                                   const float* __restrict__ pexp,
                                                   const int* __restrict__ offsets,
                                                   const int* __restrict__ src_csr,
                                                   const float* __restrict__ bias,
                                                   float* __restrict__ out, int n) {
  int wid = threadIdx.x >> 6, lane = threadIdx.x & 63;
  int node = blockIdx.x * 4 + wid;
  if (node >= n) return;
  int start = offsets[node], end = offsets[node + 1];
  int head = lane >> 4;                    // lane's 4 channels all in this head
  const float4* h4 = (const float4*)h;
  float4 acc = make_float4(0.f, 0.f, 0.f, 0.f);
  float denom = 0.f;
  int i = start;
  for (; i + 4 <= end; i += 4) {
    int s0 = src_csr[i], s1 = src_csr[i + 1], s2 = src_csr[i + 2], s3 = src_csr[i + 3];
    float w0 = pexp[i * 4 + head];
    float w1 = pexp[(i + 1) * 4 + head];
    float w2 = pexp[(i + 2) * 4 + head];
    float w3 = pexp[(i + 3) * 4 + head];
    float4 v0 = h4[(size_t)s0 * 64 + lane];
    float4 v1 = h4[(size_t)s1 * 64 + lane];
    float4 v2 = h4[(size_t)s2 * 64 + lane];
    float4 v3 = h4[(size_t)s3 * 64 + lane];
    denom += (w0 + w1) + (w2 + w3);
    acc.x += w0 * v0.x + w1 * v1.x + w2 * v2.x + w3 * v3.x;
    acc.y += w0 * v0.y + w1 * v1.y + w2 * v2.y + w3 * v3.y;
    acc.z += w0 * v0.z + w1 * v1.z + w2 * v2.z + w3 * v3.z;
    acc.w += w0 * v0.w + w1 * v1.w + w2 * v2.w + w3 * v3.w;
  }
  for (; i < end; ++i) {
    int s = src_csr[i];
    float w = pexp[i * 4 + head];
    float4 v = h4[(size_t)s * 64 + lane];
    denom += w;
    acc.x += w * v.x; acc.y += w * v.y; acc.z += w * v.z; acc.w += w * v.w;
  }
  float inv = 1.f / denom;
  float4 b4 = ((const float4*)bias)[lane];
  float4 o;
  o.x = acc.x * inv + b4.x;
  o.y = acc.y * inv + b4.y;
  o.z = acc.z * inv + b4.z;
  o.w = acc.w * inv + b4.w;
  ((float4*)out)[(size_t)node * 64 + lane] = o;
}

// ---------------- aggregation, H=1 C=64 ----------------
__global__ __launch_bounds__(256) void agg1_kernel(const float* __restrict__ h,
                                                   const float* __restrict__ pexp,
                                                   const int* __restrict__ offsets,
                                                   const int* __restrict__ src_csr,
                                                   const float* __restrict__ bias,
                                                   float* __restrict__ out, int n) {
  int wid = threadIdx.x >> 6, lane = threadIdx.x & 63;
  int node = blockIdx.x * 4 + wid;
  if (node >= n) return;
  int start = offsets[node], end = offsets[node + 1];
  float acc = 0.f, denom = 0.f;
  int i = start;
  for (; i + 4 <= end; i += 4) {
    int s0 = src_csr[i], s1 = src_csr[i + 1], s2 = src_csr[i + 2], s3 = src_csr[i + 3];
    float w0 = pexp[i], w1 = pexp[i + 1], w2 = pexp[i + 2], w3 = pexp[i + 3];
    float v0 = h[(size_t)s0 * 64 + lane];
    float v1 = h[(size_t)s1 * 64 + lane];
    float v2 = h[(size_t)s2 * 64 + lane];
    float v3 = h[(size_t)s3 * 64 + lane];
    denom += (w0 + w1) + (w2 + w3);
    acc += w0 * v0 + w1 * v1 + w2 * v2 + w3 * v3;
  }
  for (; i < end; ++i) {
    int s = src_csr[i];
    float w = pexp[i];
    denom += w;
    acc += w * h[(size_t)s * 64 + lane];
  }
  out[(size_t)node * 64 + lane] = acc / denom + bias[lane];
}

// ---------------- LayerNorm + ELU (in place) ----------------
template <int D>
__global__ void ln_elu_kernel(float* __restrict__ x, const float* __restrict__ g,
                              const float* __restrict__ b, int n) {
  int wid = threadIdx.x >> 6, lane = threadIdx.x & 63;
  int node = blockIdx.x * 4 + wid;
  if (node >= n) return;
  float* row = x + (size_t)node * D;
  constexpr int PER = D / 64;
  float v[PER];
  float s = 0.f;
  #pragma unroll
  for (int i = 0; i < PER; ++i) {
    v[i] = row[i * 64 + lane];
    s += v[i];
  }
  #pragma unroll
  for (int off = 32; off; off >>= 1) s += __shfl_xor(s, off);
  float mu = s / D;
  float var = 0.f;
  #pragma unroll
  for (int i = 0; i < PER; ++i) {
    float d = v[i] - mu;
    var += d * d;
  }
  #pragma unroll
  for (int off = 32; off; off >>= 1) var += __shfl_xor(var, off);
  var /= D;
  float r = rsqrtf(var + 1e-5f);
  #pragma unroll
  for (int i = 0; i < PER; ++i) {
    float y = (v[i] - mu) * r * g[i * 64 + lane] + b[i * 64 + lane];
    y = (y > 0.f) ? y : expm1f(y);
    row[i * 64 + lane] = y;
  }
}

// ---------------- fused pool + MLP head (batch is sorted) ----------------
__global__ __launch_bounds__(256) void graph_head_kernel(const float* __restrict__ h,
                                                         const int* __restrict__ batch, int N,
                                                         const float* __restrict__ Wg,
                                                         const float* __restrict__ bg,
                                                         const float* __restrict__ Wg2,
                                                         const float* __restrict__ bg2,
                                                         const float* __restrict__ Wo,
                                                         const float* __restrict__ bo,
                                                         float* __restrict__ out) {
  __shared__ int bounds[2];
  __shared__ float part[4][64];
  __shared__ float gm[64];
  __shared__ float z1[128];
  __shared__ float z2[64];
  int g = blockIdx.x;
  int tid = threadIdx.x;
  if (tid < 2) {
    int target = g + tid;  // lower_bound(batch, target)
    int lo = 0, hi = N;
    while (lo < hi) {
      int mid = (lo + hi) >> 1;
      if (batch[mid] < target) lo = mid + 1; else hi = mid;
    }
    bounds[tid] = lo;
  }
  __syncthreads();
  int lo = bounds[0], hi = bounds[1];
  int c = tid & 63, sub = tid >> 6;
  float acc = 0.f;
  for (int r = lo + sub; r < hi; r += 4) acc += h[(size_t)r * 64 + c];
  part[sub][c] = acc;
  __syncthreads();
  float invc = 1.f / fmaxf((float)(hi - lo), 1.f);
  if (tid < 64) gm[tid] = (part[0][tid] + part[1][tid] + part[2][tid] + part[3][tid]) * invc;
  __syncthreads();
  if (tid < 128) {
    float a = bg[tid];
    for (int k = 0; k < 64; ++k) a += gm[k] * Wg[k * 128 + tid];
    z1[tid] = fmaxf(a, 0.f);
  }
  __syncthreads();
  if (tid < 64) {
    float a = bg2[tid];
    for (int k = 0; k < 128; ++k) a += z1[k] * Wg2[k * 64 + tid];
    z2[tid] = fmaxf(a, 0.f);
  }
  __syncthreads();
  if (tid < 5) {
    float a = bo[tid];
    for (int k = 0; k < 64; ++k) a += z2[k] * Wo[k * 5 + tid];
    out[g * 5 + tid] = a;
  }
}

// ---------------- launch ----------------
extern "C" void kernel_launch(void* const* d_in, const int* in_sizes, int n_in,
                              void* d_out, int out_size, void* d_ws, size_t ws_size,
                              hipStream_t stream) {
  const float* x   = (const float*)d_in[0];
  const int* ei    = (const int*)d_in[1];
  const int* batch = (const int*)d_in[2];
  const float* W1  = (const float*)d_in[3];
  const float* a1s = (const float*)d_in[4];
  const float* a1d = (const float*)d_in[5];
  const float* b1  = (const float*)d_in[6];
  const float* g1  = (const float*)d_in[7];
  const float* be1 = (const float*)d_in[8];
  const float* W2  = (const float*)d_in[9];
  const float* a2s = (const float*)d_in[10];
  const float* a2d = (const float*)d_in[11];
  const float* b2  = (const float*)d_in[12];
  const float* g2  = (const float*)d_in[13];
  const float* be2 = (const float*)d_in[14];
  const float* W3  = (const float*)d_in[15];
  const float* a3s = (const float*)d_in[16];
  const float* a3d = (const float*)d_in[17];
  const float* b3  = (const float*)d_in[18];
  const float* g3  = (const float*)d_in[19];
  const float* be3 = (const float*)d_in[20];
  const float* Wg  = (const float*)d_in[21];
  const float* bg  = (const float*)d_in[22];
  const float* Wg2 = (const float*)d_in[23];
  const float* bg2 = (const float*)d_in[24];
  const float* Wo  = (const float*)d_in[25];
  const float* bo  = (const float*)d_in[26];

  const int N = in_sizes[2];
  const int E = in_sizes[1] / 2;
  const int ET = E + N;  // with self-loops
  const int G = 64;

  // workspace carve-up (256B aligned)
  char* ws = (char*)d_ws;
  size_t off = 0;
  auto carve = [&](size_t bytes) {
    void* p = ws + off;
    off = (off + bytes + 255) & ~(size_t)255;
    return p;
  };
  int* counts   = (int*)carve((size_t)N * 4);
  int* offsets  = (int*)carve((size_t)(N + 1) * 4);
  int* cursor   = (int*)carve((size_t)N * 4);
  int* src_csr  = (int*)carve((size_t)ET * 4);
  int* dst_csr  = (int*)carve((size_t)ET * 4);
  float* pexp   = (float*)carve((size_t)ET * 4 * 4);
  float* asrc   = (float*)carve((size_t)N * 4 * 4);
  float* adst   = (float*)carve((size_t)N * 4 * 4);
  float* bufA   = (float*)carve((size_t)N * 256 * 4);
  float* bufB   = (float*)carve((size_t)N * 256 * 4);
  float* buf3   = (float*)carve((size_t)N * 64 * 4);
  (void)ws_size;

  const int egrid = (ET + 255) / 256;
  const int ngrid4 = (N + 3) / 4;
  const int mblocks = (N + 127) / 128;

  // --- CSR (dst-sorted src/dst lists), rebuilt every call ---
  hipMemsetAsync(counts, 0, (size_t)N * 4, stream);
  count_kernel<<<egrid, 256, 0, stream>>>(ei, E, N, counts);
  scan_kernel<<<1, 1024, 0, stream>>>(counts, offsets, cursor, N);
  scatter_kernel<<<egrid, 256, 0, stream>>>(ei, E, N, cursor, src_csr, dst_csr);

  // --- layer 1 ---
  gemm_big_kernel<128><<<dim3(mblocks, 2), 256, 0, stream>>>(x, W1, bufA, N, 128, 256);
  alpha_kernel<4><<<ngrid4, 256, 0, stream>>>(bufA, a1s, a1d, asrc, adst, N);
  edge_score_kernel<4><<<egrid, 256, 0, stream>>>(asrc, adst, src_csr, dst_csr, ET, pexp);
  agg4_kernel<<<ngrid4, 256, 0, stream>>>(bufA, pexp, offsets, src_csr, b1, bufB, N);
  ln_elu_kernel<256><<<ngrid4, 256, 0, stream>>>(bufB, g1, be1, N);

  // --- layer 2 ---
  gemm_big_kernel<128><<<dim3(mblocks, 2), 256, 0, stream>>>(bufB, W2, bufA, N, 256, 256);
  alpha_kernel<4><<<ngrid4, 256, 0, stream>>>(bufA, a2s, a2d, asrc, adst, N);
  edge_score_kernel<4><<<egrid, 256, 0, stream>>>(asrc, adst, src_csr, dst_csr, ET, pexp);
  agg4_kernel<<<ngrid4, 256, 0, stream>>>(bufA, pexp, offsets, src_csr, b2, bufB, N);
  ln_elu_kernel<256><<<ngrid4, 256, 0, stream>>>(bufB, g2, be2, N);

  // --- layer 3 (H=1, C=64) ---
  gemm_big_kernel<64><<<dim3(mblocks, 1), 256, 0, stream>>>(bufB, W3, bufA, N, 256, 64);
  alpha_kernel<1><<<ngrid4, 256, 0, stream>>>(bufA, a3s, a3d, asrc, adst, N);
  edge_score_kernel<1><<<egrid, 256, 0, stream>>>(asrc, adst, src_csr, dst_csr, ET, pexp);
  agg1_kernel<<<ngrid4, 256, 0, stream>>>(bufA, pexp, offsets, src_csr, b3, buf3, N);
  ln_elu_kernel<64><<<ngrid4, 256, 0, stream>>>(buf3, g3, be3, N);

  // --- fused pool + MLP head ---
  graph_head_kernel<<<G, 256, 0, stream>>>(buf3, batch, N, Wg, bg, Wg2, bg2, Wo, bo,
                                           (float*)d_out);
}

// Round 4
// 686.322 us; speedup vs baseline: 3.8464x; 1.2773x over previous
//
#include <hip/hip_runtime.h>
#include <math.h>

typedef _Float16 half2v __attribute__((ext_vector_type(2)));
typedef _Float16 half4v __attribute__((ext_vector_type(4)));
typedef _Float16 half8v __attribute__((ext_vector_type(8)));
typedef float floatx4 __attribute__((ext_vector_type(4)));

// ---------------- CSR build ----------------
__global__ void count_kernel(const int* __restrict__ ei, int E, int N, int* __restrict__ counts) {
  int e = blockIdx.x * 256 + threadIdx.x;
  if (e >= E + N) return;
  int d = (e < E) ? ei[E + e] : (e - E);   // row1 = dst
  atomicAdd(&counts[d], 1);
}

__global__ void scan_kernel(const int* __restrict__ counts, int* __restrict__ offsets,
                            int* __restrict__ cursor, int n) {
  __shared__ int wsum[16];
  int tid = threadIdx.x;                 // blockDim = 1024
  int lane = tid & 63, wid = tid >> 6;
  int carry = 0;
  for (int base = 0; base < n; base += 1024) {
    int i = base + tid;
    int v = (i < n) ? counts[i] : 0;
    int x = v;
    #pragma unroll
    for (int off = 1; off < 64; off <<= 1) {
      int t = __shfl_up(x, off);
      if (lane >= off) x += t;
    }
    if (lane == 63) wsum[wid] = x;
    __syncthreads();
    if (wid == 0) {
      int w = (lane < 16) ? wsum[lane] : 0;
      #pragma unroll
      for (int off = 1; off < 16; off <<= 1) {
        int t = __shfl_up(w, off);
        if (lane >= off) w += t;
      }
      if (lane < 16) wsum[lane] = w;
    }
    __syncthreads();
    int wpre = (wid > 0) ? wsum[wid - 1] : 0;
    int total = wsum[15];
    if (i < n) {
      int excl = carry + wpre + x - v;
      offsets[i] = excl;
      cursor[i] = excl;
    }
    __syncthreads();                      // protect wsum before next chunk
    carry += total;
  }
  if (tid == 0) offsets[n] = carry;
}

__global__ void scatter_kernel(const int* __restrict__ ei, int E, int N,
                               int* __restrict__ cursor, int* __restrict__ src_csr,
                               int* __restrict__ dst_csr) {
  int e = blockIdx.x * 256 + threadIdx.x;
  if (e >= E + N) return;
  int s = (e < E) ? ei[e] : (e - E);
  int d = (e < E) ? ei[E + e] : (e - E);
  int pos = atomicAdd(&cursor[d], 1);
  src_csr[pos] = s;
  dst_csr[pos] = d;
}

// ---------------- f16 MFMA GEMM: out[M,Nc] = A[M,K] @ W[K,Nc], fp32 accum ----
// Block: 256 thr / 4 waves. Tile BM=128 x Nc (NT*16). BK=32.
// LDS rows padded to 40 f16 (80B stride: 16B-aligned, banks cycle 8 -> <=2-way).
// A/B frags share k-enumeration k=(lane>>4)*8+j; any consistent permutation of
// k is valid (sum over k is permutation-invariant; A/B HW layouts symmetric).
// C/D: col=lane&15, row=(lane>>4)*4+reg (HW-verified mapping).
template <int NT>   // Nc = NT*16
__global__ __launch_bounds__(256) void gemm_mfma_kernel(const float* __restrict__ A,
                                                        const float* __restrict__ W,
                                                        float* __restrict__ out,
                                                        int M, int K) {
  constexpr int Nc = NT * 16;
  constexpr int BM = 128, BK = 32;
  __shared__ _Float16 As[BM][40];
  __shared__ _Float16 Ws[Nc][40];
  int bm = blockIdx.x * BM;
  int tid = threadIdx.x;
  int w = tid >> 6, l = tid & 63;
  int lr = l & 15, lg = l >> 4;

  floatx4 acc[2][NT];
  #pragma unroll
  for (int rf = 0; rf < 2; ++rf)
    #pragma unroll
    for (int ct = 0; ct < NT; ++ct) acc[rf][ct] = (floatx4){0.f, 0.f, 0.f, 0.f};

  for (int k0 = 0; k0 < K; k0 += BK) {
    // stage A: 128x32 fp32 -> f16, 4 float4 per thread
    #pragma unroll
    for (int i = 0; i < 4; ++i) {
      int idx = tid + i * 256;          // 1024 float4 slots
      int r = idx >> 3, kq = idx & 7;
      int gr = bm + r;
      float4 v = make_float4(0.f, 0.f, 0.f, 0.f);
      if (gr < M) v = *(const float4*)&A[(size_t)gr * K + k0 + kq * 4];
      half4v hv = {(_Float16)v.x, (_Float16)v.y, (_Float16)v.z, (_Float16)v.w};
      *(half4v*)&As[r][kq * 4] = hv;
    }
    // stage W (transposed to [col][k]): NT iters, b32 (2 k) per write
    #pragma unroll
    for (int i = 0; i < NT; ++i) {
      int p = i * 256 + tid;            // pair index over (BK/2)*Nc = 16*Nc
      int col = p % Nc, kp = p / Nc;    // kp in 0..15
      float w0 = W[(size_t)(k0 + 2 * kp) * Nc + col];
      float w1 = W[(size_t)(k0 + 2 * kp + 1) * Nc + col];
      half2v hv = {(_Float16)w0, (_Float16)w1};
      *(half2v*)&Ws[col][2 * kp] = hv;
    }
    __syncthreads();
    half8v a0 = *(half8v*)&As[w * 32 + lr][lg * 8];
    half8v a1 = *(half8v*)&As[w * 32 + 16 + lr][lg * 8];
    #pragma unroll
    for (int ct = 0; ct < NT; ++ct) {
      half8v b = *(half8v*)&Ws[ct * 16 + lr][lg * 8];
      acc[0][ct] = __builtin_amdgcn_mfma_f32_16x16x32_f16(a0, b, acc[0][ct], 0, 0, 0);
      acc[1][ct] = __builtin_amdgcn_mfma_f32_16x16x32_f16(a1, b, acc[1][ct], 0, 0, 0);
    }
    __syncthreads();
  }
  #pragma unroll
  for (int rf = 0; rf < 2; ++rf)
    #pragma unroll
    for (int ct = 0; ct < NT; ++ct)
      #pragma unroll
      for (int q = 0; q < 4; ++q) {
        int row = bm + w * 32 + rf * 16 + lg * 4 + q;
        if (row < M) out[(size_t)row * Nc + ct * 16 + lr] = acc[rf][ct][q];
      }
}

// ---------------- per-node alpha_src/alpha_dst ----------------
template <int H>
__global__ void alpha_kernel(const float* __restrict__ h, const float* __restrict__ a_s,
                             const float* __restrict__ a_d, float* __restrict__ asrc,
                             float* __restrict__ adst, int n) {
  int wid = threadIdx.x >> 6, lane = threadIdx.x & 63;
  int node = blockIdx.x * 4 + wid;
  if (node >= n) return;
  const float* row = h + (size_t)node * (H * 64);
  #pragma unroll
  for (int hh = 0; hh < H; ++hh) {
    float v = row[hh * 64 + lane];
    float vs = v * a_s[hh * 64 + lane];
    float vd = v * a_d[hh * 64 + lane];
    #pragma unroll
    for (int off = 32; off; off >>= 1) {
      vs += __shfl_down(vs, off);
      vd += __shfl_down(vd, off);
    }
    if (lane == 0) {
      asrc[node * H + hh] = vs;
      adst[node * H + hh] = vd;
    }
  }
}

// ---------------- per-edge exp(leaky(score)) in CSR order ----------------
template <int H>
__global__ void edge_score_kernel(const float* __restrict__ asrc, const float* __restrict__ adst,
                                  const int* __restrict__ src_csr, const int* __restrict__ dst_csr,
                                  int ET, float* __restrict__ pexp) {
  int i = blockIdx.x * 256 + threadIdx.x;
  if (i >= ET) return;
  int s = src_csr[i], d = dst_csr[i];
  if (H == 4) {
    float4 as = ((const float4*)asrc)[s];
    float4 ad = ((const float4*)adst)[d];
    float4 e;
    float sc;
    sc = as.x + ad.x; sc = (sc >= 0.f) ? sc : 0.2f * sc; e.x = __expf(sc);
    sc = as.y + ad.y; sc = (sc >= 0.f) ? sc : 0.2f * sc; e.y = __expf(sc);
    sc = as.z + ad.z; sc = (sc >= 0.f) ? sc : 0.2f * sc; e.z = __expf(sc);
    sc = as.w + ad.w; sc = (sc >= 0.f) ? sc : 0.2f * sc; e.w = __expf(sc);
    ((float4*)pexp)[i] = e;
  } else {
    float sc = asrc[s] + adst[d];
    sc = (sc >= 0.f) ? sc : 0.2f * sc;
    pexp[i] = __expf(sc);
  }
}

// ---------------- aggregation, H=4: one wave per node, lane-float4 over 256 ch ----------------
__global__ __launch_bounds__(256) void agg4_kernel(const float* __restrict__ h,
                                                   const float* __restrict__ pexp,
                                                   const int* __restrict__ offsets,
                                                   const int* __restrict__ src_csr,
                                                   const float* __restrict__ bias,
                                                   float* __restrict__ out, int n) {
  int wid = threadIdx.x >> 6, lane = threadIdx.x & 63;
  int node = blockIdx.x * 4 + wid;
  if (node >= n) return;
  int start = offsets[node], end = offsets[node + 1];
  int head = lane >> 4;                    // lane's 4 channels all in this head
  const float4* h4 = (const float4*)h;
  float4 acc = make_float4(0.f, 0.f, 0.f, 0.f);
  float denom = 0.f;
  int i = start;
  for (; i + 4 <= end; i += 4) {
    int s0 = src_csr[i], s1 = src_csr[i + 1], s2 = src_csr[i + 2], s3 = src_csr[i + 3];
    float w0 = pexp[i * 4 + head];
    float w1 = pexp[(i + 1) * 4 + head];
    float w2 = pexp[(i + 2) * 4 + head];
    float w3 = pexp[(i + 3) * 4 + head];
    float4 v0 = h4[(size_t)s0 * 64 + lane];
    float4 v1 = h4[(size_t)s1 * 64 + lane];
    float4 v2 = h4[(size_t)s2 * 64 + lane];
    float4 v3 = h4[(size_t)s3 * 64 + lane];
    denom += (w0 + w1) + (w2 + w3);
    acc.x += w0 * v0.x + w1 * v1.x + w2 * v2.x + w3 * v3.x;
    acc.y += w0 * v0.y + w1 * v1.y + w2 * v2.y + w3 * v3.y;
    acc.z += w0 * v0.z + w1 * v1.z + w2 * v2.z + w3 * v3.z;
    acc.w += w0 * v0.w + w1 * v1.w + w2 * v2.w + w3 * v3.w;
  }
  for (; i < end; ++i) {
    int s = src_csr[i];
    float w = pexp[i * 4 + head];
    float4 v = h4[(size_t)s * 64 + lane];
    denom += w;
    acc.x += w * v.x; acc.y += w * v.y; acc.z += w * v.z; acc.w += w * v.w;
  }
  float inv = 1.f / denom;
  float4 b4 = ((const float4*)bias)[lane];
  float4 o;
  o.x = acc.x * inv + b4.x;
  o.y = acc.y * inv + b4.y;
  o.z = acc.z * inv + b4.z;
  o.w = acc.w * inv + b4.w;
  ((float4*)out)[(size_t)node * 64 + lane] = o;
}

// ---------------- aggregation, H=1 C=64 ----------------
__global__ __launch_bounds__(256) void agg1_kernel(const float* __restrict__ h,
                                                   const float* __restrict__ pexp,
                                                   const int* __restrict__ offsets,
                                                   const int* __restrict__ src_csr,
                                                   const float* __restrict__ bias,
                                                   float* __restrict__ out, int n) {
  int wid = threadIdx.x >> 6, lane = threadIdx.x & 63;
  int node = blockIdx.x * 4 + wid;
  if (node >= n) return;
  int start = offsets[node], end = offsets[node + 1];
  float acc = 0.f, denom = 0.f;
  int i = start;
  for (; i + 4 <= end; i += 4) {
    int s0 = src_csr[i], s1 = src_csr[i + 1], s2 = src_csr[i + 2], s3 = src_csr[i + 3];
    float w0 = pexp[i], w1 = pexp[i + 1], w2 = pexp[i + 2], w3 = pexp[i + 3];
    float v0 = h[(size_t)s0 * 64 + lane];
    float v1 = h[(size_t)s1 * 64 + lane];
    float v2 = h[(size_t)s2 * 64 + lane];
    float v3 = h[(size_t)s3 * 64 + lane];
    denom += (w0 + w1) + (w2 + w3);
    acc += w0 * v0 + w1 * v1 + w2 * v2 + w3 * v3;
  }
  for (; i < end; ++i) {
    int s = src_csr[i];
    float w = pexp[i];
    denom += w;
    acc += w * h[(size_t)s * 64 + lane];
  }
  out[(size_t)node * 64 + lane] = acc / denom + bias[lane];
}

// ---------------- LayerNorm + ELU (in place) ----------------
template <int D>
__global__ void ln_elu_kernel(float* __restrict__ x, const float* __restrict__ g,
                              const float* __restrict__ b, int n) {
  int wid = threadIdx.x >> 6, lane = threadIdx.x & 63;
  int node = blockIdx.x * 4 + wid;
  if (node >= n) return;
  float* row = x + (size_t)node * D;
  constexpr int PER = D / 64;
  float v[PER];
  float s = 0.f;
  #pragma unroll
  for (int i = 0; i < PER; ++i) {
    v[i] = row[i * 64 + lane];
    s += v[i];
  }
  #pragma unroll
  for (int off = 32; off; off >>= 1) s += __shfl_xor(s, off);
  float mu = s / D;
  float var = 0.f;
  #pragma unroll
  for (int i = 0; i < PER; ++i) {
    float d = v[i] - mu;
    var += d * d;
  }
  #pragma unroll
  for (int off = 32; off; off >>= 1) var += __shfl_xor(var, off);
  var /= D;
  float r = rsqrtf(var + 1e-5f);
  #pragma unroll
  for (int i = 0; i < PER; ++i) {
    float y = (v[i] - mu) * r * g[i * 64 + lane] + b[i * 64 + lane];
    y = (y > 0.f) ? y : expm1f(y);
    row[i * 64 + lane] = y;
  }
}

// ---------------- fused pool + MLP head (batch is sorted) ----------------
__global__ __launch_bounds__(256) void graph_head_kernel(const float* __restrict__ h,
                                                         const int* __restrict__ batch, int N,
                                                         const float* __restrict__ Wg,
                                                         const float* __restrict__ bg,
                                                         const float* __restrict__ Wg2,
                                                         const float* __restrict__ bg2,
                                                         const float* __restrict__ Wo,
                                                         const float* __restrict__ bo,
                                                         float* __restrict__ out) {
  __shared__ int bounds[2];
  __shared__ float part[4][64];
  __shared__ float gm[64];
  __shared__ float z1[128];
  __shared__ float z2[64];
  int g = blockIdx.x;
  int tid = threadIdx.x;
  if (tid < 2) {
    int target = g + tid;  // lower_bound(batch, target)
    int lo = 0, hi = N;
    while (lo < hi) {
      int mid = (lo + hi) >> 1;
      if (batch[mid] < target) lo = mid + 1; else hi = mid;
    }
    bounds[tid] = lo;
  }
  __syncthreads();
  int lo = bounds[0], hi = bounds[1];
  int c = tid & 63, sub = tid >> 6;
  float acc = 0.f;
  for (int r = lo + sub; r < hi; r += 4) acc += h[(size_t)r * 64 + c];
  part[sub][c] = acc;
  __syncthreads();
  float invc = 1.f / fmaxf((float)(hi - lo), 1.f);
  if (tid < 64) gm[tid] = (part[0][tid] + part[1][tid] + part[2][tid] + part[3][tid]) * invc;
  __syncthreads();
  if (tid < 128) {
    float a = bg[tid];
    for (int k = 0; k < 64; ++k) a += gm[k] * Wg[k * 128 + tid];
    z1[tid] = fmaxf(a, 0.f);
  }
  __syncthreads();
  if (tid < 64) {
    float a = bg2[tid];
    for (int k = 0; k < 128; ++k) a += z1[k] * Wg2[k * 64 + tid];
    z2[tid] = fmaxf(a, 0.f);
  }
  __syncthreads();
  if (tid < 5) {
    float a = bo[tid];
    for (int k = 0; k < 64; ++k) a += z2[k] * Wo[k * 5 + tid];
    out[g * 5 + tid] = a;
  }
}

// ---------------- launch ----------------
extern "C" void kernel_launch(void* const* d_in, const int* in_sizes, int n_in,
                              void* d_out, int out_size, void* d_ws, size_t ws_size,
                              hipStream_t stream) {
  const float* x   = (const float*)d_in[0];
  const int* ei    = (const int*)d_in[1];
  const int* batch = (const int*)d_in[2];
  const float* W1  = (const float*)d_in[3];
  const float* a1s = (const float*)d_in[4];
  const float* a1d = (const float*)d_in[5];
  const float* b1  = (const float*)d_in[6];
  const float* g1  = (const float*)d_in[7];
  const float* be1 = (const float*)d_in[8];
  const float* W2  = (const float*)d_in[9];
  const float* a2s = (const float*)d_in[10];
  const float* a2d = (const float*)d_in[11];
  const float* b2  = (const float*)d_in[12];
  const float* g2  = (const float*)d_in[13];
  const float* be2 = (const float*)d_in[14];
  const float* W3  = (const float*)d_in[15];
  const float* a3s = (const float*)d_in[16];
  const float* a3d = (const float*)d_in[17];
  const float* b3  = (const float*)d_in[18];
  const float* g3  = (const float*)d_in[19];
  const float* be3 = (const float*)d_in[20];
  const float* Wg  = (const float*)d_in[21];
  const float* bg  = (const float*)d_in[22];
  const float* Wg2 = (const float*)d_in[23];
  const float* bg2 = (const float*)d_in[24];
  const float* Wo  = (const float*)d_in[25];
  const float* bo  = (const float*)d_in[26];

  const int N = in_sizes[2];
  const int E = in_sizes[1] / 2;
  const int ET = E + N;  // with self-loops
  const int G = 64;

  // workspace carve-up (256B aligned)
  char* ws = (char*)d_ws;
  size_t off = 0;
  auto carve = [&](size_t bytes) {
    void* p = ws + off;
    off = (off + bytes + 255) & ~(size_t)255;
    return p;
  };
  int* counts   = (int*)carve((size_t)N * 4);
  int* offsets  = (int*)carve((size_t)(N + 1) * 4);
  int* cursor   = (int*)carve((size_t)N * 4);
  int* src_csr  = (int*)carve((size_t)ET * 4);
  int* dst_csr  = (int*)carve((size_t)ET * 4);
  float* pexp   = (float*)carve((size_t)ET * 4 * 4);
  float* asrc   = (float*)carve((size_t)N * 4 * 4);
  float* adst   = (float*)carve((size_t)N * 4 * 4);
  float* bufA   = (float*)carve((size_t)N * 256 * 4);
  float* bufB   = (float*)carve((size_t)N * 256 * 4);
  float* buf3   = (float*)carve((size_t)N * 64 * 4);
  (void)ws_size;

  const int egrid = (ET + 255) / 256;
  const int ngrid4 = (N + 3) / 4;
  const int mblocks = (N + 127) / 128;

  // --- CSR (dst-sorted src/dst lists), rebuilt every call ---
  hipMemsetAsync(counts, 0, (size_t)N * 4, stream);
  count_kernel<<<egrid, 256, 0, stream>>>(ei, E, N, counts);
  scan_kernel<<<1, 1024, 0, stream>>>(counts, offsets, cursor, N);
  scatter_kernel<<<egrid, 256, 0, stream>>>(ei, E, N, cursor, src_csr, dst_csr);

  // --- layer 1 ---
  gemm_mfma_kernel<16><<<mblocks, 256, 0, stream>>>(x, W1, bufA, N, 128);
  alpha_kernel<4><<<ngrid4, 256, 0, stream>>>(bufA, a1s, a1d, asrc, adst, N);
  edge_score_kernel<4><<<egrid, 256, 0, stream>>>(asrc, adst, src_csr, dst_csr, ET, pexp);
  agg4_kernel<<<ngrid4, 256, 0, stream>>>(bufA, pexp, offsets, src_csr, b1, bufB, N);
  ln_elu_kernel<256><<<ngrid4, 256, 0, stream>>>(bufB, g1, be1, N);

  // --- layer 2 ---
  gemm_mfma_kernel<16><<<mblocks, 256, 0, stream>>>(bufB, W2, bufA, N, 256);
  alpha_kernel<4><<<ngrid4, 256, 0, stream>>>(bufA, a2s, a2d, asrc, adst, N);
  edge_score_kernel<4><<<egrid, 256, 0, stream>>>(asrc, adst, src_csr, dst_csr, ET, pexp);
  agg4_kernel<<<ngrid4, 256, 0, stream>>>(bufA, pexp, offsets, src_csr, b2, bufB, N);
  ln_elu_kernel<256><<<ngrid4, 256, 0, stream>>>(bufB, g2, be2, N);

  // --- layer 3 (H=1, C=64) ---
  gemm_mfma_kernel<4><<<mblocks, 256, 0, stream>>>(bufB, W3, bufA, N, 256);
  alpha_kernel<1><<<ngrid4, 256, 0, stream>>>(bufA, a3s, a3d, asrc, adst, N);
  edge_score_kernel<1><<<egrid, 256, 0, stream>>>(asrc, adst, src_csr, dst_csr, ET, pexp);
  agg1_kernel<<<ngrid4, 256, 0, stream>>>(bufA, pexp, offsets, src_csr, b3, buf3, N);
  ln_elu_kernel<64><<<ngrid4, 256, 0, stream>>>(buf3, g3, be3, N);

  // --- fused pool + MLP head ---
  graph_head_kernel<<<G, 256, 0, stream>>>(buf3, batch, N, Wg, bg, Wg2, bg2, Wo, bo,
                                           (float*)d_out);
}

// Round 5
// 544.548 us; speedup vs baseline: 4.8478x; 1.2604x over previous
//
#include <hip/hip_runtime.h>
#include <math.h>

typedef _Float16 half2v __attribute__((ext_vector_type(2)));
typedef _Float16 half4v __attribute__((ext_vector_type(4)));
typedef _Float16 half8v __attribute__((ext_vector_type(8)));
typedef float floatx4 __attribute__((ext_vector_type(4)));

// ---------------- CSR build ----------------
__global__ void count_kernel(const int* __restrict__ ei, int E, int N, int* __restrict__ counts) {
  int e = blockIdx.x * 256 + threadIdx.x;
  if (e >= E + N) return;
  int d = (e < E) ? ei[E + e] : (e - E);   // row1 = dst
  atomicAdd(&counts[d], 1);
}

__global__ void scan_kernel(const int* __restrict__ counts, int* __restrict__ offsets,
                            int* __restrict__ cursor, int n) {
  __shared__ int wsum[16];
  int tid = threadIdx.x;                 // blockDim = 1024
  int lane = tid & 63, wid = tid >> 6;
  int carry = 0;
  for (int base = 0; base < n; base += 1024) {
    int i = base + tid;
    int v = (i < n) ? counts[i] : 0;
    int x = v;
    #pragma unroll
    for (int off = 1; off < 64; off <<= 1) {
      int t = __shfl_up(x, off);
      if (lane >= off) x += t;
    }
    if (lane == 63) wsum[wid] = x;
    __syncthreads();
    if (wid == 0) {
      int w = (lane < 16) ? wsum[lane] : 0;
      #pragma unroll
      for (int off = 1; off < 16; off <<= 1) {
        int t = __shfl_up(w, off);
        if (lane >= off) w += t;
      }
      if (lane < 16) wsum[lane] = w;
    }
    __syncthreads();
    int wpre = (wid > 0) ? wsum[wid - 1] : 0;
    int total = wsum[15];
    if (i < n) {
      int excl = carry + wpre + x - v;
      offsets[i] = excl;
      cursor[i] = excl;
    }
    __syncthreads();                      // protect wsum before next chunk
    carry += total;
  }
  if (tid == 0) offsets[n] = carry;
}

__global__ void scatter_kernel(const int* __restrict__ ei, int E, int N,
                               int* __restrict__ cursor, int* __restrict__ src_csr,
                               int* __restrict__ dst_csr) {
  int e = blockIdx.x * 256 + threadIdx.x;
  if (e >= E + N) return;
  int s = (e < E) ? ei[e] : (e - E);
  int d = (e < E) ? ei[E + e] : (e - E);
  int pos = atomicAdd(&cursor[d], 1);
  src_csr[pos] = s;
  dst_csr[pos] = d;
}

// ---------------- f16 MFMA GEMM: out[M,Nc] = A[M,K] @ W[K,Nc], fp32 accum ----
// Also writes an f16 copy of the output (gather table for aggregation).
template <int NT>   // Nc = NT*16
__global__ __launch_bounds__(256) void gemm_mfma_kernel(const float* __restrict__ A,
                                                        const float* __restrict__ W,
                                                        float* __restrict__ out,
                                                        _Float16* __restrict__ out16,
                                                        int M, int K) {
  constexpr int Nc = NT * 16;
  constexpr int BM = 128, BK = 32;
  __shared__ _Float16 As[BM][40];
  __shared__ _Float16 Ws[Nc][40];
  int bm = blockIdx.x * BM;
  int tid = threadIdx.x;
  int w = tid >> 6, l = tid & 63;
  int lr = l & 15, lg = l >> 4;

  floatx4 acc[2][NT];
  #pragma unroll
  for (int rf = 0; rf < 2; ++rf)
    #pragma unroll
    for (int ct = 0; ct < NT; ++ct) acc[rf][ct] = (floatx4){0.f, 0.f, 0.f, 0.f};

  for (int k0 = 0; k0 < K; k0 += BK) {
    // stage A: 128x32 fp32 -> f16, 4 float4 per thread
    #pragma unroll
    for (int i = 0; i < 4; ++i) {
      int idx = tid + i * 256;          // 1024 float4 slots
      int r = idx >> 3, kq = idx & 7;
      int gr = bm + r;
      float4 v = make_float4(0.f, 0.f, 0.f, 0.f);
      if (gr < M) v = *(const float4*)&A[(size_t)gr * K + k0 + kq * 4];
      half4v hv = {(_Float16)v.x, (_Float16)v.y, (_Float16)v.z, (_Float16)v.w};
      *(half4v*)&As[r][kq * 4] = hv;
    }
    // stage W (transposed to [col][k]): NT iters, b32 (2 k) per write
    #pragma unroll
    for (int i = 0; i < NT; ++i) {
      int p = i * 256 + tid;            // pair index over (BK/2)*Nc = 16*Nc
      int col = p % Nc, kp = p / Nc;    // kp in 0..15
      float w0 = W[(size_t)(k0 + 2 * kp) * Nc + col];
      float w1 = W[(size_t)(k0 + 2 * kp + 1) * Nc + col];
      half2v hv = {(_Float16)w0, (_Float16)w1};
      *(half2v*)&Ws[col][2 * kp] = hv;
    }
    __syncthreads();
    half8v a0 = *(half8v*)&As[w * 32 + lr][lg * 8];
    half8v a1 = *(half8v*)&As[w * 32 + 16 + lr][lg * 8];
    #pragma unroll
    for (int ct = 0; ct < NT; ++ct) {
      half8v b = *(half8v*)&Ws[ct * 16 + lr][lg * 8];
      acc[0][ct] = __builtin_amdgcn_mfma_f32_16x16x32_f16(a0, b, acc[0][ct], 0, 0, 0);
      acc[1][ct] = __builtin_amdgcn_mfma_f32_16x16x32_f16(a1, b, acc[1][ct], 0, 0, 0);
    }
    __syncthreads();
  }
  #pragma unroll
  for (int rf = 0; rf < 2; ++rf)
    #pragma unroll
    for (int ct = 0; ct < NT; ++ct)
      #pragma unroll
      for (int q = 0; q < 4; ++q) {
        int row = bm + w * 32 + rf * 16 + lg * 4 + q;
        if (row < M) {
          float v = acc[rf][ct][q];
          out[(size_t)row * Nc + ct * 16 + lr] = v;
          out16[(size_t)row * Nc + ct * 16 + lr] = (_Float16)v;
        }
      }
}

// ---------------- per-node alpha_src/alpha_dst ----------------
template <int H>
__global__ void alpha_kernel(const float* __restrict__ h, const float* __restrict__ a_s,
                             const float* __restrict__ a_d, float* __restrict__ asrc,
                             float* __restrict__ adst, int n) {
  int wid = threadIdx.x >> 6, lane = threadIdx.x & 63;
  int node = blockIdx.x * 4 + wid;
  if (node >= n) return;
  const float* row = h + (size_t)node * (H * 64);
  #pragma unroll
  for (int hh = 0; hh < H; ++hh) {
    float v = row[hh * 64 + lane];
    float vs = v * a_s[hh * 64 + lane];
    float vd = v * a_d[hh * 64 + lane];
    #pragma unroll
    for (int off = 32; off; off >>= 1) {
      vs += __shfl_down(vs, off);
      vd += __shfl_down(vd, off);
    }
    if (lane == 0) {
      asrc[node * H + hh] = vs;
      adst[node * H + hh] = vd;
    }
  }
}

// ---------------- per-edge exp(leaky(score)) in CSR order ----------------
template <int H>
__global__ void edge_score_kernel(const float* __restrict__ asrc, const float* __restrict__ adst,
                                  const int* __restrict__ src_csr, const int* __restrict__ dst_csr,
                                  int ET, float* __restrict__ pexp) {
  int i = blockIdx.x * 256 + threadIdx.x;
  if (i >= ET) return;
  int s = src_csr[i], d = dst_csr[i];
  if (H == 4) {
    float4 as = ((const float4*)asrc)[s];
    float4 ad = ((const float4*)adst)[d];
    float4 e;
    float sc;
    sc = as.x + ad.x; sc = (sc >= 0.f) ? sc : 0.2f * sc; e.x = __expf(sc);
    sc = as.y + ad.y; sc = (sc >= 0.f) ? sc : 0.2f * sc; e.y = __expf(sc);
    sc = as.z + ad.z; sc = (sc >= 0.f) ? sc : 0.2f * sc; e.z = __expf(sc);
    sc = as.w + ad.w; sc = (sc >= 0.f) ? sc : 0.2f * sc; e.w = __expf(sc);
    ((float4*)pexp)[i] = e;
  } else {
    float sc = asrc[s] + adst[d];
    sc = (sc >= 0.f) ? sc : 0.2f * sc;
    pexp[i] = __expf(sc);
  }
}

// ---------------- fused aggregation + LayerNorm + ELU, H=4 (256 ch) -----------
// Half-wave (32 lanes x 16B f16) covers one source row; two edges per pass.
__global__ __launch_bounds__(256) void agg4_ln_kernel(const _Float16* __restrict__ h16,
                                                      const float* __restrict__ pexp,
                                                      const int* __restrict__ offsets,
                                                      const int* __restrict__ src_csr,
                                                      const float* __restrict__ bias,
                                                      const float* __restrict__ g,
                                                      const float* __restrict__ be,
                                                      float* __restrict__ out, int n) {
  int wid = threadIdx.x >> 6, lane = threadIdx.x & 63;
  int node = blockIdx.x * 4 + wid;
  if (node >= n) return;
  int start = offsets[node], end = offsets[node + 1];
  int hl = lane >> 5;            // half-wave index (edge parity)
  int l5 = lane & 31;            // position within half: channels l5*8 .. l5*8+7
  int head = l5 >> 3;            // 8 ch per lane, 64 per head
  float acc[8] = {0.f, 0.f, 0.f, 0.f, 0.f, 0.f, 0.f, 0.f};
  float denom = 0.f;
  int i = start + hl;
  for (; i + 2 < end; i += 4) {  // two edges (i, i+2) per half-wave iteration
    int s0 = src_csr[i], s1 = src_csr[i + 2];
    float w0 = pexp[i * 4 + head];
    float w1 = pexp[(i + 2) * 4 + head];
    half8v v0 = *(const half8v*)&h16[(size_t)s0 * 256 + l5 * 8];
    half8v v1 = *(const half8v*)&h16[(size_t)s1 * 256 + l5 * 8];
    denom += w0 + w1;
    #pragma unroll
    for (int j = 0; j < 8; ++j) acc[j] += w0 * (float)v0[j] + w1 * (float)v1[j];
  }
  if (i < end) {
    int s = src_csr[i];
    float w = pexp[i * 4 + head];
    half8v v = *(const half8v*)&h16[(size_t)s * 256 + l5 * 8];
    denom += w;
    #pragma unroll
    for (int j = 0; j < 8; ++j) acc[j] += w * (float)v[j];
  }
  // combine the two half-waves (even/odd edges)
  #pragma unroll
  for (int j = 0; j < 8; ++j) acc[j] += __shfl_xor(acc[j], 32);
  denom += __shfl_xor(denom, 32);
  float inv = 1.f / denom;
  float o[8];
  float4 b0 = *(const float4*)&bias[l5 * 8];
  float4 b1 = *(const float4*)&bias[l5 * 8 + 4];
  o[0] = acc[0] * inv + b0.x; o[1] = acc[1] * inv + b0.y;
  o[2] = acc[2] * inv + b0.z; o[3] = acc[3] * inv + b0.w;
  o[4] = acc[4] * inv + b1.x; o[5] = acc[5] * inv + b1.y;
  o[6] = acc[6] * inv + b1.z; o[7] = acc[7] * inv + b1.w;
  // LayerNorm over 256 ch (row spread across 32 lanes; halves identical)
  float s = 0.f;
  #pragma unroll
  for (int j = 0; j < 8; ++j) s += o[j];
  #pragma unroll
  for (int off = 16; off; off >>= 1) s += __shfl_xor(s, off);
  float mu = s * (1.f / 256.f);
  float var = 0.f;
  #pragma unroll
  for (int j = 0; j < 8; ++j) { float d = o[j] - mu; var += d * d; }
  #pragma unroll
  for (int off = 16; off; off >>= 1) var += __shfl_xor(var, off);
  float r = rsqrtf(var * (1.f / 256.f) + 1e-5f);
  float4 g0 = *(const float4*)&g[l5 * 8];
  float4 g1 = *(const float4*)&g[l5 * 8 + 4];
  float4 e0 = *(const float4*)&be[l5 * 8];
  float4 e1 = *(const float4*)&be[l5 * 8 + 4];
  float gg[8] = {g0.x, g0.y, g0.z, g0.w, g1.x, g1.y, g1.z, g1.w};
  float ee[8] = {e0.x, e0.y, e0.z, e0.w, e1.x, e1.y, e1.z, e1.w};
  float y[8];
  #pragma unroll
  for (int j = 0; j < 8; ++j) {
    float t = (o[j] - mu) * r * gg[j] + ee[j];
    y[j] = (t > 0.f) ? t : expm1f(t);
  }
  if (hl == 0) {
    float4 y0 = make_float4(y[0], y[1], y[2], y[3]);
    float4 y1 = make_float4(y[4], y[5], y[6], y[7]);
    *(float4*)&out[(size_t)node * 256 + l5 * 8] = y0;
    *(float4*)&out[(size_t)node * 256 + l5 * 8 + 4] = y1;
  }
}

// ---------------- fused aggregation + LayerNorm + ELU, H=1 (64 ch) ------------
// Quarter-wave (16 lanes x 8B f16) covers one source row; four edges per pass.
__global__ __launch_bounds__(256) void agg1_ln_kernel(const _Float16* __restrict__ h16,
                                                      const float* __restrict__ pexp,
                                                      const int* __restrict__ offsets,
                                                      const int* __restrict__ src_csr,
                                                      const float* __restrict__ bias,
                                                      const float* __restrict__ g,
                                                      const float* __restrict__ be,
                                                      float* __restrict__ out, int n) {
  int wid = threadIdx.x >> 6, lane = threadIdx.x & 63;
  int node = blockIdx.x * 4 + wid;
  if (node >= n) return;
  int start = offsets[node], end = offsets[node + 1];
  int qi = lane >> 4;            // quarter index (edge offset)
  int ql = lane & 15;            // channels ql*4 .. ql*4+3
  float acc[4] = {0.f, 0.f, 0.f, 0.f};
  float denom = 0.f;
  int i = start + qi;
  for (; i + 4 < end; i += 8) {  // two edges (i, i+4) per quarter iteration
    int s0 = src_csr[i], s1 = src_csr[i + 4];
    float w0 = pexp[i], w1 = pexp[i + 4];
    half4v v0 = *(const half4v*)&h16[(size_t)s0 * 64 + ql * 4];
    half4v v1 = *(const half4v*)&h16[(size_t)s1 * 64 + ql * 4];
    denom += w0 + w1;
    #pragma unroll
    for (int j = 0; j < 4; ++j) acc[j] += w0 * (float)v0[j] + w1 * (float)v1[j];
  }
  if (i < end) {
    int s = src_csr[i];
    float w = pexp[i];
    half4v v = *(const half4v*)&h16[(size_t)s * 64 + ql * 4];
    denom += w;
    #pragma unroll
    for (int j = 0; j < 4; ++j) acc[j] += w * (float)v[j];
  }
  // combine four quarter-waves
  #pragma unroll
  for (int off = 32; off >= 16; off >>= 1) {
    #pragma unroll
    for (int j = 0; j < 4; ++j) acc[j] += __shfl_xor(acc[j], off);
    denom += __shfl_xor(denom, off);
  }
  float inv = 1.f / denom;
  float4 b4 = *(const float4*)&bias[ql * 4];
  float o[4];
  o[0] = acc[0] * inv + b4.x; o[1] = acc[1] * inv + b4.y;
  o[2] = acc[2] * inv + b4.z; o[3] = acc[3] * inv + b4.w;
  // LayerNorm over 64 ch (row spread across 16 lanes; quarters identical)
  float s = o[0] + o[1] + o[2] + o[3];
  #pragma unroll
  for (int off = 8; off; off >>= 1) s += __shfl_xor(s, off);
  float mu = s * (1.f / 64.f);
  float var = 0.f;
  #pragma unroll
  for (int j = 0; j < 4; ++j) { float d = o[j] - mu; var += d * d; }
  #pragma unroll
  for (int off = 8; off; off >>= 1) var += __shfl_xor(var, off);
  float r = rsqrtf(var * (1.f / 64.f) + 1e-5f);
  float4 g4 = *(const float4*)&g[ql * 4];
  float4 e4 = *(const float4*)&be[ql * 4];
  float gg[4] = {g4.x, g4.y, g4.z, g4.w};
  float ee[4] = {e4.x, e4.y, e4.z, e4.w};
  float y[4];
  #pragma unroll
  for (int j = 0; j < 4; ++j) {
    float t = (o[j] - mu) * r * gg[j] + ee[j];
    y[j] = (t > 0.f) ? t : expm1f(t);
  }
  if (qi == 0) {
    *(float4*)&out[(size_t)node * 64 + ql * 4] = make_float4(y[0], y[1], y[2], y[3]);
  }
}

// ---------------- fused pool + MLP head (batch is sorted) ----------------
__global__ __launch_bounds__(256) void graph_head_kernel(const float* __restrict__ h,
                                                         const int* __restrict__ batch, int N,
                                                         const float* __restrict__ Wg,
                                                         const float* __restrict__ bg,
                                                         const float* __restrict__ Wg2,
                                                         const float* __restrict__ bg2,
                                                         const float* __restrict__ Wo,
                                                         const float* __restrict__ bo,
                                                         float* __restrict__ out) {
  __shared__ int bounds[2];
  __shared__ float part[4][64];
  __shared__ float gm[64];
  __shared__ float z1[128];
  __shared__ float z2[64];
  int g = blockIdx.x;
  int tid = threadIdx.x;
  if (tid < 2) {
    int target = g + tid;  // lower_bound(batch, target)
    int lo = 0, hi = N;
    while (lo < hi) {
      int mid = (lo + hi) >> 1;
      if (batch[mid] < target) lo = mid + 1; else hi = mid;
    }
    bounds[tid] = lo;
  }
  __syncthreads();
  int lo = bounds[0], hi = bounds[1];
  int c = tid & 63, sub = tid >> 6;
  float acc = 0.f;
  for (int r = lo + sub; r < hi; r += 4) acc += h[(size_t)r * 64 + c];
  part[sub][c] = acc;
  __syncthreads();
  float invc = 1.f / fmaxf((float)(hi - lo), 1.f);
  if (tid < 64) gm[tid] = (part[0][tid] + part[1][tid] + part[2][tid] + part[3][tid]) * invc;
  __syncthreads();
  if (tid < 128) {
    float a = bg[tid];
    for (int k = 0; k < 64; ++k) a += gm[k] * Wg[k * 128 + tid];
    z1[tid] = fmaxf(a, 0.f);
  }
  __syncthreads();
  if (tid < 64) {
    float a = bg2[tid];
    for (int k = 0; k < 128; ++k) a += z1[k] * Wg2[k * 64 + tid];
    z2[tid] = fmaxf(a, 0.f);
  }
  __syncthreads();
  if (tid < 5) {
    float a = bo[tid];
    for (int k = 0; k < 64; ++k) a += z2[k] * Wo[k * 5 + tid];
    out[g * 5 + tid] = a;
  }
}

// ---------------- launch ----------------
extern "C" void kernel_launch(void* const* d_in, const int* in_sizes, int n_in,
                              void* d_out, int out_size, void* d_ws, size_t ws_size,
                              hipStream_t stream) {
  const float* x   = (const float*)d_in[0];
  const int* ei    = (const int*)d_in[1];
  const int* batch = (const int*)d_in[2];
  const float* W1  = (const float*)d_in[3];
  const float* a1s = (const float*)d_in[4];
  const float* a1d = (const float*)d_in[5];
  const float* b1  = (const float*)d_in[6];
  const float* g1  = (const float*)d_in[7];
  const float* be1 = (const float*)d_in[8];
  const float* W2  = (const float*)d_in[9];
  const float* a2s = (const float*)d_in[10];
  const float* a2d = (const float*)d_in[11];
  const float* b2  = (const float*)d_in[12];
  const float* g2  = (const float*)d_in[13];
  const float* be2 = (const float*)d_in[14];
  const float* W3  = (const float*)d_in[15];
  const float* a3s = (const float*)d_in[16];
  const float* a3d = (const float*)d_in[17];
  const float* b3  = (const float*)d_in[18];
  const float* g3  = (const float*)d_in[19];
  const float* be3 = (const float*)d_in[20];
  const float* Wg  = (const float*)d_in[21];
  const float* bg  = (const float*)d_in[22];
  const float* Wg2 = (const float*)d_in[23];
  const float* bg2 = (const float*)d_in[24];
  const float* Wo  = (const float*)d_in[25];
  const float* bo  = (const float*)d_in[26];

  const int N = in_sizes[2];
  const int E = in_sizes[1] / 2;
  const int ET = E + N;  // with self-loops
  const int G = 64;

  // workspace carve-up (256B aligned)
  char* ws = (char*)d_ws;
  size_t off = 0;
  auto carve = [&](size_t bytes) {
    void* p = ws + off;
    off = (off + bytes + 255) & ~(size_t)255;
    return p;
  };
  int* counts   = (int*)carve((size_t)N * 4);
  int* offsets  = (int*)carve((size_t)(N + 1) * 4);
  int* cursor   = (int*)carve((size_t)N * 4);
  int* src_csr  = (int*)carve((size_t)ET * 4);
  int* dst_csr  = (int*)carve((size_t)ET * 4);
  float* pexp   = (float*)carve((size_t)ET * 4 * 4);
  float* asrc   = (float*)carve((size_t)N * 4 * 4);
  float* adst   = (float*)carve((size_t)N * 4 * 4);
  float* bufA   = (float*)carve((size_t)N * 256 * 4);
  float* bufB   = (float*)carve((size_t)N * 256 * 4);
  float* buf3   = (float*)carve((size_t)N * 64 * 4);
  _Float16* h16 = (_Float16*)carve((size_t)N * 256 * 2);
  (void)ws_size;

  const int egrid = (ET + 255) / 256;
  const int ngrid4 = (N + 3) / 4;
  const int mblocks = (N + 127) / 128;

  // --- CSR (dst-sorted src/dst lists), rebuilt every call ---
  hipMemsetAsync(counts, 0, (size_t)N * 4, stream);
  count_kernel<<<egrid, 256, 0, stream>>>(ei, E, N, counts);
  scan_kernel<<<1, 1024, 0, stream>>>(counts, offsets, cursor, N);
  scatter_kernel<<<egrid, 256, 0, stream>>>(ei, E, N, cursor, src_csr, dst_csr);

  // --- layer 1 ---
  gemm_mfma_kernel<16><<<mblocks, 256, 0, stream>>>(x, W1, bufA, h16, N, 128);
  alpha_kernel<4><<<ngrid4, 256, 0, stream>>>(bufA, a1s, a1d, asrc, adst, N);
  edge_score_kernel<4><<<egrid, 256, 0, stream>>>(asrc, adst, src_csr, dst_csr, ET, pexp);
  agg4_ln_kernel<<<ngrid4, 256, 0, stream>>>(h16, pexp, offsets, src_csr, b1, g1, be1, bufB, N);

  // --- layer 2 ---
  gemm_mfma_kernel<16><<<mblocks, 256, 0, stream>>>(bufB, W2, bufA, h16, N, 256);
  alpha_kernel<4><<<ngrid4, 256, 0, stream>>>(bufA, a2s, a2d, asrc, adst, N);
  edge_score_kernel<4><<<egrid, 256, 0, stream>>>(asrc, adst, src_csr, dst_csr, ET, pexp);
  agg4_ln_kernel<<<ngrid4, 256, 0, stream>>>(h16, pexp, offsets, src_csr, b2, g2, be2, bufB, N);

  // --- layer 3 (H=1, C=64) ---
  gemm_mfma_kernel<4><<<mblocks, 256, 0, stream>>>(bufB, W3, bufA, h16, N, 256);
  alpha_kernel<1><<<ngrid4, 256, 0, stream>>>(bufA, a3s, a3d, asrc, adst, N);
  edge_score_kernel<1><<<egrid, 256, 0, stream>>>(asrc, adst, src_csr, dst_csr, ET, pexp);
  agg1_ln_kernel<<<ngrid4, 256, 0, stream>>>(h16, pexp, offsets, src_csr, b3, g3, be3, buf3, N);

  // --- fused pool + MLP head ---
  graph_head_kernel<<<G, 256, 0, stream>>>(buf3, batch, N, Wg, bg, Wg2, bg2, Wo, bo,
                                           (float*)d_out);
}

// Round 7
// 481.632 us; speedup vs baseline: 5.4811x; 1.1306x over previous
//
#include <hip/hip_runtime.h>
#include <math.h>

typedef _Float16 half2v __attribute__((ext_vector_type(2)));
typedef _Float16 half4v __attribute__((ext_vector_type(4)));
typedef _Float16 half8v __attribute__((ext_vector_type(8)));
typedef float floatx4 __attribute__((ext_vector_type(4)));

static __device__ __forceinline__ half2v pack_rtz(float a, float b) {
  return __builtin_bit_cast(half2v, __builtin_amdgcn_cvt_pkrtz(a, b));
}

// ---------------- CSR build ----------------
__global__ void count_kernel(const int* __restrict__ ei, int E, int N, int* __restrict__ counts) {
  int e = blockIdx.x * 256 + threadIdx.x;
  if (e >= E + N) return;
  int d = (e < E) ? ei[E + e] : (e - E);   // row1 = dst
  atomicAdd(&counts[d], 1);
}

__global__ void scan_kernel(const int* __restrict__ counts, int* __restrict__ offsets,
                            int* __restrict__ cursor, int n) {
  __shared__ int wsum[16];
  int tid = threadIdx.x;                 // blockDim = 1024
  int lane = tid & 63, wid = tid >> 6;
  int carry = 0;
  for (int base = 0; base < n; base += 1024) {
    int i = base + tid;
    int v = (i < n) ? counts[i] : 0;
    int x = v;
    #pragma unroll
    for (int off = 1; off < 64; off <<= 1) {
      int t = __shfl_up(x, off);
      if (lane >= off) x += t;
    }
    if (lane == 63) wsum[wid] = x;
    __syncthreads();
    if (wid == 0) {
      int w = (lane < 16) ? wsum[lane] : 0;
      #pragma unroll
      for (int off = 1; off < 16; off <<= 1) {
        int t = __shfl_up(w, off);
        if (lane >= off) w += t;
      }
      if (lane < 16) wsum[lane] = w;
    }
    __syncthreads();
    int wpre = (wid > 0) ? wsum[wid - 1] : 0;
    int total = wsum[15];
    if (i < n) {
      int excl = carry + wpre + x - v;
      offsets[i] = excl;
      cursor[i] = excl;
    }
    __syncthreads();                      // protect wsum before next chunk
    carry += total;
  }
  if (tid == 0) offsets[n] = carry;
}

__global__ void scatter_kernel(const int* __restrict__ ei, int E, int N,
                               int* __restrict__ cursor, int* __restrict__ src_csr,
                               int* __restrict__ dst_csr) {
  int e = blockIdx.x * 256 + threadIdx.x;
  if (e >= E + N) return;
  int s = (e < E) ? ei[e] : (e - E);
  int d = (e < E) ? ei[E + e] : (e - E);
  int pos = atomicAdd(&cursor[d], 1);
  src_csr[pos] = s;
  dst_csr[pos] = d;
}

// ---------------- f16 MFMA GEMM + fused alpha epilogue ----------------
// Writes h16 (f16 gather table) and asrc/adst (per-node attention scalars).
// No f32 h output (nothing downstream reads it).
template <int NT, int H>   // Nc = NT*16
__global__ __launch_bounds__(256) void gemm_mfma_kernel(const float* __restrict__ A,
                                                        const float* __restrict__ W,
                                                        const float* __restrict__ als,
                                                        const float* __restrict__ ald,
                                                        _Float16* __restrict__ out16,
                                                        float* __restrict__ asrc,
                                                        float* __restrict__ adst,
                                                        int M, int K) {
  constexpr int Nc = NT * 16;
  constexpr int BM = 128, BK = 32;
  constexpr int CPH = NT / H;            // col-tiles per head
  __shared__ _Float16 As[BM][40];
  __shared__ _Float16 Ws[Nc][40];
  int bm = blockIdx.x * BM;
  int tid = threadIdx.x;
  int w = tid >> 6, l = tid & 63;
  int lr = l & 15, lg = l >> 4;

  floatx4 acc[2][NT];
  #pragma unroll
  for (int rf = 0; rf < 2; ++rf)
    #pragma unroll
    for (int ct = 0; ct < NT; ++ct) acc[rf][ct] = (floatx4){0.f, 0.f, 0.f, 0.f};

  for (int k0 = 0; k0 < K; k0 += BK) {
    // stage A: 128x32 fp32 -> f16, 4 float4 per thread
    #pragma unroll
    for (int i = 0; i < 4; ++i) {
      int idx = tid + i * 256;          // 1024 float4 slots
      int r = idx >> 3, kq = idx & 7;
      int gr = bm + r;
      float4 v = make_float4(0.f, 0.f, 0.f, 0.f);
      if (gr < M) v = *(const float4*)&A[(size_t)gr * K + k0 + kq * 4];
      half4v hv = {(_Float16)v.x, (_Float16)v.y, (_Float16)v.z, (_Float16)v.w};
      *(half4v*)&As[r][kq * 4] = hv;
    }
    // stage W (transposed to [col][k]): NT iters, b32 (2 k) per write
    #pragma unroll
    for (int i = 0; i < NT; ++i) {
      int p = i * 256 + tid;            // pair index over (BK/2)*Nc = 16*Nc
      int col = p % Nc, kp = p / Nc;    // kp in 0..15
      float w0 = W[(size_t)(k0 + 2 * kp) * Nc + col];
      float w1 = W[(size_t)(k0 + 2 * kp + 1) * Nc + col];
      half2v hv = {(_Float16)w0, (_Float16)w1};
      *(half2v*)&Ws[col][2 * kp] = hv;
    }
    __syncthreads();
    half8v a0 = *(half8v*)&As[w * 32 + lr][lg * 8];
    half8v a1 = *(half8v*)&As[w * 32 + 16 + lr][lg * 8];
    #pragma unroll
    for (int ct = 0; ct < NT; ++ct) {
      half8v b = *(half8v*)&Ws[ct * 16 + lr][lg * 8];
      acc[0][ct] = __builtin_amdgcn_mfma_f32_16x16x32_f16(a0, b, acc[0][ct], 0, 0, 0);
      acc[1][ct] = __builtin_amdgcn_mfma_f32_16x16x32_f16(a1, b, acc[1][ct], 0, 0, 0);
    }
    __syncthreads();
  }
  // preload attention vectors (col = ct*16 + lr)
  float als_r[NT], ald_r[NT];
  #pragma unroll
  for (int ct = 0; ct < NT; ++ct) {
    als_r[ct] = als[ct * 16 + lr];
    ald_r[ct] = ald[ct * 16 + lr];
  }
  #pragma unroll
  for (int rf = 0; rf < 2; ++rf)
    #pragma unroll
    for (int q = 0; q < 4; ++q) {
      int row = bm + w * 32 + rf * 16 + lg * 4 + q;
      float ps[H], pd[H];
      #pragma unroll
      for (int hh = 0; hh < H; ++hh) {
        float s = 0.f, d = 0.f;
        #pragma unroll
        for (int c2 = 0; c2 < CPH; ++c2) {
          int ct = hh * CPH + c2;
          s += acc[rf][ct][q] * als_r[ct];
          d += acc[rf][ct][q] * ald_r[ct];
        }
        ps[hh] = s; pd[hh] = d;
      }
      #pragma unroll
      for (int off = 1; off < 16; off <<= 1) {
        #pragma unroll
        for (int hh = 0; hh < H; ++hh) {
          ps[hh] += __shfl_xor(ps[hh], off);
          pd[hh] += __shfl_xor(pd[hh], off);
        }
      }
      if (row < M) {
        if (lr == 0) {
          #pragma unroll
          for (int hh = 0; hh < H; ++hh) asrc[row * H + hh] = ps[hh];
        } else if (lr == 1) {
          #pragma unroll
          for (int hh = 0; hh < H; ++hh) adst[row * H + hh] = pd[hh];
        }
        #pragma unroll
        for (int ct = 0; ct < NT; ++ct)
          out16[(size_t)row * Nc + ct * 16 + lr] = (_Float16)acc[rf][ct][q];
      }
    }
}

// ---------------- per-edge exp(leaky(score)) in CSR order ----------------
template <int H>
__global__ void edge_score_kernel(const float* __restrict__ asrc, const float* __restrict__ adst,
                                  const int* __restrict__ src_csr, const int* __restrict__ dst_csr,
                                  int ET, float* __restrict__ pexp) {
  int i = blockIdx.x * 256 + threadIdx.x;
  if (i >= ET) return;
  int s = src_csr[i], d = dst_csr[i];
  if (H == 4) {
    float4 as = ((const float4*)asrc)[s];
    float4 ad = ((const float4*)adst)[d];
    float4 e;
    float sc;
    sc = as.x + ad.x; sc = (sc >= 0.f) ? sc : 0.2f * sc; e.x = __expf(sc);
    sc = as.y + ad.y; sc = (sc >= 0.f) ? sc : 0.2f * sc; e.y = __expf(sc);
    sc = as.z + ad.z; sc = (sc >= 0.f) ? sc : 0.2f * sc; e.z = __expf(sc);
    sc = as.w + ad.w; sc = (sc >= 0.f) ? sc : 0.2f * sc; e.w = __expf(sc);
    ((float4*)pexp)[i] = e;
  } else {
    float sc = asrc[s] + adst[d];
    sc = (sc >= 0.f) ? sc : 0.2f * sc;
    pexp[i] = __expf(sc);
  }
}

// ---------------- fused aggregation + LayerNorm + ELU, H=4 (256 ch) -----------
// Half-wave (32 lanes x 16B f16) per source row; 2 edges fused via v_dot2.
__global__ __launch_bounds__(256) void agg4_ln_kernel(const _Float16* __restrict__ h16,
                                                      const float* __restrict__ pexp,
                                                      const int* __restrict__ offsets,
                                                      const int* __restrict__ src_csr,
                                                      const float* __restrict__ bias,
                                                      const float* __restrict__ g,
                                                      const float* __restrict__ be,
                                                      float* __restrict__ out, int n) {
  int wid = threadIdx.x >> 6, lane = threadIdx.x & 63;
  int node = blockIdx.x * 4 + wid;
  if (node >= n) return;
  int start = offsets[node], end = offsets[node + 1];
  int hl = lane >> 5;            // half-wave index (edge parity)
  int l5 = lane & 31;            // channels l5*8 .. l5*8+7
  int head = l5 >> 3;
  const uint4* h4 = (const uint4*)h16;   // one uint4 = 8 f16
  const half2v ones = {(_Float16)1.f, (_Float16)1.f};
  float acc[8] = {0.f, 0.f, 0.f, 0.f, 0.f, 0.f, 0.f, 0.f};
  float denom = 0.f;
  int i = start + hl;
  for (; i + 2 < end; i += 4) {  // edges i and i+2 in this half-wave
    int s0 = src_csr[i], s1 = src_csr[i + 2];
    float w0 = pexp[i * 4 + head];
    float w1 = pexp[(i + 2) * 4 + head];
    uint4 x = h4[(size_t)s0 * 32 + l5];
    uint4 y = h4[(size_t)s1 * 32 + l5];
    half2v w01 = pack_rtz(w0, w1);
    denom = __builtin_amdgcn_fdot2(w01, ones, denom, false);
    acc[0] = __builtin_amdgcn_fdot2(w01, __builtin_bit_cast(half2v, __builtin_amdgcn_perm(y.x, x.x, 0x05040100u)), acc[0], false);
    acc[1] = __builtin_amdgcn_fdot2(w01, __builtin_bit_cast(half2v, __builtin_amdgcn_perm(y.x, x.x, 0x07060302u)), acc[1], false);
    acc[2] = __builtin_amdgcn_fdot2(w01, __builtin_bit_cast(half2v, __builtin_amdgcn_perm(y.y, x.y, 0x05040100u)), acc[2], false);
    acc[3] = __builtin_amdgcn_fdot2(w01, __builtin_bit_cast(half2v, __builtin_amdgcn_perm(y.y, x.y, 0x07060302u)), acc[3], false);
    acc[4] = __builtin_amdgcn_fdot2(w01, __builtin_bit_cast(half2v, __builtin_amdgcn_perm(y.z, x.z, 0x05040100u)), acc[4], false);
    acc[5] = __builtin_amdgcn_fdot2(w01, __builtin_bit_cast(half2v, __builtin_amdgcn_perm(y.z, x.z, 0x07060302u)), acc[5], false);
    acc[6] = __builtin_amdgcn_fdot2(w01, __builtin_bit_cast(half2v, __builtin_amdgcn_perm(y.w, x.w, 0x05040100u)), acc[6], false);
    acc[7] = __builtin_amdgcn_fdot2(w01, __builtin_bit_cast(half2v, __builtin_amdgcn_perm(y.w, x.w, 0x07060302u)), acc[7], false);
  }
  if (i < end) {                 // tail edge (w1 = 0)
    int s0 = src_csr[i];
    float w0 = pexp[i * 4 + head];
    uint4 x = h4[(size_t)s0 * 32 + l5];
    half2v w01 = pack_rtz(w0, 0.f);
    denom = __builtin_amdgcn_fdot2(w01, ones, denom, false);
    acc[0] = __builtin_amdgcn_fdot2(w01, __builtin_bit_cast(half2v, __builtin_amdgcn_perm(x.x, x.x, 0x05040100u)), acc[0], false);
    acc[1] = __builtin_amdgcn_fdot2(w01, __builtin_bit_cast(half2v, __builtin_amdgcn_perm(x.x, x.x, 0x07060302u)), acc[1], false);
    acc[2] = __builtin_amdgcn_fdot2(w01, __builtin_bit_cast(half2v, __builtin_amdgcn_perm(x.y, x.y, 0x05040100u)), acc[2], false);
    acc[3] = __builtin_amdgcn_fdot2(w01, __builtin_bit_cast(half2v, __builtin_amdgcn_perm(x.y, x.y, 0x07060302u)), acc[3], false);
    acc[4] = __builtin_amdgcn_fdot2(w01, __builtin_bit_cast(half2v, __builtin_amdgcn_perm(x.z, x.z, 0x05040100u)), acc[4], false);
    acc[5] = __builtin_amdgcn_fdot2(w01, __builtin_bit_cast(half2v, __builtin_amdgcn_perm(x.z, x.z, 0x07060302u)), acc[5], false);
    acc[6] = __builtin_amdgcn_fdot2(w01, __builtin_bit_cast(half2v, __builtin_amdgcn_perm(x.w, x.w, 0x05040100u)), acc[6], false);
    acc[7] = __builtin_amdgcn_fdot2(w01, __builtin_bit_cast(half2v, __builtin_amdgcn_perm(x.w, x.w, 0x07060302u)), acc[7], false);
  }
  // combine the two half-waves (even/odd edges)
  #pragma unroll
  for (int j = 0; j < 8; ++j) acc[j] += __shfl_xor(acc[j], 32);
  denom += __shfl_xor(denom, 32);
  float inv = 1.f / denom;
  float o[8];
  float4 b0 = *(const float4*)&bias[l5 * 8];
  float4 b1 = *(const float4*)&bias[l5 * 8 + 4];
  o[0] = acc[0] * inv + b0.x; o[1] = acc[1] * inv + b0.y;
  o[2] = acc[2] * inv + b0.z; o[3] = acc[3] * inv + b0.w;
  o[4] = acc[4] * inv + b1.x; o[5] = acc[5] * inv + b1.y;
  o[6] = acc[6] * inv + b1.z; o[7] = acc[7] * inv + b1.w;
  // LayerNorm over 256 ch (row spread across 32 lanes; halves identical)
  float s = 0.f;
  #pragma unroll
  for (int j = 0; j < 8; ++j) s += o[j];
  #pragma unroll
  for (int off = 16; off; off >>= 1) s += __shfl_xor(s, off);
  float mu = s * (1.f / 256.f);
  float var = 0.f;
  #pragma unroll
  for (int j = 0; j < 8; ++j) { float d = o[j] - mu; var += d * d; }
  #pragma unroll
  for (int off = 16; off; off >>= 1) var += __shfl_xor(var, off);
  float r = rsqrtf(var * (1.f / 256.f) + 1e-5f);
  float4 g0 = *(const float4*)&g[l5 * 8];
  float4 g1 = *(const float4*)&g[l5 * 8 + 4];
  float4 e0 = *(const float4*)&be[l5 * 8];
  float4 e1 = *(const float4*)&be[l5 * 8 + 4];
  float gg[8] = {g0.x, g0.y, g0.z, g0.w, g1.x, g1.y, g1.z, g1.w};
  float ee[8] = {e0.x, e0.y, e0.z, e0.w, e1.x, e1.y, e1.z, e1.w};
  float y[8];
  #pragma unroll
  for (int j = 0; j < 8; ++j) {
    float t = (o[j] - mu) * r * gg[j] + ee[j];
    y[j] = (t > 0.f) ? t : expm1f(t);
  }
  if (hl == 0) {
    float4 y0 = make_float4(y[0], y[1], y[2], y[3]);
    float4 y1 = make_float4(y[4], y[5], y[6], y[7]);
    *(float4*)&out[(size_t)node * 256 + l5 * 8] = y0;
    *(float4*)&out[(size_t)node * 256 + l5 * 8 + 4] = y1;
  }
}

// ---------------- fused aggregation + LayerNorm + ELU, H=1 (64 ch) ------------
// Quarter-wave (16 lanes x 8B f16) per source row; 2 edges fused via v_dot2.
__global__ __launch_bounds__(256) void agg1_ln_kernel(const _Float16* __restrict__ h16,
                                                      const float* __restrict__ pexp,
                                                      const int* __restrict__ offsets,
                                                      const int* __restrict__ src_csr,
                                                      const float* __restrict__ bias,
                                                      const float* __restrict__ g,
                                                      const float* __restrict__ be,
                                                      float* __restrict__ out, int n) {
  int wid = threadIdx.x >> 6, lane = threadIdx.x & 63;
  int node = blockIdx.x * 4 + wid;
  if (node >= n) return;
  int start = offsets[node], end = offsets[node + 1];
  int qi = lane >> 4;            // quarter index (edge offset)
  int ql = lane & 15;            // channels ql*4 .. ql*4+3
  const uint2* h2 = (const uint2*)h16;   // one uint2 = 4 f16
  const half2v ones = {(_Float16)1.f, (_Float16)1.f};
  float acc[4] = {0.f, 0.f, 0.f, 0.f};
  float denom = 0.f;
  int i = start + qi;
  for (; i + 4 < end; i += 8) {  // edges i and i+4 in this quarter
    int s0 = src_csr[i], s1 = src_csr[i + 4];
    float w0 = pexp[i], w1 = pexp[i + 4];
    uint2 x = h2[(size_t)s0 * 16 + ql];
    uint2 y = h2[(size_t)s1 * 16 + ql];
    half2v w01 = pack_rtz(w0, w1);
    denom = __builtin_amdgcn_fdot2(w01, ones, denom, false);
    acc[0] = __builtin_amdgcn_fdot2(w01, __builtin_bit_cast(half2v, __builtin_amdgcn_perm(y.x, x.x, 0x05040100u)), acc[0], false);
    acc[1] = __builtin_amdgcn_fdot2(w01, __builtin_bit_cast(half2v, __builtin_amdgcn_perm(y.x, x.x, 0x07060302u)), acc[1], false);
    acc[2] = __builtin_amdgcn_fdot2(w01, __builtin_bit_cast(half2v, __builtin_amdgcn_perm(y.y, x.y, 0x05040100u)), acc[2], false);
    acc[3] = __builtin_amdgcn_fdot2(w01, __builtin_bit_cast(half2v, __builtin_amdgcn_perm(y.y, x.y, 0x07060302u)), acc[3], false);
  }
  if (i < end) {
    int s0 = src_csr[i];
    float w0 = pexp[i];
    uint2 x = h2[(size_t)s0 * 16 + ql];
    half2v w01 = pack_rtz(w0, 0.f);
    denom = __builtin_amdgcn_fdot2(w01, ones, denom, false);
    acc[0] = __builtin_amdgcn_fdot2(w01, __builtin_bit_cast(half2v, __builtin_amdgcn_perm(x.x, x.x, 0x05040100u)), acc[0], false);
    acc[1] = __builtin_amdgcn_fdot2(w01, __builtin_bit_cast(half2v, __builtin_amdgcn_perm(x.x, x.x, 0x07060302u)), acc[1], false);
    acc[2] = __builtin_amdgcn_fdot2(w01, __builtin_bit_cast(half2v, __builtin_amdgcn_perm(x.y, x.y, 0x05040100u)), acc[2], false);
    acc[3] = __builtin_amdgcn_fdot2(w01, __builtin_bit_cast(half2v, __builtin_amdgcn_perm(x.y, x.y, 0x07060302u)), acc[3], false);
  }
  // combine four quarter-waves
  #pragma unroll
  for (int off = 32; off >= 16; off >>= 1) {
    #pragma unroll
    for (int j = 0; j < 4; ++j) acc[j] += __shfl_xor(acc[j], off);
    denom += __shfl_xor(denom, off);
  }
  float inv = 1.f / denom;
  float4 b4 = *(const float4*)&bias[ql * 4];
  float o[4];
  o[0] = acc[0] * inv + b4.x; o[1] = acc[1] * inv + b4.y;
  o[2] = acc[2] * inv + b4.z; o[3] = acc[3] * inv + b4.w;
  // LayerNorm over 64 ch (row spread across 16 lanes; quarters identical)
  float s = o[0] + o[1] + o[2] + o[3];
  #pragma unroll
  for (int off = 8; off; off >>= 1) s += __shfl_xor(s, off);
  float mu = s * (1.f / 64.f);
  float var = 0.f;
  #pragma unroll
  for (int j = 0; j < 4; ++j) { float d = o[j] - mu; var += d * d; }
  #pragma unroll
  for (int off = 8; off; off >>= 1) var += __shfl_xor(var, off);
  float r = rsqrtf(var * (1.f / 64.f) + 1e-5f);
  float4 g4 = *(const float4*)&g[ql * 4];
  float4 e4 = *(const float4*)&be[ql * 4];
  float gg[4] = {g4.x, g4.y, g4.z, g4.w};
  float ee[4] = {e4.x, e4.y, e4.z, e4.w};
  float y[4];
  #pragma unroll
  for (int j = 0; j < 4; ++j) {
    float t = (o[j] - mu) * r * gg[j] + ee[j];
    y[j] = (t > 0.f) ? t : expm1f(t);
  }
  if (qi == 0) {
    *(float4*)&out[(size_t)node * 64 + ql * 4] = make_float4(y[0], y[1], y[2], y[3]);
  }
}

// ---------------- fused pool + MLP head (batch is sorted) ----------------
__global__ __launch_bounds__(256) void graph_head_kernel(const float* __restrict__ h,
                                                         const int* __restrict__ batch, int N,
                                                         const float* __restrict__ Wg,
                                                         const float* __restrict__ bg,
                                                         const float* __restrict__ Wg2,
                                                         const float* __restrict__ bg2,
                                                         const float* __restrict__ Wo,
                                                         const float* __restrict__ bo,
                                                         float* __restrict__ out) {
  __shared__ int bounds[2];
  __shared__ float part[4][64];
  __shared__ float gm[64];
  __shared__ float z1[128];
  __shared__ float z2[64];
  int g = blockIdx.x;
  int tid = threadIdx.x;
  if (tid < 2) {
    int target = g + tid;  // lower_bound(batch, target)
    int lo = 0, hi = N;
    while (lo < hi) {
      int mid = (lo + hi) >> 1;
      if (batch[mid] < target) lo = mid + 1; else hi = mid;
    }
    bounds[tid] = lo;
  }
  __syncthreads();
  int lo = bounds[0], hi = bounds[1];
  int c = tid & 63, sub = tid >> 6;
  float acc = 0.f;
  for (int r = lo + sub; r < hi; r += 4) acc += h[(size_t)r * 64 + c];
  part[sub][c] = acc;
  __syncthreads();
  float invc = 1.f / fmaxf((float)(hi - lo), 1.f);
  if (tid < 64) gm[tid] = (part[0][tid] + part[1][tid] + part[2][tid] + part[3][tid]) * invc;
  __syncthreads();
  if (tid < 128) {
    float a = bg[tid];
    for (int k = 0; k < 64; ++k) a += gm[k] * Wg[k * 128 + tid];
    z1[tid] = fmaxf(a, 0.f);
  }
  __syncthreads();
  if (tid < 64) {
    float a = bg2[tid];
    for (int k = 0; k < 128; ++k) a += z1[k] * Wg2[k * 64 + tid];
    z2[tid] = fmaxf(a, 0.f);
  }
  __syncthreads();
  if (tid < 5) {
    float a = bo[tid];
    for (int k = 0; k < 64; ++k) a += z2[k] * Wo[k * 5 + tid];
    out[g * 5 + tid] = a;
  }
}

// ---------------- launch ----------------
extern "C" void kernel_launch(void* const* d_in, const int* in_sizes, int n_in,
                              void* d_out, int out_size, void* d_ws, size_t ws_size,
                              hipStream_t stream) {
  const float* x   = (const float*)d_in[0];
  const int* ei    = (const int*)d_in[1];
  const int* batch = (const int*)d_in[2];
  const float* W1  = (const float*)d_in[3];
  const float* a1s = (const float*)d_in[4];
  const float* a1d = (const float*)d_in[5];
  const float* b1  = (const float*)d_in[6];
  const float* g1  = (const float*)d_in[7];
  const float* be1 = (const float*)d_in[8];
  const float* W2  = (const float*)d_in[9];
  const float* a2s = (const float*)d_in[10];
  const float* a2d = (const float*)d_in[11];
  const float* b2  = (const float*)d_in[12];
  const float* g2  = (const float*)d_in[13];
  const float* be2 = (const float*)d_in[14];
  const float* W3  = (const float*)d_in[15];
  const float* a3s = (const float*)d_in[16];
  const float* a3d = (const float*)d_in[17];
  const float* b3  = (const float*)d_in[18];
  const float* g3  = (const float*)d_in[19];
  const float* be3 = (const float*)d_in[20];
  const float* Wg  = (const float*)d_in[21];
  const float* bg  = (const float*)d_in[22];
  const float* Wg2 = (const float*)d_in[23];
  const float* bg2 = (const float*)d_in[24];
  const float* Wo  = (const float*)d_in[25];
  const float* bo  = (const float*)d_in[26];

  const int N = in_sizes[2];
  const int E = in_sizes[1] / 2;
  const int ET = E + N;  // with self-loops
  const int G = 64;

  // workspace carve-up (256B aligned)
  char* ws = (char*)d_ws;
  size_t off = 0;
  auto carve = [&](size_t bytes) {
    void* p = ws + off;
    off = (off + bytes + 255) & ~(size_t)255;
    return p;
  };
  int* counts   = (int*)carve((size_t)N * 4);
  int* offsets  = (int*)carve((size_t)(N + 1) * 4);
  int* cursor   = (int*)carve((size_t)N * 4);
  int* src_csr  = (int*)carve((size_t)ET * 4);
  int* dst_csr  = (int*)carve((size_t)ET * 4);
  float* pexp   = (float*)carve((size_t)ET * 4 * 4);
  float* asrc   = (float*)carve((size_t)N * 4 * 4);
  float* adst   = (float*)carve((size_t)N * 4 * 4);
  float* bufB   = (float*)carve((size_t)N * 256 * 4);
  float* buf3   = (float*)carve((size_t)N * 64 * 4);
  _Float16* h16 = (_Float16*)carve((size_t)N * 256 * 2);
  (void)ws_size;

  const int egrid = (ET + 255) / 256;
  const int ngrid4 = (N + 3) / 4;
  const int mblocks = (N + 127) / 128;

  // --- CSR (dst-sorted src/dst lists), rebuilt every call ---
  hipMemsetAsync(counts, 0, (size_t)N * 4, stream);
  count_kernel<<<egrid, 256, 0, stream>>>(ei, E, N, counts);
  scan_kernel<<<1, 1024, 0, stream>>>(counts, offsets, cursor, N);
  scatter_kernel<<<egrid, 256, 0, stream>>>(ei, E, N, cursor, src_csr, dst_csr);

  // --- layer 1 ---
  gemm_mfma_kernel<16, 4><<<mblocks, 256, 0, stream>>>(x, W1, a1s, a1d, h16, asrc, adst, N, 128);
  edge_score_kernel<4><<<egrid, 256, 0, stream>>>(asrc, adst, src_csr, dst_csr, ET, pexp);
  agg4_ln_kernel<<<ngrid4, 256, 0, stream>>>(h16, pexp, offsets, src_csr, b1, g1, be1, bufB, N);

  // --- layer 2 ---
  gemm_mfma_kernel<16, 4><<<mblocks, 256, 0, stream>>>(bufB, W2, a2s, a2d, h16, asrc, adst, N, 256);
  edge_score_kernel<4><<<egrid, 256, 0, stream>>>(asrc, adst, src_csr, dst_csr, ET, pexp);
  agg4_ln_kernel<<<ngrid4, 256, 0, stream>>>(h16, pexp, offsets, src_csr, b2, g2, be2, bufB, N);

  // --- layer 3 (H=1, C=64) ---
  gemm_mfma_kernel<4, 1><<<mblocks, 256, 0, stream>>>(bufB, W3, a3s, a3d, h16, asrc, adst, N, 256);
  edge_score_kernel<1><<<egrid, 256, 0, stream>>>(asrc, adst, src_csr, dst_csr, ET, pexp);
  agg1_ln_kernel<<<ngrid4, 256, 0, stream>>>(h16, pexp, offsets, src_csr, b3, g3, be3, buf3, N);

  // --- fused pool + MLP head ---
  graph_head_kernel<<<G, 256, 0, stream>>>(buf3, batch, N, Wg, bg, Wg2, bg2, Wo, bo,
                                           (float*)d_out);
}

// Round 8
// 442.374 us; speedup vs baseline: 5.9675x; 1.0887x over previous
//
#include <hip/hip_runtime.h>
#include <math.h>

typedef _Float16 half2v __attribute__((ext_vector_type(2)));
typedef _Float16 half4v __attribute__((ext_vector_type(4)));
typedef _Float16 half8v __attribute__((ext_vector_type(8)));
typedef float floatx4 __attribute__((ext_vector_type(4)));

static __device__ __forceinline__ half2v pack_rtz(float a, float b) {
  return __builtin_bit_cast(half2v, __builtin_amdgcn_cvt_pkrtz(a, b));
}

// ---------------- CSR build ----------------
__global__ void count_kernel(const int* __restrict__ ei, int E, int N, int* __restrict__ counts) {
  int e = blockIdx.x * 256 + threadIdx.x;
  if (e >= E + N) return;
  int d = (e < E) ? ei[E + e] : (e - E);   // row1 = dst
  atomicAdd(&counts[d], 1);
}

// phase 1: per-1024-chunk exclusive scan + chunk totals
__global__ __launch_bounds__(1024) void scan1_kernel(const int* __restrict__ counts,
                                                     int* __restrict__ offsets,
                                                     int* __restrict__ blocksums, int n) {
  __shared__ int wsum[16];
  int tid = threadIdx.x, lane = tid & 63, wid = tid >> 6;
  int i = blockIdx.x * 1024 + tid;
  int v = (i < n) ? counts[i] : 0;
  int x = v;
  #pragma unroll
  for (int off = 1; off < 64; off <<= 1) {
    int t = __shfl_up(x, off);
    if (lane >= off) x += t;
  }
  if (lane == 63) wsum[wid] = x;
  __syncthreads();
  if (wid == 0) {
    int w = (lane < 16) ? wsum[lane] : 0;
    #pragma unroll
    for (int off = 1; off < 16; off <<= 1) {
      int t = __shfl_up(w, off);
      if (lane >= off) w += t;
    }
    if (lane < 16) wsum[lane] = w;
  }
  __syncthreads();
  int wpre = (wid > 0) ? wsum[wid - 1] : 0;
  if (i < n) offsets[i] = wpre + x - v;    // exclusive within chunk
  if (tid == 0) blocksums[blockIdx.x] = wsum[15];
}

// phase 2: scan chunk totals (nb <= 1024); writes grand total to offsets[n]
__global__ __launch_bounds__(1024) void scan2_kernel(int* __restrict__ blocksums,
                                                     int* __restrict__ offsets, int nb, int n) {
  __shared__ int wsum[16];
  int tid = threadIdx.x, lane = tid & 63, wid = tid >> 6;
  int v = (tid < nb) ? blocksums[tid] : 0;
  int x = v;
  #pragma unroll
  for (int off = 1; off < 64; off <<= 1) {
    int t = __shfl_up(x, off);
    if (lane >= off) x += t;
  }
  if (lane == 63) wsum[wid] = x;
  __syncthreads();
  if (wid == 0) {
    int w = (lane < 16) ? wsum[lane] : 0;
    #pragma unroll
    for (int off = 1; off < 16; off <<= 1) {
      int t = __shfl_up(w, off);
      if (lane >= off) w += t;
    }
    if (lane < 16) wsum[lane] = w;
  }
  __syncthreads();
  int wpre = (wid > 0) ? wsum[wid - 1] : 0;
  if (tid < nb) blocksums[tid] = wpre + x - v;   // exclusive chunk base
  if (tid == 0) offsets[n] = wsum[15];
}

// phase 3: add chunk bases; init cursor
__global__ void scan3_kernel(int* __restrict__ offsets, int* __restrict__ cursor,
                             const int* __restrict__ blocksums, int n) {
  int i = blockIdx.x * 256 + threadIdx.x;
  if (i < n) {
    int o = offsets[i] + blocksums[i >> 10];
    offsets[i] = o;
    cursor[i] = o;
  }
}

__global__ void scatter_kernel(const int* __restrict__ ei, int E, int N,
                               int* __restrict__ cursor, int* __restrict__ src_csr) {
  int e = blockIdx.x * 256 + threadIdx.x;
  if (e >= E + N) return;
  int s = (e < E) ? ei[e] : (e - E);
  int d = (e < E) ? ei[E + e] : (e - E);
  int pos = atomicAdd(&cursor[d], 1);
  src_csr[pos] = s;
}

// ---------------- f16 MFMA GEMM + fused alpha epilogue ----------------
template <int NT, int H>   // Nc = NT*16
__global__ __launch_bounds__(256) void gemm_mfma_kernel(const float* __restrict__ A,
                                                        const float* __restrict__ W,
                                                        const float* __restrict__ als,
                                                        const float* __restrict__ ald,
                                                        _Float16* __restrict__ out16,
                                                        float* __restrict__ asrc,
                                                        float* __restrict__ adst,
                                                        int M, int K) {
  constexpr int Nc = NT * 16;
  constexpr int BM = 128, BK = 32;
  constexpr int CPH = NT / H;            // col-tiles per head
  __shared__ _Float16 As[BM][40];
  __shared__ _Float16 Ws[Nc][40];
  int bm = blockIdx.x * BM;
  int tid = threadIdx.x;
  int w = tid >> 6, l = tid & 63;
  int lr = l & 15, lg = l >> 4;

  floatx4 acc[2][NT];
  #pragma unroll
  for (int rf = 0; rf < 2; ++rf)
    #pragma unroll
    for (int ct = 0; ct < NT; ++ct) acc[rf][ct] = (floatx4){0.f, 0.f, 0.f, 0.f};

  for (int k0 = 0; k0 < K; k0 += BK) {
    #pragma unroll
    for (int i = 0; i < 4; ++i) {
      int idx = tid + i * 256;          // 1024 float4 slots
      int r = idx >> 3, kq = idx & 7;
      int gr = bm + r;
      float4 v = make_float4(0.f, 0.f, 0.f, 0.f);
      if (gr < M) v = *(const float4*)&A[(size_t)gr * K + k0 + kq * 4];
      half4v hv = {(_Float16)v.x, (_Float16)v.y, (_Float16)v.z, (_Float16)v.w};
      *(half4v*)&As[r][kq * 4] = hv;
    }
    #pragma unroll
    for (int i = 0; i < NT; ++i) {
      int p = i * 256 + tid;            // pair index over (BK/2)*Nc = 16*Nc
      int col = p % Nc, kp = p / Nc;    // kp in 0..15
      float w0 = W[(size_t)(k0 + 2 * kp) * Nc + col];
      float w1 = W[(size_t)(k0 + 2 * kp + 1) * Nc + col];
      half2v hv = {(_Float16)w0, (_Float16)w1};
      *(half2v*)&Ws[col][2 * kp] = hv;
    }
    __syncthreads();
    half8v a0 = *(half8v*)&As[w * 32 + lr][lg * 8];
    half8v a1 = *(half8v*)&As[w * 32 + 16 + lr][lg * 8];
    #pragma unroll
    for (int ct = 0; ct < NT; ++ct) {
      half8v b = *(half8v*)&Ws[ct * 16 + lr][lg * 8];
      acc[0][ct] = __builtin_amdgcn_mfma_f32_16x16x32_f16(a0, b, acc[0][ct], 0, 0, 0);
      acc[1][ct] = __builtin_amdgcn_mfma_f32_16x16x32_f16(a1, b, acc[1][ct], 0, 0, 0);
    }
    __syncthreads();
  }
  float als_r[NT], ald_r[NT];
  #pragma unroll
  for (int ct = 0; ct < NT; ++ct) {
    als_r[ct] = als[ct * 16 + lr];
    ald_r[ct] = ald[ct * 16 + lr];
  }
  #pragma unroll
  for (int rf = 0; rf < 2; ++rf)
    #pragma unroll
    for (int q = 0; q < 4; ++q) {
      int row = bm + w * 32 + rf * 16 + lg * 4 + q;
      float ps[H], pd[H];
      #pragma unroll
      for (int hh = 0; hh < H; ++hh) {
        float s = 0.f, d = 0.f;
        #pragma unroll
        for (int c2 = 0; c2 < CPH; ++c2) {
          int ct = hh * CPH + c2;
          s += acc[rf][ct][q] * als_r[ct];
          d += acc[rf][ct][q] * ald_r[ct];
        }
        ps[hh] = s; pd[hh] = d;
      }
      #pragma unroll
      for (int off = 1; off < 16; off <<= 1) {
        #pragma unroll
        for (int hh = 0; hh < H; ++hh) {
          ps[hh] += __shfl_xor(ps[hh], off);
          pd[hh] += __shfl_xor(pd[hh], off);
        }
      }
      if (row < M) {
        if (lr == 0) {
          #pragma unroll
          for (int hh = 0; hh < H; ++hh) asrc[row * H + hh] = ps[hh];
        } else if (lr == 1) {
          #pragma unroll
          for (int hh = 0; hh < H; ++hh) adst[row * H + hh] = pd[hh];
        }
        #pragma unroll
        for (int ct = 0; ct < NT; ++ct)
          out16[(size_t)row * Nc + ct * 16 + lr] = (_Float16)acc[rf][ct][q];
      }
    }
}

// ---------------- fused score + aggregation + LayerNorm + ELU, H=4 ----------
// Half-wave (32 lanes x 16B f16) per source row; scores computed inline from
// L2-resident asrc table; 2 edges fused via v_dot2.
__global__ __launch_bounds__(256) void agg4_ln_kernel(const _Float16* __restrict__ h16,
                                                      const float* __restrict__ asrc,
                                                      const float* __restrict__ adst,
                                                      const int* __restrict__ offsets,
                                                      const int* __restrict__ src_csr,
                                                      const float* __restrict__ bias,
                                                      const float* __restrict__ g,
                                                      const float* __restrict__ be,
                                                      float* __restrict__ out, int n) {
  int wid = threadIdx.x >> 6, lane = threadIdx.x & 63;
  int node = blockIdx.x * 4 + wid;
  if (node >= n) return;
  int start = offsets[node], end = offsets[node + 1];
  int hl = lane >> 5;            // half-wave index (edge parity)
  int l5 = lane & 31;            // channels l5*8 .. l5*8+7
  int head = l5 >> 3;
  float adh = adst[node * 4 + head];
  const uint4* h4 = (const uint4*)h16;   // one uint4 = 8 f16
  const half2v ones = {(_Float16)1.f, (_Float16)1.f};
  float acc[8] = {0.f, 0.f, 0.f, 0.f, 0.f, 0.f, 0.f, 0.f};
  float denom = 0.f;
  int i = start + hl;
  for (; i + 2 < end; i += 4) {  // edges i and i+2 in this half-wave
    int s0 = src_csr[i], s1 = src_csr[i + 2];
    float sc0 = asrc[s0 * 4 + head] + adh;
    float sc1 = asrc[s1 * 4 + head] + adh;
    sc0 = (sc0 >= 0.f) ? sc0 : 0.2f * sc0;
    sc1 = (sc1 >= 0.f) ? sc1 : 0.2f * sc1;
    float w0 = __expf(sc0), w1 = __expf(sc1);
    uint4 x = h4[(size_t)s0 * 32 + l5];
    uint4 y = h4[(size_t)s1 * 32 + l5];
    half2v w01 = pack_rtz(w0, w1);
    denom = __builtin_amdgcn_fdot2(w01, ones, denom, false);
    acc[0] = __builtin_amdgcn_fdot2(w01, __builtin_bit_cast(half2v, __builtin_amdgcn_perm(y.x, x.x, 0x05040100u)), acc[0], false);
    acc[1] = __builtin_amdgcn_fdot2(w01, __builtin_bit_cast(half2v, __builtin_amdgcn_perm(y.x, x.x, 0x07060302u)), acc[1], false);
    acc[2] = __builtin_amdgcn_fdot2(w01, __builtin_bit_cast(half2v, __builtin_amdgcn_perm(y.y, x.y, 0x05040100u)), acc[2], false);
    acc[3] = __builtin_amdgcn_fdot2(w01, __builtin_bit_cast(half2v, __builtin_amdgcn_perm(y.y, x.y, 0x07060302u)), acc[3], false);
    acc[4] = __builtin_amdgcn_fdot2(w01, __builtin_bit_cast(half2v, __builtin_amdgcn_perm(y.z, x.z, 0x05040100u)), acc[4], false);
    acc[5] = __builtin_amdgcn_fdot2(w01, __builtin_bit_cast(half2v, __builtin_amdgcn_perm(y.z, x.z, 0x07060302u)), acc[5], false);
    acc[6] = __builtin_amdgcn_fdot2(w01, __builtin_bit_cast(half2v, __builtin_amdgcn_perm(y.w, x.w, 0x05040100u)), acc[6], false);
    acc[7] = __builtin_amdgcn_fdot2(w01, __builtin_bit_cast(half2v, __builtin_amdgcn_perm(y.w, x.w, 0x07060302u)), acc[7], false);
  }
  if (i < end) {                 // tail edge (w1 = 0)
    int s0 = src_csr[i];
    float sc0 = asrc[s0 * 4 + head] + adh;
    sc0 = (sc0 >= 0.f) ? sc0 : 0.2f * sc0;
    float w0 = __expf(sc0);
    uint4 x = h4[(size_t)s0 * 32 + l5];
    half2v w01 = pack_rtz(w0, 0.f);
    denom = __builtin_amdgcn_fdot2(w01, ones, denom, false);
    acc[0] = __builtin_amdgcn_fdot2(w01, __builtin_bit_cast(half2v, __builtin_amdgcn_perm(x.x, x.x, 0x05040100u)), acc[0], false);
    acc[1] = __builtin_amdgcn_fdot2(w01, __builtin_bit_cast(half2v, __builtin_amdgcn_perm(x.x, x.x, 0x07060302u)), acc[1], false);
    acc[2] = __builtin_amdgcn_fdot2(w01, __builtin_bit_cast(half2v, __builtin_amdgcn_perm(x.y, x.y, 0x05040100u)), acc[2], false);
    acc[3] = __builtin_amdgcn_fdot2(w01, __builtin_bit_cast(half2v, __builtin_amdgcn_perm(x.y, x.y, 0x07060302u)), acc[3], false);
    acc[4] = __builtin_amdgcn_fdot2(w01, __builtin_bit_cast(half2v, __builtin_amdgcn_perm(x.z, x.z, 0x05040100u)), acc[4], false);
    acc[5] = __builtin_amdgcn_fdot2(w01, __builtin_bit_cast(half2v, __builtin_amdgcn_perm(x.z, x.z, 0x07060302u)), acc[5], false);
    acc[6] = __builtin_amdgcn_fdot2(w01, __builtin_bit_cast(half2v, __builtin_amdgcn_perm(x.w, x.w, 0x05040100u)), acc[6], false);
    acc[7] = __builtin_amdgcn_fdot2(w01, __builtin_bit_cast(half2v, __builtin_amdgcn_perm(x.w, x.w, 0x07060302u)), acc[7], false);
  }
  // combine the two half-waves (even/odd edges)
  #pragma unroll
  for (int j = 0; j < 8; ++j) acc[j] += __shfl_xor(acc[j], 32);
  denom += __shfl_xor(denom, 32);
  float inv = 1.f / denom;
  float o[8];
  float4 b0 = *(const float4*)&bias[l5 * 8];
  float4 b1 = *(const float4*)&bias[l5 * 8 + 4];
  o[0] = acc[0] * inv + b0.x; o[1] = acc[1] * inv + b0.y;
  o[2] = acc[2] * inv + b0.z; o[3] = acc[3] * inv + b0.w;
  o[4] = acc[4] * inv + b1.x; o[5] = acc[5] * inv + b1.y;
  o[6] = acc[6] * inv + b1.z; o[7] = acc[7] * inv + b1.w;
  float s = 0.f;
  #pragma unroll
  for (int j = 0; j < 8; ++j) s += o[j];
  #pragma unroll
  for (int off = 16; off; off >>= 1) s += __shfl_xor(s, off);
  float mu = s * (1.f / 256.f);
  float var = 0.f;
  #pragma unroll
  for (int j = 0; j < 8; ++j) { float d = o[j] - mu; var += d * d; }
  #pragma unroll
  for (int off = 16; off; off >>= 1) var += __shfl_xor(var, off);
  float r = rsqrtf(var * (1.f / 256.f) + 1e-5f);
  float4 g0 = *(const float4*)&g[l5 * 8];
  float4 g1 = *(const float4*)&g[l5 * 8 + 4];
  float4 e0 = *(const float4*)&be[l5 * 8];
  float4 e1 = *(const float4*)&be[l5 * 8 + 4];
  float gg[8] = {g0.x, g0.y, g0.z, g0.w, g1.x, g1.y, g1.z, g1.w};
  float ee[8] = {e0.x, e0.y, e0.z, e0.w, e1.x, e1.y, e1.z, e1.w};
  float y[8];
  #pragma unroll
  for (int j = 0; j < 8; ++j) {
    float t = (o[j] - mu) * r * gg[j] + ee[j];
    y[j] = (t > 0.f) ? t : expm1f(t);
  }
  if (hl == 0) {
    float4 y0 = make_float4(y[0], y[1], y[2], y[3]);
    float4 y1 = make_float4(y[4], y[5], y[6], y[7]);
    *(float4*)&out[(size_t)node * 256 + l5 * 8] = y0;
    *(float4*)&out[(size_t)node * 256 + l5 * 8 + 4] = y1;
  }
}

// ---------------- fused score + aggregation + LayerNorm + ELU, H=1 ----------
__global__ __launch_bounds__(256) void agg1_ln_kernel(const _Float16* __restrict__ h16,
                                                      const float* __restrict__ asrc,
                                                      const float* __restrict__ adst,
                                                      const int* __restrict__ offsets,
                                                      const int* __restrict__ src_csr,
                                                      const float* __restrict__ bias,
                                                      const float* __restrict__ g,
                                                      const float* __restrict__ be,
                                                      float* __restrict__ out, int n) {
  int wid = threadIdx.x >> 6, lane = threadIdx.x & 63;
  int node = blockIdx.x * 4 + wid;
  if (node >= n) return;
  int start = offsets[node], end = offsets[node + 1];
  int qi = lane >> 4;            // quarter index (edge offset)
  int ql = lane & 15;            // channels ql*4 .. ql*4+3
  float adh = adst[node];
  const uint2* h2 = (const uint2*)h16;   // one uint2 = 4 f16
  const half2v ones = {(_Float16)1.f, (_Float16)1.f};
  float acc[4] = {0.f, 0.f, 0.f, 0.f};
  float denom = 0.f;
  int i = start + qi;
  for (; i + 4 < end; i += 8) {  // edges i and i+4 in this quarter
    int s0 = src_csr[i], s1 = src_csr[i + 4];
    float sc0 = asrc[s0] + adh;
    float sc1 = asrc[s1] + adh;
    sc0 = (sc0 >= 0.f) ? sc0 : 0.2f * sc0;
    sc1 = (sc1 >= 0.f) ? sc1 : 0.2f * sc1;
    float w0 = __expf(sc0), w1 = __expf(sc1);
    uint2 x = h2[(size_t)s0 * 16 + ql];
    uint2 y = h2[(size_t)s1 * 16 + ql];
    half2v w01 = pack_rtz(w0, w1);
    denom = __builtin_amdgcn_fdot2(w01, ones, denom, false);
    acc[0] = __builtin_amdgcn_fdot2(w01, __builtin_bit_cast(half2v, __builtin_amdgcn_perm(y.x, x.x, 0x05040100u)), acc[0], false);
    acc[1] = __builtin_amdgcn_fdot2(w01, __builtin_bit_cast(half2v, __builtin_amdgcn_perm(y.x, x.x, 0x07060302u)), acc[1], false);
    acc[2] = __builtin_amdgcn_fdot2(w01, __builtin_bit_cast(half2v, __builtin_amdgcn_perm(y.y, x.y, 0x05040100u)), acc[2], false);
    acc[3] = __builtin_amdgcn_fdot2(w01, __builtin_bit_cast(half2v, __builtin_amdgcn_perm(y.y, x.y, 0x07060302u)), acc[3], false);
  }
  if (i < end) {
    int s0 = src_csr[i];
    float sc0 = asrc[s0] + adh;
    sc0 = (sc0 >= 0.f) ? sc0 : 0.2f * sc0;
    float w0 = __expf(sc0);
    uint2 x = h2[(size_t)s0 * 16 + ql];
    half2v w01 = pack_rtz(w0, 0.f);
    denom = __builtin_amdgcn_fdot2(w01, ones, denom, false);
    acc[0] = __builtin_amdgcn_fdot2(w01, __builtin_bit_cast(half2v, __builtin_amdgcn_perm(x.x, x.x, 0x05040100u)), acc[0], false);
    acc[1] = __builtin_amdgcn_fdot2(w01, __builtin_bit_cast(half2v, __builtin_amdgcn_perm(x.x, x.x, 0x07060302u)), acc[1], false);
    acc[2] = __builtin_amdgcn_fdot2(w01, __builtin_bit_cast(half2v, __builtin_amdgcn_perm(x.y, x.y, 0x05040100u)), acc[2], false);
    acc[3] = __builtin_amdgcn_fdot2(w01, __builtin_bit_cast(half2v, __builtin_amdgcn_perm(x.y, x.y, 0x07060302u)), acc[3], false);
  }
  #pragma unroll
  for (int off = 32; off >= 16; off >>= 1) {
    #pragma unroll
    for (int j = 0; j < 4; ++j) acc[j] += __shfl_xor(acc[j], off);
    denom += __shfl_xor(denom, off);
  }
  float inv = 1.f / denom;
  float4 b4 = *(const float4*)&bias[ql * 4];
  float o[4];
  o[0] = acc[0] * inv + b4.x; o[1] = acc[1] * inv + b4.y;
  o[2] = acc[2] * inv + b4.z; o[3] = acc[3] * inv + b4.w;
  float s = o[0] + o[1] + o[2] + o[3];
  #pragma unroll
  for (int off = 8; off; off >>= 1) s += __shfl_xor(s, off);
  float mu = s * (1.f / 64.f);
  float var = 0.f;
  #pragma unroll
  for (int j = 0; j < 4; ++j) { float d = o[j] - mu; var += d * d; }
  #pragma unroll
  for (int off = 8; off; off >>= 1) var += __shfl_xor(var, off);
  float r = rsqrtf(var * (1.f / 64.f) + 1e-5f);
  float4 g4 = *(const float4*)&g[ql * 4];
  float4 e4 = *(const float4*)&be[ql * 4];
  float gg[4] = {g4.x, g4.y, g4.z, g4.w};
  float ee[4] = {e4.x, e4.y, e4.z, e4.w};
  float y[4];
  #pragma unroll
  for (int j = 0; j < 4; ++j) {
    float t = (o[j] - mu) * r * gg[j] + ee[j];
    y[j] = (t > 0.f) ? t : expm1f(t);
  }
  if (qi == 0) {
    *(float4*)&out[(size_t)node * 64 + ql * 4] = make_float4(y[0], y[1], y[2], y[3]);
  }
}

// ---------------- fused pool + MLP head (batch is sorted) ----------------
__global__ __launch_bounds__(256) void graph_head_kernel(const float* __restrict__ h,
                                                         const int* __restrict__ batch, int N,
                                                         const float* __restrict__ Wg,
                                                         const float* __restrict__ bg,
                                                         const float* __restrict__ Wg2,
                                                         const float* __restrict__ bg2,
                                                         const float* __restrict__ Wo,
                                                         const float* __restrict__ bo,
                                                         float* __restrict__ out) {
  __shared__ int bounds[2];
  __shared__ float part[4][64];
  __shared__ float gm[64];
  __shared__ float z1[128];
  __shared__ float z2[64];
  int g = blockIdx.x;
  int tid = threadIdx.x;
  if (tid < 2) {
    int target = g + tid;  // lower_bound(batch, target)
    int lo = 0, hi = N;
    while (lo < hi) {
      int mid = (lo + hi) >> 1;
      if (batch[mid] < target) lo = mid + 1; else hi = mid;
    }
    bounds[tid] = lo;
  }
  __syncthreads();
  int lo = bounds[0], hi = bounds[1];
  int c = tid & 63, sub = tid >> 6;
  float acc = 0.f;
  for (int r = lo + sub; r < hi; r += 4) acc += h[(size_t)r * 64 + c];
  part[sub][c] = acc;
  __syncthreads();
  float invc = 1.f / fmaxf((float)(hi - lo), 1.f);
  if (tid < 64) gm[tid] = (part[0][tid] + part[1][tid] + part[2][tid] + part[3][tid]) * invc;
  __syncthreads();
  if (tid < 128) {
    float a = bg[tid];
    for (int k = 0; k < 64; ++k) a += gm[k] * Wg[k * 128 + tid];
    z1[tid] = fmaxf(a, 0.f);
  }
  __syncthreads();
  if (tid < 64) {
    float a = bg2[tid];
    for (int k = 0; k < 128; ++k) a += z1[k] * Wg2[k * 64 + tid];
    z2[tid] = fmaxf(a, 0.f);
  }
  __syncthreads();
  if (tid < 5) {
    float a = bo[tid];
    for (int k = 0; k < 64; ++k) a += z2[k] * Wo[k * 5 + tid];
    out[g * 5 + tid] = a;
  }
}

// ---------------- launch ----------------
extern "C" void kernel_launch(void* const* d_in, const int* in_sizes, int n_in,
                              void* d_out, int out_size, void* d_ws, size_t ws_size,
                              hipStream_t stream) {
  const float* x   = (const float*)d_in[0];
  const int* ei    = (const int*)d_in[1];
  const int* batch = (const int*)d_in[2];
  const float* W1  = (const float*)d_in[3];
  const float* a1s = (const float*)d_in[4];
  const float* a1d = (const float*)d_in[5];
  const float* b1  = (const float*)d_in[6];
  const float* g1  = (const float*)d_in[7];
  const float* be1 = (const float*)d_in[8];
  const float* W2  = (const float*)d_in[9];
  const float* a2s = (const float*)d_in[10];
  const float* a2d = (const float*)d_in[11];
  const float* b2  = (const float*)d_in[12];
  const float* g2  = (const float*)d_in[13];
  const float* be2 = (const float*)d_in[14];
  const float* W3  = (const float*)d_in[15];
  const float* a3s = (const float*)d_in[16];
  const float* a3d = (const float*)d_in[17];
  const float* b3  = (const float*)d_in[18];
  const float* g3  = (const float*)d_in[19];
  const float* be3 = (const float*)d_in[20];
  const float* Wg  = (const float*)d_in[21];
  const float* bg  = (const float*)d_in[22];
  const float* Wg2 = (const float*)d_in[23];
  const float* bg2 = (const float*)d_in[24];
  const float* Wo  = (const float*)d_in[25];
  const float* bo  = (const float*)d_in[26];

  const int N = in_sizes[2];
  const int E = in_sizes[1] / 2;
  const int ET = E + N;  // with self-loops
  const int G = 64;
  const int NB = (N + 1023) / 1024;      // scan chunks (<=1024)

  // workspace carve-up (256B aligned)
  char* ws = (char*)d_ws;
  size_t off = 0;
  auto carve = [&](size_t bytes) {
    void* p = ws + off;
    off = (off + bytes + 255) & ~(size_t)255;
    return p;
  };
  int* counts    = (int*)carve((size_t)N * 4);
  int* offsets   = (int*)carve((size_t)(N + 1) * 4);
  int* cursor    = (int*)carve((size_t)N * 4);
  int* blocksums = (int*)carve((size_t)NB * 4);
  int* src_csr   = (int*)carve((size_t)ET * 4);
  float* asrc    = (float*)carve((size_t)N * 4 * 4);
  float* adst    = (float*)carve((size_t)N * 4 * 4);
  float* bufB    = (float*)carve((size_t)N * 256 * 4);
  float* buf3    = (float*)carve((size_t)N * 64 * 4);
  _Float16* h16  = (_Float16*)carve((size_t)N * 256 * 2);
  (void)ws_size;

  const int egrid = (ET + 255) / 256;
  const int ngrid4 = (N + 3) / 4;
  const int mblocks = (N + 127) / 128;

  // --- CSR (dst-sorted src list), rebuilt every call ---
  hipMemsetAsync(counts, 0, (size_t)N * 4, stream);
  count_kernel<<<egrid, 256, 0, stream>>>(ei, E, N, counts);
  scan1_kernel<<<NB, 1024, 0, stream>>>(counts, offsets, blocksums, N);
  scan2_kernel<<<1, 1024, 0, stream>>>(blocksums, offsets, NB, N);
  scan3_kernel<<<(N + 255) / 256, 256, 0, stream>>>(offsets, cursor, blocksums, N);
  scatter_kernel<<<egrid, 256, 0, stream>>>(ei, E, N, cursor, src_csr);

  // --- layer 1 ---
  gemm_mfma_kernel<16, 4><<<mblocks, 256, 0, stream>>>(x, W1, a1s, a1d, h16, asrc, adst, N, 128);
  agg4_ln_kernel<<<ngrid4, 256, 0, stream>>>(h16, asrc, adst, offsets, src_csr, b1, g1, be1, bufB, N);

  // --- layer 2 ---
  gemm_mfma_kernel<16, 4><<<mblocks, 256, 0, stream>>>(bufB, W2, a2s, a2d, h16, asrc, adst, N, 256);
  agg4_ln_kernel<<<ngrid4, 256, 0, stream>>>(h16, asrc, adst, offsets, src_csr, b2, g2, be2, bufB, N);

  // --- layer 3 (H=1, C=64) ---
  gemm_mfma_kernel<4, 1><<<mblocks, 256, 0, stream>>>(bufB, W3, a3s, a3d, h16, asrc, adst, N, 256);
  agg1_ln_kernel<<<ngrid4, 256, 0, stream>>>(h16, asrc, adst, offsets, src_csr, b3, g3, be3, buf3, N);

  // --- fused pool + MLP head ---
  graph_head_kernel<<<G, 256, 0, stream>>>(buf3, batch, N, Wg, bg, Wg2, bg2, Wo, bo,
                                           (float*)d_out);
}

// Round 9
// 417.885 us; speedup vs baseline: 6.3172x; 1.0586x over previous
//
#include <hip/hip_runtime.h>
#include <math.h>

typedef _Float16 half2v __attribute__((ext_vector_type(2)));
typedef _Float16 half4v __attribute__((ext_vector_type(4)));
typedef _Float16 half8v __attribute__((ext_vector_type(8)));
typedef float floatx4 __attribute__((ext_vector_type(4)));

static __device__ __forceinline__ half2v pack_rtz(float a, float b) {
  return __builtin_bit_cast(half2v, __builtin_amdgcn_cvt_pkrtz(a, b));
}

// ---------------- tiny pre-passes ----------------
__global__ void cvt16_kernel(const float* __restrict__ in, _Float16* __restrict__ out, int n8) {
  int i = blockIdx.x * 256 + threadIdx.x;   // 8 elems per thread
  if (i >= n8) return;
  float4 a = ((const float4*)in)[2 * i];
  float4 b = ((const float4*)in)[2 * i + 1];
  half8v h = {(_Float16)a.x, (_Float16)a.y, (_Float16)a.z, (_Float16)a.w,
              (_Float16)b.x, (_Float16)b.y, (_Float16)b.z, (_Float16)b.w};
  ((half8v*)out)[i] = h;
}

// W [K][Nc] f32 -> Wt [Nc][K] f16. One block per col.
__global__ void wt_kernel(const float* __restrict__ W, _Float16* __restrict__ Wt, int K, int Nc) {
  int col = blockIdx.x;
  int k = threadIdx.x;
  if (k < K) Wt[(size_t)col * K + k] = (_Float16)W[(size_t)k * Nc + col];
}

// ---------------- CSR build ----------------
__global__ void count_kernel(const int* __restrict__ ei, int E, int N, int* __restrict__ counts) {
  int e = blockIdx.x * 256 + threadIdx.x;
  if (e >= E + N) return;
  int d = (e < E) ? ei[E + e] : (e - E);   // row1 = dst
  atomicAdd(&counts[d], 1);
}

__global__ __launch_bounds__(1024) void scan1_kernel(const int* __restrict__ counts,
                                                     int* __restrict__ offsets,
                                                     int* __restrict__ blocksums, int n) {
  __shared__ int wsum[16];
  int tid = threadIdx.x, lane = tid & 63, wid = tid >> 6;
  int i = blockIdx.x * 1024 + tid;
  int v = (i < n) ? counts[i] : 0;
  int x = v;
  #pragma unroll
  for (int off = 1; off < 64; off <<= 1) {
    int t = __shfl_up(x, off);
    if (lane >= off) x += t;
  }
  if (lane == 63) wsum[wid] = x;
  __syncthreads();
  if (wid == 0) {
    int w = (lane < 16) ? wsum[lane] : 0;
    #pragma unroll
    for (int off = 1; off < 16; off <<= 1) {
      int t = __shfl_up(w, off);
      if (lane >= off) w += t;
    }
    if (lane < 16) wsum[lane] = w;
  }
  __syncthreads();
  int wpre = (wid > 0) ? wsum[wid - 1] : 0;
  if (i < n) offsets[i] = wpre + x - v;
  if (tid == 0) blocksums[blockIdx.x] = wsum[15];
}

__global__ __launch_bounds__(1024) void scan2_kernel(int* __restrict__ blocksums,
                                                     int* __restrict__ offsets, int nb, int n) {
  __shared__ int wsum[16];
  int tid = threadIdx.x, lane = tid & 63, wid = tid >> 6;
  int v = (tid < nb) ? blocksums[tid] : 0;
  int x = v;
  #pragma unroll
  for (int off = 1; off < 64; off <<= 1) {
    int t = __shfl_up(x, off);
    if (lane >= off) x += t;
  }
  if (lane == 63) wsum[wid] = x;
  __syncthreads();
  if (wid == 0) {
    int w = (lane < 16) ? wsum[lane] : 0;
    #pragma unroll
    for (int off = 1; off < 16; off <<= 1) {
      int t = __shfl_up(w, off);
      if (lane >= off) w += t;
    }
    if (lane < 16) wsum[lane] = w;
  }
  __syncthreads();
  int wpre = (wid > 0) ? wsum[wid - 1] : 0;
  if (tid < nb) blocksums[tid] = wpre + x - v;
  if (tid == 0) offsets[n] = wsum[15];
}

__global__ void scan3_kernel(int* __restrict__ offsets, int* __restrict__ cursor,
                             const int* __restrict__ blocksums, int n) {
  int i = blockIdx.x * 256 + threadIdx.x;
  if (i < n) {
    int o = offsets[i] + blocksums[i >> 10];
    offsets[i] = o;
    cursor[i] = o;
  }
}

__global__ void scatter_kernel(const int* __restrict__ ei, int E, int N,
                               int* __restrict__ cursor, int* __restrict__ src_csr) {
  int e = blockIdx.x * 256 + threadIdx.x;
  if (e >= E + N) return;
  int s = (e < E) ? ei[e] : (e - E);
  int d = (e < E) ? ei[E + e] : (e - E);
  int pos = atomicAdd(&cursor[d], 1);
  src_csr[pos] = s;
}

// ---------------- all-f16 MFMA GEMM + fused alpha epilogue ----------------
// A16 [M][K] f16, Wt16 [Nc][K] f16. Vector (half8) staging only.
template <int NT, int H>   // Nc = NT*16
__global__ __launch_bounds__(256) void gemm16_kernel(const _Float16* __restrict__ A,
                                                     const _Float16* __restrict__ Wt,
                                                     const float* __restrict__ als,
                                                     const float* __restrict__ ald,
                                                     _Float16* __restrict__ out16,
                                                     float* __restrict__ asrc,
                                                     float* __restrict__ adst,
                                                     int M, int K) {
  constexpr int Nc = NT * 16;
  constexpr int BM = 128, BK = 32;
  constexpr int CPH = NT / H;
  __shared__ _Float16 As[BM][40];
  __shared__ _Float16 Ws[Nc][40];
  int bm = blockIdx.x * BM;
  int tid = threadIdx.x;
  int w = tid >> 6, l = tid & 63;
  int lr = l & 15, lg = l >> 4;

  floatx4 acc[2][NT];
  #pragma unroll
  for (int rf = 0; rf < 2; ++rf)
    #pragma unroll
    for (int ct = 0; ct < NT; ++ct) acc[rf][ct] = (floatx4){0.f, 0.f, 0.f, 0.f};

  for (int k0 = 0; k0 < K; k0 += BK) {
    // stage A: 128x32 halves = 512 half8 chunks, 2 per thread
    #pragma unroll
    for (int i = 0; i < 2; ++i) {
      int idx = tid + i * 256;
      int r = idx >> 2, c8 = idx & 3;
      int gr = bm + r;
      half8v hv = {(_Float16)0, (_Float16)0, (_Float16)0, (_Float16)0,
                   (_Float16)0, (_Float16)0, (_Float16)0, (_Float16)0};
      if (gr < M) hv = *(const half8v*)&A[(size_t)gr * K + k0 + c8 * 8];
      *(half8v*)&As[r][c8 * 8] = hv;
    }
    // stage W: Nc x 32 halves = Nc*4 half8 chunks, NT/4 per thread
    #pragma unroll
    for (int i = 0; i < NT / 4; ++i) {
      int idx = tid + i * 256;
      int col = idx >> 2, c8 = idx & 3;
      *(half8v*)&Ws[col][c8 * 8] = *(const half8v*)&Wt[(size_t)col * K + k0 + c8 * 8];
    }
    __syncthreads();
    half8v a0 = *(half8v*)&As[w * 32 + lr][lg * 8];
    half8v a1 = *(half8v*)&As[w * 32 + 16 + lr][lg * 8];
    #pragma unroll
    for (int ct = 0; ct < NT; ++ct) {
      half8v b = *(half8v*)&Ws[ct * 16 + lr][lg * 8];
      acc[0][ct] = __builtin_amdgcn_mfma_f32_16x16x32_f16(a0, b, acc[0][ct], 0, 0, 0);
      acc[1][ct] = __builtin_amdgcn_mfma_f32_16x16x32_f16(a1, b, acc[1][ct], 0, 0, 0);
    }
    __syncthreads();
  }
  float als_r[NT], ald_r[NT];
  #pragma unroll
  for (int ct = 0; ct < NT; ++ct) {
    als_r[ct] = als[ct * 16 + lr];
    ald_r[ct] = ald[ct * 16 + lr];
  }
  #pragma unroll
  for (int rf = 0; rf < 2; ++rf)
    #pragma unroll
    for (int q = 0; q < 4; ++q) {
      int row = bm + w * 32 + rf * 16 + lg * 4 + q;
      float ps[H], pd[H];
      #pragma unroll
      for (int hh = 0; hh < H; ++hh) {
        float s = 0.f, d = 0.f;
        #pragma unroll
        for (int c2 = 0; c2 < CPH; ++c2) {
          int ct = hh * CPH + c2;
          s += acc[rf][ct][q] * als_r[ct];
          d += acc[rf][ct][q] * ald_r[ct];
        }
        ps[hh] = s; pd[hh] = d;
      }
      #pragma unroll
      for (int off = 1; off < 16; off <<= 1) {
        #pragma unroll
        for (int hh = 0; hh < H; ++hh) {
          ps[hh] += __shfl_xor(ps[hh], off);
          pd[hh] += __shfl_xor(pd[hh], off);
        }
      }
      if (row < M) {
        if (lr == 0) {
          #pragma unroll
          for (int hh = 0; hh < H; ++hh) asrc[row * H + hh] = ps[hh];
        } else if (lr == 1) {
          #pragma unroll
          for (int hh = 0; hh < H; ++hh) adst[row * H + hh] = pd[hh];
        }
        #pragma unroll
        for (int ct = 0; ct < NT; ++ct)
          out16[(size_t)row * Nc + ct * 16 + lr] = (_Float16)acc[rf][ct][q];
      }
    }
}

// ---------------- fused score + aggregation + LayerNorm + ELU, H=4 ----------
// Output written directly as f16 (identical rounding to old f32->GEMM-staging path).
__global__ __launch_bounds__(256) void agg4_ln_kernel(const _Float16* __restrict__ h16,
                                                      const float* __restrict__ asrc,
                                                      const float* __restrict__ adst,
                                                      const int* __restrict__ offsets,
                                                      const int* __restrict__ src_csr,
                                                      const float* __restrict__ bias,
                                                      const float* __restrict__ g,
                                                      const float* __restrict__ be,
                                                      _Float16* __restrict__ out, int n) {
  int wid = threadIdx.x >> 6, lane = threadIdx.x & 63;
  int node = blockIdx.x * 4 + wid;
  if (node >= n) return;
  int start = offsets[node], end = offsets[node + 1];
  int hl = lane >> 5;            // half-wave index (edge parity)
  int l5 = lane & 31;            // channels l5*8 .. l5*8+7
  int head = l5 >> 3;
  float adh = adst[node * 4 + head];
  const uint4* h4 = (const uint4*)h16;   // one uint4 = 8 f16
  const half2v ones = {(_Float16)1.f, (_Float16)1.f};
  float acc[8] = {0.f, 0.f, 0.f, 0.f, 0.f, 0.f, 0.f, 0.f};
  float denom = 0.f;
  int i = start + hl;
  for (; i + 2 < end; i += 4) {  // edges i and i+2 in this half-wave
    int s0 = src_csr[i], s1 = src_csr[i + 2];
    float sc0 = asrc[s0 * 4 + head] + adh;
    float sc1 = asrc[s1 * 4 + head] + adh;
    sc0 = (sc0 >= 0.f) ? sc0 : 0.2f * sc0;
    sc1 = (sc1 >= 0.f) ? sc1 : 0.2f * sc1;
    float w0 = __expf(sc0), w1 = __expf(sc1);
    uint4 x = h4[(size_t)s0 * 32 + l5];
    uint4 y = h4[(size_t)s1 * 32 + l5];
    half2v w01 = pack_rtz(w0, w1);
    denom = __builtin_amdgcn_fdot2(w01, ones, denom, false);
    acc[0] = __builtin_amdgcn_fdot2(w01, __builtin_bit_cast(half2v, __builtin_amdgcn_perm(y.x, x.x, 0x05040100u)), acc[0], false);
    acc[1] = __builtin_amdgcn_fdot2(w01, __builtin_bit_cast(half2v, __builtin_amdgcn_perm(y.x, x.x, 0x07060302u)), acc[1], false);
    acc[2] = __builtin_amdgcn_fdot2(w01, __builtin_bit_cast(half2v, __builtin_amdgcn_perm(y.y, x.y, 0x05040100u)), acc[2], false);
    acc[3] = __builtin_amdgcn_fdot2(w01, __builtin_bit_cast(half2v, __builtin_amdgcn_perm(y.y, x.y, 0x07060302u)), acc[3], false);
    acc[4] = __builtin_amdgcn_fdot2(w01, __builtin_bit_cast(half2v, __builtin_amdgcn_perm(y.z, x.z, 0x05040100u)), acc[4], false);
    acc[5] = __builtin_amdgcn_fdot2(w01, __builtin_bit_cast(half2v, __builtin_amdgcn_perm(y.z, x.z, 0x07060302u)), acc[5], false);
    acc[6] = __builtin_amdgcn_fdot2(w01, __builtin_bit_cast(half2v, __builtin_amdgcn_perm(y.w, x.w, 0x05040100u)), acc[6], false);
    acc[7] = __builtin_amdgcn_fdot2(w01, __builtin_bit_cast(half2v, __builtin_amdgcn_perm(y.w, x.w, 0x07060302u)), acc[7], false);
  }
  if (i < end) {                 // tail edge (w1 = 0)
    int s0 = src_csr[i];
    float sc0 = asrc[s0 * 4 + head] + adh;
    sc0 = (sc0 >= 0.f) ? sc0 : 0.2f * sc0;
    float w0 = __expf(sc0);
    uint4 x = h4[(size_t)s0 * 32 + l5];
    half2v w01 = pack_rtz(w0, 0.f);
    denom = __builtin_amdgcn_fdot2(w01, ones, denom, false);
    acc[0] = __builtin_amdgcn_fdot2(w01, __builtin_bit_cast(half2v, __builtin_amdgcn_perm(x.x, x.x, 0x05040100u)), acc[0], false);
    acc[1] = __builtin_amdgcn_fdot2(w01, __builtin_bit_cast(half2v, __builtin_amdgcn_perm(x.x, x.x, 0x07060302u)), acc[1], false);
    acc[2] = __builtin_amdgcn_fdot2(w01, __builtin_bit_cast(half2v, __builtin_amdgcn_perm(x.y, x.y, 0x05040100u)), acc[2], false);
    acc[3] = __builtin_amdgcn_fdot2(w01, __builtin_bit_cast(half2v, __builtin_amdgcn_perm(x.y, x.y, 0x07060302u)), acc[3], false);
    acc[4] = __builtin_amdgcn_fdot2(w01, __builtin_bit_cast(half2v, __builtin_amdgcn_perm(x.z, x.z, 0x05040100u)), acc[4], false);
    acc[5] = __builtin_amdgcn_fdot2(w01, __builtin_bit_cast(half2v, __builtin_amdgcn_perm(x.z, x.z, 0x07060302u)), acc[5], false);
    acc[6] = __builtin_amdgcn_fdot2(w01, __builtin_bit_cast(half2v, __builtin_amdgcn_perm(x.w, x.w, 0x05040100u)), acc[6], false);
    acc[7] = __builtin_amdgcn_fdot2(w01, __builtin_bit_cast(half2v, __builtin_amdgcn_perm(x.w, x.w, 0x07060302u)), acc[7], false);
  }
  #pragma unroll
  for (int j = 0; j < 8; ++j) acc[j] += __shfl_xor(acc[j], 32);
  denom += __shfl_xor(denom, 32);
  float inv = 1.f / denom;
  float o[8];
  float4 b0 = *(const float4*)&bias[l5 * 8];
  float4 b1 = *(const float4*)&bias[l5 * 8 + 4];
  o[0] = acc[0] * inv + b0.x; o[1] = acc[1] * inv + b0.y;
  o[2] = acc[2] * inv + b0.z; o[3] = acc[3] * inv + b0.w;
  o[4] = acc[4] * inv + b1.x; o[5] = acc[5] * inv + b1.y;
  o[6] = acc[6] * inv + b1.z; o[7] = acc[7] * inv + b1.w;
  float s = 0.f;
  #pragma unroll
  for (int j = 0; j < 8; ++j) s += o[j];
  #pragma unroll
  for (int off = 16; off; off >>= 1) s += __shfl_xor(s, off);
  float mu = s * (1.f / 256.f);
  float var = 0.f;
  #pragma unroll
  for (int j = 0; j < 8; ++j) { float d = o[j] - mu; var += d * d; }
  #pragma unroll
  for (int off = 16; off; off >>= 1) var += __shfl_xor(var, off);
  float r = rsqrtf(var * (1.f / 256.f) + 1e-5f);
  float4 g0 = *(const float4*)&g[l5 * 8];
  float4 g1 = *(const float4*)&g[l5 * 8 + 4];
  float4 e0 = *(const float4*)&be[l5 * 8];
  float4 e1 = *(const float4*)&be[l5 * 8 + 4];
  float gg[8] = {g0.x, g0.y, g0.z, g0.w, g1.x, g1.y, g1.z, g1.w};
  float ee[8] = {e0.x, e0.y, e0.z, e0.w, e1.x, e1.y, e1.z, e1.w};
  if (hl == 0) {
    half8v yv;
    #pragma unroll
    for (int j = 0; j < 8; ++j) {
      float t = (o[j] - mu) * r * gg[j] + ee[j];
      t = (t > 0.f) ? t : expm1f(t);
      yv[j] = (_Float16)t;
    }
    *(half8v*)&out[(size_t)node * 256 + l5 * 8] = yv;
  }
}

// ---------------- fused score + aggregation + LayerNorm + ELU, H=1 ----------
__global__ __launch_bounds__(256) void agg1_ln_kernel(const _Float16* __restrict__ h16,
                                                      const float* __restrict__ asrc,
                                                      const float* __restrict__ adst,
                                                      const int* __restrict__ offsets,
                                                      const int* __restrict__ src_csr,
                                                      const float* __restrict__ bias,
                                                      const float* __restrict__ g,
                                                      const float* __restrict__ be,
                                                      float* __restrict__ out, int n) {
  int wid = threadIdx.x >> 6, lane = threadIdx.x & 63;
  int node = blockIdx.x * 4 + wid;
  if (node >= n) return;
  int start = offsets[node], end = offsets[node + 1];
  int qi = lane >> 4;            // quarter index (edge offset)
  int ql = lane & 15;            // channels ql*4 .. ql*4+3
  float adh = adst[node];
  const uint2* h2 = (const uint2*)h16;   // one uint2 = 4 f16
  const half2v ones = {(_Float16)1.f, (_Float16)1.f};
  float acc[4] = {0.f, 0.f, 0.f, 0.f};
  float denom = 0.f;
  int i = start + qi;
  for (; i + 4 < end; i += 8) {  // edges i and i+4 in this quarter
    int s0 = src_csr[i], s1 = src_csr[i + 4];
    float sc0 = asrc[s0] + adh;
    float sc1 = asrc[s1] + adh;
    sc0 = (sc0 >= 0.f) ? sc0 : 0.2f * sc0;
    sc1 = (sc1 >= 0.f) ? sc1 : 0.2f * sc1;
    float w0 = __expf(sc0), w1 = __expf(sc1);
    uint2 x = h2[(size_t)s0 * 16 + ql];
    uint2 y = h2[(size_t)s1 * 16 + ql];
    half2v w01 = pack_rtz(w0, w1);
    denom = __builtin_amdgcn_fdot2(w01, ones, denom, false);
    acc[0] = __builtin_amdgcn_fdot2(w01, __builtin_bit_cast(half2v, __builtin_amdgcn_perm(y.x, x.x, 0x05040100u)), acc[0], false);
    acc[1] = __builtin_amdgcn_fdot2(w01, __builtin_bit_cast(half2v, __builtin_amdgcn_perm(y.x, x.x, 0x07060302u)), acc[1], false);
    acc[2] = __builtin_amdgcn_fdot2(w01, __builtin_bit_cast(half2v, __builtin_amdgcn_perm(y.y, x.y, 0x05040100u)), acc[2], false);
    acc[3] = __builtin_amdgcn_fdot2(w01, __builtin_bit_cast(half2v, __builtin_amdgcn_perm(y.y, x.y, 0x07060302u)), acc[3], false);
  }
  if (i < end) {
    int s0 = src_csr[i];
    float sc0 = asrc[s0] + adh;
    sc0 = (sc0 >= 0.f) ? sc0 : 0.2f * sc0;
    float w0 = __expf(sc0);
    uint2 x = h2[(size_t)s0 * 16 + ql];
    half2v w01 = pack_rtz(w0, 0.f);
    denom = __builtin_amdgcn_fdot2(w01, ones, denom, false);
    acc[0] = __builtin_amdgcn_fdot2(w01, __builtin_bit_cast(half2v, __builtin_amdgcn_perm(x.x, x.x, 0x05040100u)), acc[0], false);
    acc[1] = __builtin_amdgcn_fdot2(w01, __builtin_bit_cast(half2v, __builtin_amdgcn_perm(x.x, x.x, 0x07060302u)), acc[1], false);
    acc[2] = __builtin_amdgcn_fdot2(w01, __builtin_bit_cast(half2v, __builtin_amdgcn_perm(x.y, x.y, 0x05040100u)), acc[2], false);
    acc[3] = __builtin_amdgcn_fdot2(w01, __builtin_bit_cast(half2v, __builtin_amdgcn_perm(x.y, x.y, 0x07060302u)), acc[3], false);
  }
  #pragma unroll
  for (int off = 32; off >= 16; off >>= 1) {
    #pragma unroll
    for (int j = 0; j < 4; ++j) acc[j] += __shfl_xor(acc[j], off);
    denom += __shfl_xor(denom, off);
  }
  float inv = 1.f / denom;
  float4 b4 = *(const float4*)&bias[ql * 4];
  float o[4];
  o[0] = acc[0] * inv + b4.x; o[1] = acc[1] * inv + b4.y;
  o[2] = acc[2] * inv + b4.z; o[3] = acc[3] * inv + b4.w;
  float s = o[0] + o[1] + o[2] + o[3];
  #pragma unroll
  for (int off = 8; off; off >>= 1) s += __shfl_xor(s, off);
  float mu = s * (1.f / 64.f);
  float var = 0.f;
  #pragma unroll
  for (int j = 0; j < 4; ++j) { float d = o[j] - mu; var += d * d; }
  #pragma unroll
  for (int off = 8; off; off >>= 1) var += __shfl_xor(var, off);
  float r = rsqrtf(var * (1.f / 64.f) + 1e-5f);
  float4 g4 = *(const float4*)&g[ql * 4];
  float4 e4 = *(const float4*)&be[ql * 4];
  float gg[4] = {g4.x, g4.y, g4.z, g4.w};
  float ee[4] = {e4.x, e4.y, e4.z, e4.w};
  float y[4];
  #pragma unroll
  for (int j = 0; j < 4; ++j) {
    float t = (o[j] - mu) * r * gg[j] + ee[j];
    y[j] = (t > 0.f) ? t : expm1f(t);
  }
  if (qi == 0) {
    *(float4*)&out[(size_t)node * 64 + ql * 4] = make_float4(y[0], y[1], y[2], y[3]);
  }
}

// ---------------- fused pool + MLP head (batch is sorted) ----------------
__global__ __launch_bounds__(256) void graph_head_kernel(const float* __restrict__ h,
                                                         const int* __restrict__ batch, int N,
                                                         const float* __restrict__ Wg,
                                                         const float* __restrict__ bg,
                                                         const float* __restrict__ Wg2,
                                                         const float* __restrict__ bg2,
                                                         const float* __restrict__ Wo,
                                                         const float* __restrict__ bo,
                                                         float* __restrict__ out) {
  __shared__ int bounds[2];
  __shared__ float part[4][64];
  __shared__ float gm[64];
  __shared__ float z1[128];
  __shared__ float z2[64];
  int g = blockIdx.x;
  int tid = threadIdx.x;
  if (tid < 2) {
    int target = g + tid;  // lower_bound(batch, target)
    int lo = 0, hi = N;
    while (lo < hi) {
      int mid = (lo + hi) >> 1;
      if (batch[mid] < target) lo = mid + 1; else hi = mid;
    }
    bounds[tid] = lo;
  }
  __syncthreads();
  int lo = bounds[0], hi = bounds[1];
  int c = tid & 63, sub = tid >> 6;
  float acc = 0.f;
  for (int r = lo + sub; r < hi; r += 4) acc += h[(size_t)r * 64 + c];
  part[sub][c] = acc;
  __syncthreads();
  float invc = 1.f / fmaxf((float)(hi - lo), 1.f);
  if (tid < 64) gm[tid] = (part[0][tid] + part[1][tid] + part[2][tid] + part[3][tid]) * invc;
  __syncthreads();
  if (tid < 128) {
    float a = bg[tid];
    for (int k = 0; k < 64; ++k) a += gm[k] * Wg[k * 128 + tid];
    z1[tid] = fmaxf(a, 0.f);
  }
  __syncthreads();
  if (tid < 64) {
    float a = bg2[tid];
    for (int k = 0; k < 128; ++k) a += z1[k] * Wg2[k * 64 + tid];
    z2[tid] = fmaxf(a, 0.f);
  }
  __syncthreads();
  if (tid < 5) {
    float a = bo[tid];
    for (int k = 0; k < 64; ++k) a += z2[k] * Wo[k * 5 + tid];
    out[g * 5 + tid] = a;
  }
}

// ---------------- launch ----------------
extern "C" void kernel_launch(void* const* d_in, const int* in_sizes, int n_in,
                              void* d_out, int out_size, void* d_ws, size_t ws_size,
                              hipStream_t stream) {
  const float* x   = (const float*)d_in[0];
  const int* ei    = (const int*)d_in[1];
  const int* batch = (const int*)d_in[2];
  const float* W1  = (const float*)d_in[3];
  const float* a1s = (const float*)d_in[4];
  const float* a1d = (const float*)d_in[5];
  const float* b1  = (const float*)d_in[6];
  const float* g1  = (const float*)d_in[7];
  const float* be1 = (const float*)d_in[8];
  const float* W2  = (const float*)d_in[9];
  const float* a2s = (const float*)d_in[10];
  const float* a2d = (const float*)d_in[11];
  const float* b2  = (const float*)d_in[12];
  const float* g2  = (const float*)d_in[13];
  const float* be2 = (const float*)d_in[14];
  const float* W3  = (const float*)d_in[15];
  const float* a3s = (const float*)d_in[16];
  const float* a3d = (const float*)d_in[17];
  const float* b3  = (const float*)d_in[18];
  const float* g3  = (const float*)d_in[19];
  const float* be3 = (const float*)d_in[20];
  const float* Wg  = (const float*)d_in[21];
  const float* bg  = (const float*)d_in[22];
  const float* Wg2 = (const float*)d_in[23];
  const float* bg2 = (const float*)d_in[24];
  const float* Wo  = (const float*)d_in[25];
  const float* bo  = (const float*)d_in[26];

  const int N = in_sizes[2];
  const int E = in_sizes[1] / 2;
  const int ET = E + N;  // with self-loops
  const int G = 64;
  const int NB = (N + 1023) / 1024;

  // workspace carve-up (256B aligned)
  char* ws = (char*)d_ws;
  size_t off = 0;
  auto carve = [&](size_t bytes) {
    void* p = ws + off;
    off = (off + bytes + 255) & ~(size_t)255;
    return p;
  };
  int* counts    = (int*)carve((size_t)N * 4);
  int* offsets   = (int*)carve((size_t)(N + 1) * 4);
  int* cursor    = (int*)carve((size_t)N * 4);
  int* blocksums = (int*)carve((size_t)NB * 4);
  int* src_csr   = (int*)carve((size_t)ET * 4);
  float* asrc    = (float*)carve((size_t)N * 4 * 4);
  float* adst    = (float*)carve((size_t)N * 4 * 4);
  _Float16* x16  = (_Float16*)carve((size_t)N * 128 * 2);
  _Float16* a16  = (_Float16*)carve((size_t)N * 256 * 2);
  _Float16* h16  = (_Float16*)carve((size_t)N * 256 * 2);
  float* buf3    = (float*)carve((size_t)N * 64 * 4);
  _Float16* Wt1  = (_Float16*)carve((size_t)128 * 256 * 2);
  _Float16* Wt2  = (_Float16*)carve((size_t)256 * 256 * 2);
  _Float16* Wt3  = (_Float16*)carve((size_t)256 * 64 * 2);
  (void)ws_size;

  const int egrid = (ET + 255) / 256;
  const int ngrid4 = (N + 3) / 4;
  const int mblocks = (N + 127) / 128;

  // --- pre-passes: weight transpose + x conversion (independent of CSR) ---
  wt_kernel<<<256, 256, 0, stream>>>(W1, Wt1, 128, 256);
  wt_kernel<<<256, 256, 0, stream>>>(W2, Wt2, 256, 256);
  wt_kernel<<<64, 256, 0, stream>>>(W3, Wt3, 256, 64);
  cvt16_kernel<<<(N * 16 + 255) / 256, 256, 0, stream>>>(x, x16, N * 16);

  // --- CSR (dst-sorted src list), rebuilt every call ---
  hipMemsetAsync(counts, 0, (size_t)N * 4, stream);
  count_kernel<<<egrid, 256, 0, stream>>>(ei, E, N, counts);
  scan1_kernel<<<NB, 1024, 0, stream>>>(counts, offsets, blocksums, N);
  scan2_kernel<<<1, 1024, 0, stream>>>(blocksums, offsets, NB, N);
  scan3_kernel<<<(N + 255) / 256, 256, 0, stream>>>(offsets, cursor, blocksums, N);
  scatter_kernel<<<egrid, 256, 0, stream>>>(ei, E, N, cursor, src_csr);

  // --- layer 1 ---
  gemm16_kernel<16, 4><<<mblocks, 256, 0, stream>>>(x16, Wt1, a1s, a1d, h16, asrc, adst, N, 128);
  agg4_ln_kernel<<<ngrid4, 256, 0, stream>>>(h16, asrc, adst, offsets, src_csr, b1, g1, be1, a16, N);

  // --- layer 2 ---
  gemm16_kernel<16, 4><<<mblocks, 256, 0, stream>>>(a16, Wt2, a2s, a2d, h16, asrc, adst, N, 256);
  agg4_ln_kernel<<<ngrid4, 256, 0, stream>>>(h16, asrc, adst, offsets, src_csr, b2, g2, be2, a16, N);

  // --- layer 3 (H=1, C=64) ---
  gemm16_kernel<4, 1><<<mblocks, 256, 0, stream>>>(a16, Wt3, a3s, a3d, h16, asrc, adst, N, 256);
  agg1_ln_kernel<<<ngrid4, 256, 0, stream>>>(h16, asrc, adst, offsets, src_csr, b3, g3, be3, buf3, N);

  // --- fused pool + MLP head ---
  graph_head_kernel<<<G, 256, 0, stream>>>(buf3, batch, N, Wg, bg, Wg2, bg2, Wo, bo,
                                           (float*)d_out);
}

// Round 10
// 399.941 us; speedup vs baseline: 6.6006x; 1.0449x over previous
//
#include <hip/hip_runtime.h>
#include <math.h>

typedef _Float16 half2v __attribute__((ext_vector_type(2)));
typedef _Float16 half4v __attribute__((ext_vector_type(4)));
typedef _Float16 half8v __attribute__((ext_vector_type(8)));
typedef float floatx4 __attribute__((ext_vector_type(4)));

static __device__ __forceinline__ half2v pack_rtz(float a, float b) {
  return __builtin_bit_cast(half2v, __builtin_amdgcn_cvt_pkrtz(a, b));
}
static __device__ __forceinline__ float dot2(half2v w, unsigned hi, unsigned lo, unsigned sel, float acc) {
  return __builtin_amdgcn_fdot2(w, __builtin_bit_cast(half2v, __builtin_amdgcn_perm(hi, lo, sel)), acc, false);
}

// ---------------- fused pre-pass: W transposes + x conversion ----------------
__global__ __launch_bounds__(256) void prep_kernel(const float* __restrict__ W1,
                                                   const float* __restrict__ W2,
                                                   const float* __restrict__ W3,
                                                   const float* __restrict__ x,
                                                   _Float16* __restrict__ Wt1,
                                                   _Float16* __restrict__ Wt2,
                                                   _Float16* __restrict__ Wt3,
                                                   _Float16* __restrict__ x16, int n8) {
  int b = blockIdx.x;
  int t = threadIdx.x;
  if (b < 256) {                       // Wt1 [256][128] <- W1 [128][256]
    if (t < 128) Wt1[(size_t)b * 128 + t] = (_Float16)W1[(size_t)t * 256 + b];
  } else if (b < 512) {                // Wt2 [256][256] <- W2 [256][256]
    int col = b - 256;
    Wt2[(size_t)col * 256 + t] = (_Float16)W2[(size_t)t * 256 + col];
  } else if (b < 576) {                // Wt3 [64][256] <- W3 [256][64]
    int col = b - 512;
    Wt3[(size_t)col * 256 + t] = (_Float16)W3[(size_t)t * 64 + col];
  } else {                             // x -> x16 (8 elems/thread)
    int i = (b - 576) * 256 + t;
    if (i < n8) {
      float4 a = ((const float4*)x)[2 * i];
      float4 c = ((const float4*)x)[2 * i + 1];
      half8v h = {(_Float16)a.x, (_Float16)a.y, (_Float16)a.z, (_Float16)a.w,
                  (_Float16)c.x, (_Float16)c.y, (_Float16)c.z, (_Float16)c.w};
      ((half8v*)x16)[i] = h;
    }
  }
}

// ---------------- CSR build ----------------
__global__ void count_kernel(const int* __restrict__ ei, int E, int N, int* __restrict__ counts) {
  int e = blockIdx.x * 256 + threadIdx.x;
  if (e >= E + N) return;
  int d = (e < E) ? ei[E + e] : (e - E);   // row1 = dst
  atomicAdd(&counts[d], 1);
}

__global__ __launch_bounds__(1024) void scan1_kernel(const int* __restrict__ counts,
                                                     int* __restrict__ offsets,
                                                     int* __restrict__ blocksums, int n) {
  __shared__ int wsum[16];
  int tid = threadIdx.x, lane = tid & 63, wid = tid >> 6;
  int i = blockIdx.x * 1024 + tid;
  int v = (i < n) ? counts[i] : 0;
  int x = v;
  #pragma unroll
  for (int off = 1; off < 64; off <<= 1) {
    int t = __shfl_up(x, off);
    if (lane >= off) x += t;
  }
  if (lane == 63) wsum[wid] = x;
  __syncthreads();
  if (wid == 0) {
    int w = (lane < 16) ? wsum[lane] : 0;
    #pragma unroll
    for (int off = 1; off < 16; off <<= 1) {
      int t = __shfl_up(w, off);
      if (lane >= off) w += t;
    }
    if (lane < 16) wsum[lane] = w;
  }
  __syncthreads();
  int wpre = (wid > 0) ? wsum[wid - 1] : 0;
  if (i < n) offsets[i] = wpre + x - v;
  if (tid == 0) blocksums[blockIdx.x] = wsum[15];
}

__global__ __launch_bounds__(1024) void scan2_kernel(int* __restrict__ blocksums,
                                                     int* __restrict__ offsets, int nb, int n) {
  __shared__ int wsum[16];
  int tid = threadIdx.x, lane = tid & 63, wid = tid >> 6;
  int v = (tid < nb) ? blocksums[tid] : 0;
  int x = v;
  #pragma unroll
  for (int off = 1; off < 64; off <<= 1) {
    int t = __shfl_up(x, off);
    if (lane >= off) x += t;
  }
  if (lane == 63) wsum[wid] = x;
  __syncthreads();
  if (wid == 0) {
    int w = (lane < 16) ? wsum[lane] : 0;
    #pragma unroll
    for (int off = 1; off < 16; off <<= 1) {
      int t = __shfl_up(w, off);
      if (lane >= off) w += t;
    }
    if (lane < 16) wsum[lane] = w;
  }
  __syncthreads();
  int wpre = (wid > 0) ? wsum[wid - 1] : 0;
  if (tid < nb) blocksums[tid] = wpre + x - v;
  if (tid == 0) offsets[n] = wsum[15];
}

__global__ void scan3_kernel(int* __restrict__ offsets, int* __restrict__ cursor,
                             const int* __restrict__ blocksums, int n) {
  int i = blockIdx.x * 256 + threadIdx.x;
  if (i < n) {
    int o = offsets[i] + blocksums[i >> 10];
    offsets[i] = o;
    cursor[i] = o;
  }
}

__global__ void scatter_kernel(const int* __restrict__ ei, int E, int N,
                               int* __restrict__ cursor, int* __restrict__ src_csr) {
  int e = blockIdx.x * 256 + threadIdx.x;
  if (e >= E + N) return;
  int s = (e < E) ? ei[e] : (e - E);
  int d = (e < E) ? ei[E + e] : (e - E);
  int pos = atomicAdd(&cursor[d], 1);
  src_csr[pos] = s;
}

// ---------------- all-f16 MFMA GEMM + fused alpha epilogue ----------------
template <int NT, int H>   // Nc = NT*16
__global__ __launch_bounds__(256) void gemm16_kernel(const _Float16* __restrict__ A,
                                                     const _Float16* __restrict__ Wt,
                                                     const float* __restrict__ als,
                                                     const float* __restrict__ ald,
                                                     _Float16* __restrict__ out16,
                                                     float* __restrict__ asrc,
                                                     float* __restrict__ adst,
                                                     int M, int K) {
  constexpr int Nc = NT * 16;
  constexpr int BM = 128, BK = 32;
  constexpr int CPH = NT / H;
  __shared__ _Float16 As[BM][40];
  __shared__ _Float16 Ws[Nc][40];
  int bm = blockIdx.x * BM;
  int tid = threadIdx.x;
  int w = tid >> 6, l = tid & 63;
  int lr = l & 15, lg = l >> 4;

  floatx4 acc[2][NT];
  #pragma unroll
  for (int rf = 0; rf < 2; ++rf)
    #pragma unroll
    for (int ct = 0; ct < NT; ++ct) acc[rf][ct] = (floatx4){0.f, 0.f, 0.f, 0.f};

  for (int k0 = 0; k0 < K; k0 += BK) {
    #pragma unroll
    for (int i = 0; i < 2; ++i) {
      int idx = tid + i * 256;
      int r = idx >> 2, c8 = idx & 3;
      int gr = bm + r;
      half8v hv = {(_Float16)0, (_Float16)0, (_Float16)0, (_Float16)0,
                   (_Float16)0, (_Float16)0, (_Float16)0, (_Float16)0};
      if (gr < M) hv = *(const half8v*)&A[(size_t)gr * K + k0 + c8 * 8];
      *(half8v*)&As[r][c8 * 8] = hv;
    }
    #pragma unroll
    for (int i = 0; i < NT / 4; ++i) {
      int idx = tid + i * 256;
      int col = idx >> 2, c8 = idx & 3;
      *(half8v*)&Ws[col][c8 * 8] = *(const half8v*)&Wt[(size_t)col * K + k0 + c8 * 8];
    }
    __syncthreads();
    half8v a0 = *(half8v*)&As[w * 32 + lr][lg * 8];
    half8v a1 = *(half8v*)&As[w * 32 + 16 + lr][lg * 8];
    #pragma unroll
    for (int ct = 0; ct < NT; ++ct) {
      half8v b = *(half8v*)&Ws[ct * 16 + lr][lg * 8];
      acc[0][ct] = __builtin_amdgcn_mfma_f32_16x16x32_f16(a0, b, acc[0][ct], 0, 0, 0);
      acc[1][ct] = __builtin_amdgcn_mfma_f32_16x16x32_f16(a1, b, acc[1][ct], 0, 0, 0);
    }
    __syncthreads();
  }
  float als_r[NT], ald_r[NT];
  #pragma unroll
  for (int ct = 0; ct < NT; ++ct) {
    als_r[ct] = als[ct * 16 + lr];
    ald_r[ct] = ald[ct * 16 + lr];
  }
  #pragma unroll
  for (int rf = 0; rf < 2; ++rf)
    #pragma unroll
    for (int q = 0; q < 4; ++q) {
      int row = bm + w * 32 + rf * 16 + lg * 4 + q;
      float ps[H], pd[H];
      #pragma unroll
      for (int hh = 0; hh < H; ++hh) {
        float s = 0.f, d = 0.f;
        #pragma unroll
        for (int c2 = 0; c2 < CPH; ++c2) {
          int ct = hh * CPH + c2;
          s += acc[rf][ct][q] * als_r[ct];
          d += acc[rf][ct][q] * ald_r[ct];
        }
        ps[hh] = s; pd[hh] = d;
      }
      #pragma unroll
      for (int off = 1; off < 16; off <<= 1) {
        #pragma unroll
        for (int hh = 0; hh < H; ++hh) {
          ps[hh] += __shfl_xor(ps[hh], off);
          pd[hh] += __shfl_xor(pd[hh], off);
        }
      }
      if (row < M) {
        if (lr == 0) {
          #pragma unroll
          for (int hh = 0; hh < H; ++hh) asrc[row * H + hh] = ps[hh];
        } else if (lr == 1) {
          #pragma unroll
          for (int hh = 0; hh < H; ++hh) adst[row * H + hh] = pd[hh];
        }
        #pragma unroll
        for (int ct = 0; ct < NT; ++ct)
          out16[(size_t)row * Nc + ct * 16 + lr] = (_Float16)acc[rf][ct][q];
      }
    }
}

// ---------------- fused score + aggregation + LayerNorm + ELU, H=4 ----------
// 2 nodes per 128-thr block; half-wave (32 lanes x 16B) per source row.
// Edge loop unrolled x2: 4 independent gathers in flight per lane.
__global__ __launch_bounds__(128) void agg4_ln_kernel(const _Float16* __restrict__ h16,
                                                      const float* __restrict__ asrc,
                                                      const float* __restrict__ adst,
                                                      const int* __restrict__ offsets,
                                                      const int* __restrict__ src_csr,
                                                      const float* __restrict__ bias,
                                                      const float* __restrict__ g,
                                                      const float* __restrict__ be,
                                                      _Float16* __restrict__ out, int n) {
  int wid = threadIdx.x >> 6, lane = threadIdx.x & 63;
  int node = blockIdx.x * 2 + wid;
  if (node >= n) return;
  int start = offsets[node], end = offsets[node + 1];
  int hl = lane >> 5;            // half-wave index (edge parity)
  int l5 = lane & 31;            // channels l5*8 .. l5*8+7
  int head = l5 >> 3;
  float adh = adst[node * 4 + head];
  const uint4* h4 = (const uint4*)h16;
  const half2v ones = {(_Float16)1.f, (_Float16)1.f};
  float acc[8] = {0.f, 0.f, 0.f, 0.f, 0.f, 0.f, 0.f, 0.f};
  float denom = 0.f;
  int i = start + hl;
  // unrolled: 4 edges (i, i+2, i+4, i+6) per iteration
  for (; i + 6 < end; i += 8) {
    int s0 = src_csr[i], s1 = src_csr[i + 2], s2 = src_csr[i + 4], s3 = src_csr[i + 6];
    uint4 x0 = h4[(size_t)s0 * 32 + l5];
    uint4 x1 = h4[(size_t)s1 * 32 + l5];
    uint4 x2 = h4[(size_t)s2 * 32 + l5];
    uint4 x3 = h4[(size_t)s3 * 32 + l5];
    float sc0 = asrc[s0 * 4 + head] + adh;
    float sc1 = asrc[s1 * 4 + head] + adh;
    float sc2 = asrc[s2 * 4 + head] + adh;
    float sc3 = asrc[s3 * 4 + head] + adh;
    sc0 = (sc0 >= 0.f) ? sc0 : 0.2f * sc0;
    sc1 = (sc1 >= 0.f) ? sc1 : 0.2f * sc1;
    sc2 = (sc2 >= 0.f) ? sc2 : 0.2f * sc2;
    sc3 = (sc3 >= 0.f) ? sc3 : 0.2f * sc3;
    half2v wa = pack_rtz(__expf(sc0), __expf(sc1));
    half2v wb = pack_rtz(__expf(sc2), __expf(sc3));
    denom = __builtin_amdgcn_fdot2(wa, ones, denom, false);
    denom = __builtin_amdgcn_fdot2(wb, ones, denom, false);
    acc[0] = dot2(wa, x1.x, x0.x, 0x05040100u, acc[0]);
    acc[1] = dot2(wa, x1.x, x0.x, 0x07060302u, acc[1]);
    acc[2] = dot2(wa, x1.y, x0.y, 0x05040100u, acc[2]);
    acc[3] = dot2(wa, x1.y, x0.y, 0x07060302u, acc[3]);
    acc[4] = dot2(wa, x1.z, x0.z, 0x05040100u, acc[4]);
    acc[5] = dot2(wa, x1.z, x0.z, 0x07060302u, acc[5]);
    acc[6] = dot2(wa, x1.w, x0.w, 0x05040100u, acc[6]);
    acc[7] = dot2(wa, x1.w, x0.w, 0x07060302u, acc[7]);
    acc[0] = dot2(wb, x3.x, x2.x, 0x05040100u, acc[0]);
    acc[1] = dot2(wb, x3.x, x2.x, 0x07060302u, acc[1]);
    acc[2] = dot2(wb, x3.y, x2.y, 0x05040100u, acc[2]);
    acc[3] = dot2(wb, x3.y, x2.y, 0x07060302u, acc[3]);
    acc[4] = dot2(wb, x3.z, x2.z, 0x05040100u, acc[4]);
    acc[5] = dot2(wb, x3.z, x2.z, 0x07060302u, acc[5]);
    acc[6] = dot2(wb, x3.w, x2.w, 0x05040100u, acc[6]);
    acc[7] = dot2(wb, x3.w, x2.w, 0x07060302u, acc[7]);
  }
  for (; i + 2 < end; i += 4) {  // 2 edges
    int s0 = src_csr[i], s1 = src_csr[i + 2];
    uint4 x0 = h4[(size_t)s0 * 32 + l5];
    uint4 x1 = h4[(size_t)s1 * 32 + l5];
    float sc0 = asrc[s0 * 4 + head] + adh;
    float sc1 = asrc[s1 * 4 + head] + adh;
    sc0 = (sc0 >= 0.f) ? sc0 : 0.2f * sc0;
    sc1 = (sc1 >= 0.f) ? sc1 : 0.2f * sc1;
    half2v wa = pack_rtz(__expf(sc0), __expf(sc1));
    denom = __builtin_amdgcn_fdot2(wa, ones, denom, false);
    acc[0] = dot2(wa, x1.x, x0.x, 0x05040100u, acc[0]);
    acc[1] = dot2(wa, x1.x, x0.x, 0x07060302u, acc[1]);
    acc[2] = dot2(wa, x1.y, x0.y, 0x05040100u, acc[2]);
    acc[3] = dot2(wa, x1.y, x0.y, 0x07060302u, acc[3]);
    acc[4] = dot2(wa, x1.z, x0.z, 0x05040100u, acc[4]);
    acc[5] = dot2(wa, x1.z, x0.z, 0x07060302u, acc[5]);
    acc[6] = dot2(wa, x1.w, x0.w, 0x05040100u, acc[6]);
    acc[7] = dot2(wa, x1.w, x0.w, 0x07060302u, acc[7]);
  }
  if (i < end) {                 // tail edge
    int s0 = src_csr[i];
    uint4 x0 = h4[(size_t)s0 * 32 + l5];
    float sc0 = asrc[s0 * 4 + head] + adh;
    sc0 = (sc0 >= 0.f) ? sc0 : 0.2f * sc0;
    half2v wa = pack_rtz(__expf(sc0), 0.f);
    denom = __builtin_amdgcn_fdot2(wa, ones, denom, false);
    acc[0] = dot2(wa, x0.x, x0.x, 0x05040100u, acc[0]);
    acc[1] = dot2(wa, x0.x, x0.x, 0x07060302u, acc[1]);
    acc[2] = dot2(wa, x0.y, x0.y, 0x05040100u, acc[2]);
    acc[3] = dot2(wa, x0.y, x0.y, 0x07060302u, acc[3]);
    acc[4] = dot2(wa, x0.z, x0.z, 0x05040100u, acc[4]);
    acc[5] = dot2(wa, x0.z, x0.z, 0x07060302u, acc[5]);
    acc[6] = dot2(wa, x0.w, x0.w, 0x05040100u, acc[6]);
    acc[7] = dot2(wa, x0.w, x0.w, 0x07060302u, acc[7]);
  }
  #pragma unroll
  for (int j = 0; j < 8; ++j) acc[j] += __shfl_xor(acc[j], 32);
  denom += __shfl_xor(denom, 32);
  float inv = 1.f / denom;
  float o[8];
  float4 b0 = *(const float4*)&bias[l5 * 8];
  float4 b1 = *(const float4*)&bias[l5 * 8 + 4];
  o[0] = acc[0] * inv + b0.x; o[1] = acc[1] * inv + b0.y;
  o[2] = acc[2] * inv + b0.z; o[3] = acc[3] * inv + b0.w;
  o[4] = acc[4] * inv + b1.x; o[5] = acc[5] * inv + b1.y;
  o[6] = acc[6] * inv + b1.z; o[7] = acc[7] * inv + b1.w;
  float s = 0.f;
  #pragma unroll
  for (int j = 0; j < 8; ++j) s += o[j];
  #pragma unroll
  for (int off = 16; off; off >>= 1) s += __shfl_xor(s, off);
  float mu = s * (1.f / 256.f);
  float var = 0.f;
  #pragma unroll
  for (int j = 0; j < 8; ++j) { float d = o[j] - mu; var += d * d; }
  #pragma unroll
  for (int off = 16; off; off >>= 1) var += __shfl_xor(var, off);
  float r = rsqrtf(var * (1.f / 256.f) + 1e-5f);
  float4 g0 = *(const float4*)&g[l5 * 8];
  float4 g1 = *(const float4*)&g[l5 * 8 + 4];
  float4 e0 = *(const float4*)&be[l5 * 8];
  float4 e1 = *(const float4*)&be[l5 * 8 + 4];
  float gg[8] = {g0.x, g0.y, g0.z, g0.w, g1.x, g1.y, g1.z, g1.w};
  float ee[8] = {e0.x, e0.y, e0.z, e0.w, e1.x, e1.y, e1.z, e1.w};
  if (hl == 0) {
    half8v yv;
    #pragma unroll
    for (int j = 0; j < 8; ++j) {
      float t = (o[j] - mu) * r * gg[j] + ee[j];
      t = (t > 0.f) ? t : expm1f(t);
      yv[j] = (_Float16)t;
    }
    *(half8v*)&out[(size_t)node * 256 + l5 * 8] = yv;
  }
}

// ---------------- fused score + aggregation + LayerNorm + ELU, H=1 ----------
// 2 nodes per 128-thr block; quarter-wave per row; 4 edges in flight.
__global__ __launch_bounds__(128) void agg1_ln_kernel(const _Float16* __restrict__ h16,
                                                      const float* __restrict__ asrc,
                                                      const float* __restrict__ adst,
                                                      const int* __restrict__ offsets,
                                                      const int* __restrict__ src_csr,
                                                      const float* __restrict__ bias,
                                                      const float* __restrict__ g,
                                                      const float* __restrict__ be,
                                                      float* __restrict__ out, int n) {
  int wid = threadIdx.x >> 6, lane = threadIdx.x & 63;
  int node = blockIdx.x * 2 + wid;
  if (node >= n) return;
  int start = offsets[node], end = offsets[node + 1];
  int qi = lane >> 4;            // quarter index (edge offset)
  int ql = lane & 15;            // channels ql*4 .. ql*4+3
  float adh = adst[node];
  const uint2* h2 = (const uint2*)h16;
  const half2v ones = {(_Float16)1.f, (_Float16)1.f};
  float acc[4] = {0.f, 0.f, 0.f, 0.f};
  float denom = 0.f;
  int i = start + qi;
  for (; i + 12 < end; i += 16) {  // 4 edges (i, i+4, i+8, i+12)
    int s0 = src_csr[i], s1 = src_csr[i + 4], s2 = src_csr[i + 8], s3 = src_csr[i + 12];
    uint2 x0 = h2[(size_t)s0 * 16 + ql];
    uint2 x1 = h2[(size_t)s1 * 16 + ql];
    uint2 x2 = h2[(size_t)s2 * 16 + ql];
    uint2 x3 = h2[(size_t)s3 * 16 + ql];
    float sc0 = asrc[s0] + adh;
    float sc1 = asrc[s1] + adh;
    float sc2 = asrc[s2] + adh;
    float sc3 = asrc[s3] + adh;
    sc0 = (sc0 >= 0.f) ? sc0 : 0.2f * sc0;
    sc1 = (sc1 >= 0.f) ? sc1 : 0.2f * sc1;
    sc2 = (sc2 >= 0.f) ? sc2 : 0.2f * sc2;
    sc3 = (sc3 >= 0.f) ? sc3 : 0.2f * sc3;
    half2v wa = pack_rtz(__expf(sc0), __expf(sc1));
    half2v wb = pack_rtz(__expf(sc2), __expf(sc3));
    denom = __builtin_amdgcn_fdot2(wa, ones, denom, false);
    denom = __builtin_amdgcn_fdot2(wb, ones, denom, false);
    acc[0] = dot2(wa, x1.x, x0.x, 0x05040100u, acc[0]);
    acc[1] = dot2(wa, x1.x, x0.x, 0x07060302u, acc[1]);
    acc[2] = dot2(wa, x1.y, x0.y, 0x05040100u, acc[2]);
    acc[3] = dot2(wa, x1.y, x0.y, 0x07060302u, acc[3]);
    acc[0] = dot2(wb, x3.x, x2.x, 0x05040100u, acc[0]);
    acc[1] = dot2(wb, x3.x, x2.x, 0x07060302u, acc[1]);
    acc[2] = dot2(wb, x3.y, x2.y, 0x05040100u, acc[2]);
    acc[3] = dot2(wb, x3.y, x2.y, 0x07060302u, acc[3]);
  }
  for (; i + 4 < end; i += 8) {    // 2 edges
    int s0 = src_csr[i], s1 = src_csr[i + 4];
    uint2 x0 = h2[(size_t)s0 * 16 + ql];
    uint2 x1 = h2[(size_t)s1 * 16 + ql];
    float sc0 = asrc[s0] + adh;
    float sc1 = asrc[s1] + adh;
    sc0 = (sc0 >= 0.f) ? sc0 : 0.2f * sc0;
    sc1 = (sc1 >= 0.f) ? sc1 : 0.2f * sc1;
    half2v wa = pack_rtz(__expf(sc0), __expf(sc1));
    denom = __builtin_amdgcn_fdot2(wa, ones, denom, false);
    acc[0] = dot2(wa, x1.x, x0.x, 0x05040100u, acc[0]);
    acc[1] = dot2(wa, x1.x, x0.x, 0x07060302u, acc[1]);
    acc[2] = dot2(wa, x1.y, x0.y, 0x05040100u, acc[2]);
    acc[3] = dot2(wa, x1.y, x0.y, 0x07060302u, acc[3]);
  }
  if (i < end) {
    int s0 = src_csr[i];
    uint2 x0 = h2[(size_t)s0 * 16 + ql];
    float sc0 = asrc[s0] + adh;
    sc0 = (sc0 >= 0.f) ? sc0 : 0.2f * sc0;
    half2v wa = pack_rtz(__expf(sc0), 0.f);
    denom = __builtin_amdgcn_fdot2(wa, ones, denom, false);
    acc[0] = dot2(wa, x0.x, x0.x, 0x05040100u, acc[0]);
    acc[1] = dot2(wa, x0.x, x0.x, 0x07060302u, acc[1]);
    acc[2] = dot2(wa, x0.y, x0.y, 0x05040100u, acc[2]);
    acc[3] = dot2(wa, x0.y, x0.y, 0x07060302u, acc[3]);
  }
  #pragma unroll
  for (int off = 32; off >= 16; off >>= 1) {
    #pragma unroll
    for (int j = 0; j < 4; ++j) acc[j] += __shfl_xor(acc[j], off);
    denom += __shfl_xor(denom, off);
  }
  float inv = 1.f / denom;
  float4 b4 = *(const float4*)&bias[ql * 4];
  float o[4];
  o[0] = acc[0] * inv + b4.x; o[1] = acc[1] * inv + b4.y;
  o[2] = acc[2] * inv + b4.z; o[3] = acc[3] * inv + b4.w;
  float s = o[0] + o[1] + o[2] + o[3];
  #pragma unroll
  for (int off = 8; off; off >>= 1) s += __shfl_xor(s, off);
  float mu = s * (1.f / 64.f);
  float var = 0.f;
  #pragma unroll
  for (int j = 0; j < 4; ++j) { float d = o[j] - mu; var += d * d; }
  #pragma unroll
  for (int off = 8; off; off >>= 1) var += __shfl_xor(var, off);
  float r = rsqrtf(var * (1.f / 64.f) + 1e-5f);
  float4 g4 = *(const float4*)&g[ql * 4];
  float4 e4 = *(const float4*)&be[ql * 4];
  float gg[4] = {g4.x, g4.y, g4.z, g4.w};
  float ee[4] = {e4.x, e4.y, e4.z, e4.w};
  float y[4];
  #pragma unroll
  for (int j = 0; j < 4; ++j) {
    float t = (o[j] - mu) * r * gg[j] + ee[j];
    y[j] = (t > 0.f) ? t : expm1f(t);
  }
  if (qi == 0) {
    *(float4*)&out[(size_t)node * 64 + ql * 4] = make_float4(y[0], y[1], y[2], y[3]);
  }
}

// ---------------- fused pool + MLP head (batch is sorted) ----------------
__global__ __launch_bounds__(256) void graph_head_kernel(const float* __restrict__ h,
                                                         const int* __restrict__ batch, int N,
                                                         const float* __restrict__ Wg,
                                                         const float* __restrict__ bg,
                                                         const float* __restrict__ Wg2,
                                                         const float* __restrict__ bg2,
                                                         const float* __restrict__ Wo,
                                                         const float* __restrict__ bo,
                                                         float* __restrict__ out) {
  __shared__ int bounds[2];
  __shared__ float part[4][64];
  __shared__ float gm[64];
  __shared__ float z1[128];
  __shared__ float z2[64];
  int g = blockIdx.x;
  int tid = threadIdx.x;
  if (tid < 2) {
    int target = g + tid;  // lower_bound(batch, target)
    int lo = 0, hi = N;
    while (lo < hi) {
      int mid = (lo + hi) >> 1;
      if (batch[mid] < target) lo = mid + 1; else hi = mid;
    }
    bounds[tid] = lo;
  }
  __syncthreads();
  int lo = bounds[0], hi = bounds[1];
  int c = tid & 63, sub = tid >> 6;
  float acc = 0.f;
  for (int r = lo + sub; r < hi; r += 4) acc += h[(size_t)r * 64 + c];
  part[sub][c] = acc;
  __syncthreads();
  float invc = 1.f / fmaxf((float)(hi - lo), 1.f);
  if (tid < 64) gm[tid] = (part[0][tid] + part[1][tid] + part[2][tid] + part[3][tid]) * invc;
  __syncthreads();
  if (tid < 128) {
    float a = bg[tid];
    for (int k = 0; k < 64; ++k) a += gm[k] * Wg[k * 128 + tid];
    z1[tid] = fmaxf(a, 0.f);
  }
  __syncthreads();
  if (tid < 64) {
    float a = bg2[tid];
    for (int k = 0; k < 128; ++k) a += z1[k] * Wg2[k * 64 + tid];
    z2[tid] = fmaxf(a, 0.f);
  }
  __syncthreads();
  if (tid < 5) {
    float a = bo[tid];
    for (int k = 0; k < 64; ++k) a += z2[k] * Wo[k * 5 + tid];
    out[g * 5 + tid] = a;
  }
}

// ---------------- launch ----------------
extern "C" void kernel_launch(void* const* d_in, const int* in_sizes, int n_in,
                              void* d_out, int out_size, void* d_ws, size_t ws_size,
                              hipStream_t stream) {
  const float* x   = (const float*)d_in[0];
  const int* ei    = (const int*)d_in[1];
  const int* batch = (const int*)d_in[2];
  const float* W1  = (const float*)d_in[3];
  const float* a1s = (const float*)d_in[4];
  const float* a1d = (const float*)d_in[5];
  const float* b1  = (const float*)d_in[6];
  const float* g1  = (const float*)d_in[7];
  const float* be1 = (const float*)d_in[8];
  const float* W2  = (const float*)d_in[9];
  const float* a2s = (const float*)d_in[10];
  const float* a2d = (const float*)d_in[11];
  const float* b2  = (const float*)d_in[12];
  const float* g2  = (const float*)d_in[13];
  const float* be2 = (const float*)d_in[14];
  const float* W3  = (const float*)d_in[15];
  const float* a3s = (const float*)d_in[16];
  const float* a3d = (const float*)d_in[17];
  const float* b3  = (const float*)d_in[18];
  const float* g3  = (const float*)d_in[19];
  const float* be3 = (const float*)d_in[20];
  const float* Wg  = (const float*)d_in[21];
  const float* bg  = (const float*)d_in[22];
  const float* Wg2 = (const float*)d_in[23];
  const float* bg2 = (const float*)d_in[24];
  const float* Wo  = (const float*)d_in[25];
  const float* bo  = (const float*)d_in[26];

  const int N = in_sizes[2];
  const int E = in_sizes[1] / 2;
  const int ET = E + N;  // with self-loops
  const int G = 64;
  const int NB = (N + 1023) / 1024;

  // workspace carve-up (256B aligned)
  char* ws = (char*)d_ws;
  size_t off = 0;
  auto carve = [&](size_t bytes) {
    void* p = ws + off;
    off = (off + bytes + 255) & ~(size_t)255;
    return p;
  };
  int* counts    = (int*)carve((size_t)N * 4);
  int* offsets   = (int*)carve((size_t)(N + 1) * 4);
  int* cursor    = (int*)carve((size_t)N * 4);
  int* blocksums = (int*)carve((size_t)NB * 4);
  int* src_csr   = (int*)carve((size_t)ET * 4);
  float* asrc    = (float*)carve((size_t)N * 4 * 4);
  float* adst    = (float*)carve((size_t)N * 4 * 4);
  _Float16* x16  = (_Float16*)carve((size_t)N * 128 * 2);
  _Float16* a16  = (_Float16*)carve((size_t)N * 256 * 2);
  _Float16* h16  = (_Float16*)carve((size_t)N * 256 * 2);
  float* buf3    = (float*)carve((size_t)N * 64 * 4);
  _Float16* Wt1  = (_Float16*)carve((size_t)128 * 256 * 2);
  _Float16* Wt2  = (_Float16*)carve((size_t)256 * 256 * 2);
  _Float16* Wt3  = (_Float16*)carve((size_t)256 * 64 * 2);
  (void)ws_size;

  const int egrid = (ET + 255) / 256;
  const int ngrid2 = (N + 1) / 2;
  const int mblocks = (N + 127) / 128;
  const int ncvt = (N * 16 + 255) / 256;

  // --- fused pre-pass (W transposes + x16) ---
  prep_kernel<<<576 + ncvt, 256, 0, stream>>>(W1, W2, W3, x, Wt1, Wt2, Wt3, x16, N * 16);

  // --- CSR (dst-sorted src list), rebuilt every call ---
  hipMemsetAsync(counts, 0, (size_t)N * 4, stream);
  count_kernel<<<egrid, 256, 0, stream>>>(ei, E, N, counts);
  scan1_kernel<<<NB, 1024, 0, stream>>>(counts, offsets, blocksums, N);
  scan2_kernel<<<1, 1024, 0, stream>>>(blocksums, offsets, NB, N);
  scan3_kernel<<<(N + 255) / 256, 256, 0, stream>>>(offsets, cursor, blocksums, N);
  scatter_kernel<<<egrid, 256, 0, stream>>>(ei, E, N, cursor, src_csr);

  // --- layer 1 ---
  gemm16_kernel<16, 4><<<mblocks, 256, 0, stream>>>(x16, Wt1, a1s, a1d, h16, asrc, adst, N, 128);
  agg4_ln_kernel<<<ngrid2, 128, 0, stream>>>(h16, asrc, adst, offsets, src_csr, b1, g1, be1, a16, N);

  // --- layer 2 ---
  gemm16_kernel<16, 4><<<mblocks, 256, 0, stream>>>(a16, Wt2, a2s, a2d, h16, asrc, adst, N, 256);
  agg4_ln_kernel<<<ngrid2, 128, 0, stream>>>(h16, asrc, adst, offsets, src_csr, b2, g2, be2, a16, N);

  // --- layer 3 (H=1, C=64) ---
  gemm16_kernel<4, 1><<<mblocks, 256, 0, stream>>>(a16, Wt3, a3s, a3d, h16, asrc, adst, N, 256);
  agg1_ln_kernel<<<ngrid2, 128, 0, stream>>>(h16, asrc, adst, offsets, src_csr, b3, g3, be3, buf3, N);

  // --- fused pool + MLP head ---
  graph_head_kernel<<<G, 256, 0, stream>>>(buf3, batch, N, Wg, bg, Wg2, bg2, Wo, bo,
                                           (float*)d_out);
}

// Round 11
// 347.624 us; speedup vs baseline: 7.5940x; 1.1505x over previous
//
#include <hip/hip_runtime.h>
#include <math.h>

typedef _Float16 half2v __attribute__((ext_vector_type(2)));
typedef _Float16 half4v __attribute__((ext_vector_type(4)));
typedef _Float16 half8v __attribute__((ext_vector_type(8)));
typedef float floatx4 __attribute__((ext_vector_type(4)));

static __device__ __forceinline__ half2v pack_rtz(float a, float b) {
  return __builtin_bit_cast(half2v, __builtin_amdgcn_cvt_pkrtz(a, b));
}
static __device__ __forceinline__ float dot2(half2v w, unsigned hi, unsigned lo, unsigned sel, float acc) {
  return __builtin_amdgcn_fdot2(w, __builtin_bit_cast(half2v, __builtin_amdgcn_perm(hi, lo, sel)), acc, false);
}

// ------- fused pre-pass: W transposes + x conversion + edge count -------
__global__ __launch_bounds__(256) void prep_kernel(const float* __restrict__ W1,
                                                   const float* __restrict__ W2,
                                                   const float* __restrict__ W3,
                                                   const float* __restrict__ x,
                                                   _Float16* __restrict__ Wt1,
                                                   _Float16* __restrict__ Wt2,
                                                   _Float16* __restrict__ Wt3,
                                                   _Float16* __restrict__ x16, int n8,
                                                   const int* __restrict__ ei, int E, int N,
                                                   int* __restrict__ counts, int ncvt) {
  int b = blockIdx.x;
  int t = threadIdx.x;
  if (b < 256) {                       // Wt1 [256][128] <- W1 [128][256]
    if (t < 128) Wt1[(size_t)b * 128 + t] = (_Float16)W1[(size_t)t * 256 + b];
  } else if (b < 512) {                // Wt2 [256][256] <- W2 [256][256]
    int col = b - 256;
    Wt2[(size_t)col * 256 + t] = (_Float16)W2[(size_t)t * 256 + col];
  } else if (b < 576) {                // Wt3 [64][256] <- W3 [256][64]
    int col = b - 512;
    Wt3[(size_t)col * 256 + t] = (_Float16)W3[(size_t)t * 64 + col];
  } else if (b < 576 + ncvt) {         // x -> x16 (8 elems/thread)
    int i = (b - 576) * 256 + t;
    if (i < n8) {
      float4 a = ((const float4*)x)[2 * i];
      float4 c = ((const float4*)x)[2 * i + 1];
      half8v h = {(_Float16)a.x, (_Float16)a.y, (_Float16)a.z, (_Float16)a.w,
                  (_Float16)c.x, (_Float16)c.y, (_Float16)c.z, (_Float16)c.w};
      ((half8v*)x16)[i] = h;
    }
  } else {                             // edge degree count
    int e = (b - 576 - ncvt) * 256 + t;
    if (e < E + N) {
      int d = (e < E) ? ei[E + e] : (e - E);
      atomicAdd(&counts[d], 1);
    }
  }
}

// ---------------- CSR build ----------------
__global__ __launch_bounds__(1024) void scan1_kernel(const int* __restrict__ counts,
                                                     int* __restrict__ offsets,
                                                     int* __restrict__ blocksums, int n) {
  __shared__ int wsum[16];
  int tid = threadIdx.x, lane = tid & 63, wid = tid >> 6;
  int i = blockIdx.x * 1024 + tid;
  int v = (i < n) ? counts[i] : 0;
  int x = v;
  #pragma unroll
  for (int off = 1; off < 64; off <<= 1) {
    int t = __shfl_up(x, off);
    if (lane >= off) x += t;
  }
  if (lane == 63) wsum[wid] = x;
  __syncthreads();
  if (wid == 0) {
    int w = (lane < 16) ? wsum[lane] : 0;
    #pragma unroll
    for (int off = 1; off < 16; off <<= 1) {
      int t = __shfl_up(w, off);
      if (lane >= off) w += t;
    }
    if (lane < 16) wsum[lane] = w;
  }
  __syncthreads();
  int wpre = (wid > 0) ? wsum[wid - 1] : 0;
  if (i < n) offsets[i] = wpre + x - v;
  if (tid == 0) blocksums[blockIdx.x] = wsum[15];
}

__global__ __launch_bounds__(1024) void scan2_kernel(int* __restrict__ blocksums,
                                                     int* __restrict__ offsets, int nb, int n) {
  __shared__ int wsum[16];
  int tid = threadIdx.x, lane = tid & 63, wid = tid >> 6;
  int v = (tid < nb) ? blocksums[tid] : 0;
  int x = v;
  #pragma unroll
  for (int off = 1; off < 64; off <<= 1) {
    int t = __shfl_up(x, off);
    if (lane >= off) x += t;
  }
  if (lane == 63) wsum[wid] = x;
  __syncthreads();
  if (wid == 0) {
    int w = (lane < 16) ? wsum[lane] : 0;
    #pragma unroll
    for (int off = 1; off < 16; off <<= 1) {
      int t = __shfl_up(w, off);
      if (lane >= off) w += t;
    }
    if (lane < 16) wsum[lane] = w;
  }
  __syncthreads();
  int wpre = (wid > 0) ? wsum[wid - 1] : 0;
  if (tid < nb) blocksums[tid] = wpre + x - v;
  if (tid == 0) offsets[n] = wsum[15];
}

__global__ void scan3_kernel(int* __restrict__ offsets, int* __restrict__ cursor,
                             const int* __restrict__ blocksums, int n) {
  int i = blockIdx.x * 256 + threadIdx.x;
  if (i < n) {
    int o = offsets[i] + blocksums[i >> 10];
    offsets[i] = o;
    cursor[i] = o;
  }
}

__global__ void scatter_kernel(const int* __restrict__ ei, int E, int N,
                               int* __restrict__ cursor, int* __restrict__ src_csr) {
  int e = blockIdx.x * 256 + threadIdx.x;
  if (e >= E + N) return;
  int s = (e < E) ? ei[e] : (e - E);
  int d = (e < E) ? ei[E + e] : (e - E);
  int pos = atomicAdd(&cursor[d], 1);
  src_csr[pos] = s;
}

// ---------------- all-f16 MFMA GEMM + fused alpha epilogue ----------------
// Operand-swapped: A-operand = weight cols, B-operand = node rows.
// D mapping: node = lane&15 (per B-frag), wcol = ct*16 + (lane>>4)*4 + reg.
// => per-thread output cols are CONTIGUOUS (half4 stores, 4x fewer than before).
template <int NT, int H>   // Nc = NT*16
__global__ __launch_bounds__(256) void gemm16_kernel(const _Float16* __restrict__ A,
                                                     const _Float16* __restrict__ Wt,
                                                     const float* __restrict__ als,
                                                     const float* __restrict__ ald,
                                                     _Float16* __restrict__ out16,
                                                     float* __restrict__ asrc,
                                                     float* __restrict__ adst,
                                                     int M, int K) {
  constexpr int Nc = NT * 16;
  constexpr int BM = 128, BK = 32;
  constexpr int CPH = NT / H;
  __shared__ _Float16 As[BM][40];
  __shared__ _Float16 Ws[Nc][40];
  int bm = blockIdx.x * BM;
  int tid = threadIdx.x;
  int w = tid >> 6, l = tid & 63;
  int lr = l & 15, lg = l >> 4;

  floatx4 acc[2][NT];   // [node-frag nf][weight-col tile ct]
  #pragma unroll
  for (int nf = 0; nf < 2; ++nf)
    #pragma unroll
    for (int ct = 0; ct < NT; ++ct) acc[nf][ct] = (floatx4){0.f, 0.f, 0.f, 0.f};

  for (int k0 = 0; k0 < K; k0 += BK) {
    #pragma unroll
    for (int i = 0; i < 2; ++i) {
      int idx = tid + i * 256;
      int r = idx >> 2, c8 = idx & 3;
      int gr = bm + r;
      half8v hv = {(_Float16)0, (_Float16)0, (_Float16)0, (_Float16)0,
                   (_Float16)0, (_Float16)0, (_Float16)0, (_Float16)0};
      if (gr < M) hv = *(const half8v*)&A[(size_t)gr * K + k0 + c8 * 8];
      *(half8v*)&As[r][c8 * 8] = hv;
    }
    #pragma unroll
    for (int i = 0; i < NT / 4; ++i) {
      int idx = tid + i * 256;
      int col = idx >> 2, c8 = idx & 3;
      *(half8v*)&Ws[col][c8 * 8] = *(const half8v*)&Wt[(size_t)col * K + k0 + c8 * 8];
    }
    __syncthreads();
    half8v b0 = *(half8v*)&As[w * 32 + lr][lg * 8];        // nodes w*32+0..15
    half8v b1 = *(half8v*)&As[w * 32 + 16 + lr][lg * 8];   // nodes w*32+16..31
    #pragma unroll
    for (int ct = 0; ct < NT; ++ct) {
      half8v a = *(half8v*)&Ws[ct * 16 + lr][lg * 8];      // weight cols
      acc[0][ct] = __builtin_amdgcn_mfma_f32_16x16x32_f16(a, b0, acc[0][ct], 0, 0, 0);
      acc[1][ct] = __builtin_amdgcn_mfma_f32_16x16x32_f16(a, b1, acc[1][ct], 0, 0, 0);
    }
    __syncthreads();
  }
  // attention vectors for this thread's col slots: ct*16 + lg*4 + q
  float4 als4[NT], ald4[NT];
  #pragma unroll
  for (int ct = 0; ct < NT; ++ct) {
    als4[ct] = *(const float4*)&als[ct * 16 + lg * 4];
    ald4[ct] = *(const float4*)&ald[ct * 16 + lg * 4];
  }
  #pragma unroll
  for (int nf = 0; nf < 2; ++nf) {
    int node = bm + w * 32 + nf * 16 + lr;
    float ps[H], pd[H];
    #pragma unroll
    for (int hh = 0; hh < H; ++hh) {
      float s = 0.f, d = 0.f;
      #pragma unroll
      for (int c2 = 0; c2 < CPH; ++c2) {
        int ct = hh * CPH + c2;
        s += acc[nf][ct][0] * als4[ct].x + acc[nf][ct][1] * als4[ct].y +
             acc[nf][ct][2] * als4[ct].z + acc[nf][ct][3] * als4[ct].w;
        d += acc[nf][ct][0] * ald4[ct].x + acc[nf][ct][1] * ald4[ct].y +
             acc[nf][ct][2] * ald4[ct].z + acc[nf][ct][3] * ald4[ct].w;
      }
      ps[hh] = s; pd[hh] = d;
    }
    #pragma unroll
    for (int hh = 0; hh < H; ++hh) {    // reduce over lg group {lr, lr+16, lr+32, lr+48}
      ps[hh] += __shfl_xor(ps[hh], 16); ps[hh] += __shfl_xor(ps[hh], 32);
      pd[hh] += __shfl_xor(pd[hh], 16); pd[hh] += __shfl_xor(pd[hh], 32);
    }
    if (node < M) {
      if (lg == 0) {
        #pragma unroll
        for (int hh = 0; hh < H; ++hh) asrc[node * H + hh] = ps[hh];
      } else if (lg == 1) {
        #pragma unroll
        for (int hh = 0; hh < H; ++hh) adst[node * H + hh] = pd[hh];
      }
      #pragma unroll
      for (int ct = 0; ct < NT; ++ct) {
        half4v hv = {(_Float16)acc[nf][ct][0], (_Float16)acc[nf][ct][1],
                     (_Float16)acc[nf][ct][2], (_Float16)acc[nf][ct][3]};
        *(half4v*)&out16[(size_t)node * Nc + ct * 16 + lg * 4] = hv;
      }
    }
  }
}

// ---------------- fused score + aggregation + LayerNorm + ELU, H=4 ----------
__global__ __launch_bounds__(128) void agg4_ln_kernel(const _Float16* __restrict__ h16,
                                                      const float* __restrict__ asrc,
                                                      const float* __restrict__ adst,
                                                      const int* __restrict__ offsets,
                                                      const int* __restrict__ src_csr,
                                                      const float* __restrict__ bias,
                                                      const float* __restrict__ g,
                                                      const float* __restrict__ be,
                                                      _Float16* __restrict__ out, int n) {
  int wid = threadIdx.x >> 6, lane = threadIdx.x & 63;
  int node = blockIdx.x * 2 + wid;
  if (node >= n) return;
  int start = offsets[node], end = offsets[node + 1];
  int hl = lane >> 5;
  int l5 = lane & 31;
  int head = l5 >> 3;
  float adh = adst[node * 4 + head];
  const uint4* h4 = (const uint4*)h16;
  const half2v ones = {(_Float16)1.f, (_Float16)1.f};
  float acc[8] = {0.f, 0.f, 0.f, 0.f, 0.f, 0.f, 0.f, 0.f};
  float denom = 0.f;
  int i = start + hl;
  for (; i + 6 < end; i += 8) {
    int s0 = src_csr[i], s1 = src_csr[i + 2], s2 = src_csr[i + 4], s3 = src_csr[i + 6];
    uint4 x0 = h4[(size_t)s0 * 32 + l5];
    uint4 x1 = h4[(size_t)s1 * 32 + l5];
    uint4 x2 = h4[(size_t)s2 * 32 + l5];
    uint4 x3 = h4[(size_t)s3 * 32 + l5];
    float sc0 = asrc[s0 * 4 + head] + adh;
    float sc1 = asrc[s1 * 4 + head] + adh;
    float sc2 = asrc[s2 * 4 + head] + adh;
    float sc3 = asrc[s3 * 4 + head] + adh;
    sc0 = fmaxf(sc0, 0.2f * sc0);
    sc1 = fmaxf(sc1, 0.2f * sc1);
    sc2 = fmaxf(sc2, 0.2f * sc2);
    sc3 = fmaxf(sc3, 0.2f * sc3);
    half2v wa = pack_rtz(__expf(sc0), __expf(sc1));
    half2v wb = pack_rtz(__expf(sc2), __expf(sc3));
    denom = __builtin_amdgcn_fdot2(wa, ones, denom, false);
    denom = __builtin_amdgcn_fdot2(wb, ones, denom, false);
    acc[0] = dot2(wa, x1.x, x0.x, 0x05040100u, acc[0]);
    acc[1] = dot2(wa, x1.x, x0.x, 0x07060302u, acc[1]);
    acc[2] = dot2(wa, x1.y, x0.y, 0x05040100u, acc[2]);
    acc[3] = dot2(wa, x1.y, x0.y, 0x07060302u, acc[3]);
    acc[4] = dot2(wa, x1.z, x0.z, 0x05040100u, acc[4]);
    acc[5] = dot2(wa, x1.z, x0.z, 0x07060302u, acc[5]);
    acc[6] = dot2(wa, x1.w, x0.w, 0x05040100u, acc[6]);
    acc[7] = dot2(wa, x1.w, x0.w, 0x07060302u, acc[7]);
    acc[0] = dot2(wb, x3.x, x2.x, 0x05040100u, acc[0]);
    acc[1] = dot2(wb, x3.x, x2.x, 0x07060302u, acc[1]);
    acc[2] = dot2(wb, x3.y, x2.y, 0x05040100u, acc[2]);
    acc[3] = dot2(wb, x3.y, x2.y, 0x07060302u, acc[3]);
    acc[4] = dot2(wb, x3.z, x2.z, 0x05040100u, acc[4]);
    acc[5] = dot2(wb, x3.z, x2.z, 0x07060302u, acc[5]);
    acc[6] = dot2(wb, x3.w, x2.w, 0x05040100u, acc[6]);
    acc[7] = dot2(wb, x3.w, x2.w, 0x07060302u, acc[7]);
  }
  for (; i + 2 < end; i += 4) {
    int s0 = src_csr[i], s1 = src_csr[i + 2];
    uint4 x0 = h4[(size_t)s0 * 32 + l5];
    uint4 x1 = h4[(size_t)s1 * 32 + l5];
    float sc0 = asrc[s0 * 4 + head] + adh;
    float sc1 = asrc[s1 * 4 + head] + adh;
    sc0 = fmaxf(sc0, 0.2f * sc0);
    sc1 = fmaxf(sc1, 0.2f * sc1);
    half2v wa = pack_rtz(__expf(sc0), __expf(sc1));
    denom = __builtin_amdgcn_fdot2(wa, ones, denom, false);
    acc[0] = dot2(wa, x1.x, x0.x, 0x05040100u, acc[0]);
    acc[1] = dot2(wa, x1.x, x0.x, 0x07060302u, acc[1]);
    acc[2] = dot2(wa, x1.y, x0.y, 0x05040100u, acc[2]);
    acc[3] = dot2(wa, x1.y, x0.y, 0x07060302u, acc[3]);
    acc[4] = dot2(wa, x1.z, x0.z, 0x05040100u, acc[4]);
    acc[5] = dot2(wa, x1.z, x0.z, 0x07060302u, acc[5]);
    acc[6] = dot2(wa, x1.w, x0.w, 0x05040100u, acc[6]);
    acc[7] = dot2(wa, x1.w, x0.w, 0x07060302u, acc[7]);
  }
  if (i < end) {
    int s0 = src_csr[i];
    uint4 x0 = h4[(size_t)s0 * 32 + l5];
    float sc0 = asrc[s0 * 4 + head] + adh;
    sc0 = fmaxf(sc0, 0.2f * sc0);
    half2v wa = pack_rtz(__expf(sc0), 0.f);
    denom = __builtin_amdgcn_fdot2(wa, ones, denom, false);
    acc[0] = dot2(wa, x0.x, x0.x, 0x05040100u, acc[0]);
    acc[1] = dot2(wa, x0.x, x0.x, 0x07060302u, acc[1]);
    acc[2] = dot2(wa, x0.y, x0.y, 0x05040100u, acc[2]);
    acc[3] = dot2(wa, x0.y, x0.y, 0x07060302u, acc[3]);
    acc[4] = dot2(wa, x0.z, x0.z, 0x05040100u, acc[4]);
    acc[5] = dot2(wa, x0.z, x0.z, 0x07060302u, acc[5]);
    acc[6] = dot2(wa, x0.w, x0.w, 0x05040100u, acc[6]);
    acc[7] = dot2(wa, x0.w, x0.w, 0x07060302u, acc[7]);
  }
  #pragma unroll
  for (int j = 0; j < 8; ++j) acc[j] += __shfl_xor(acc[j], 32);
  denom += __shfl_xor(denom, 32);
  float inv = 1.f / denom;
  float o[8];
  float4 b0 = *(const float4*)&bias[l5 * 8];
  float4 b1 = *(const float4*)&bias[l5 * 8 + 4];
  o[0] = acc[0] * inv + b0.x; o[1] = acc[1] * inv + b0.y;
  o[2] = acc[2] * inv + b0.z; o[3] = acc[3] * inv + b0.w;
  o[4] = acc[4] * inv + b1.x; o[5] = acc[5] * inv + b1.y;
  o[6] = acc[6] * inv + b1.z; o[7] = acc[7] * inv + b1.w;
  float s = 0.f;
  #pragma unroll
  for (int j = 0; j < 8; ++j) s += o[j];
  #pragma unroll
  for (int off = 16; off; off >>= 1) s += __shfl_xor(s, off);
  float mu = s * (1.f / 256.f);
  float var = 0.f;
  #pragma unroll
  for (int j = 0; j < 8; ++j) { float d = o[j] - mu; var += d * d; }
  #pragma unroll
  for (int off = 16; off; off >>= 1) var += __shfl_xor(var, off);
  float r = rsqrtf(var * (1.f / 256.f) + 1e-5f);
  float4 g0 = *(const float4*)&g[l5 * 8];
  float4 g1 = *(const float4*)&g[l5 * 8 + 4];
  float4 e0 = *(const float4*)&be[l5 * 8];
  float4 e1 = *(const float4*)&be[l5 * 8 + 4];
  float gg[8] = {g0.x, g0.y, g0.z, g0.w, g1.x, g1.y, g1.z, g1.w};
  float ee[8] = {e0.x, e0.y, e0.z, e0.w, e1.x, e1.y, e1.z, e1.w};
  if (hl == 0) {
    half8v yv;
    #pragma unroll
    for (int j = 0; j < 8; ++j) {
      float t = (o[j] - mu) * r * gg[j] + ee[j];
      t = (t > 0.f) ? t : expm1f(t);
      yv[j] = (_Float16)t;
    }
    *(half8v*)&out[(size_t)node * 256 + l5 * 8] = yv;
  }
}

// ---------------- fused score + aggregation + LayerNorm + ELU, H=1 ----------
__global__ __launch_bounds__(128) void agg1_ln_kernel(const _Float16* __restrict__ h16,
                                                      const float* __restrict__ asrc,
                                                      const float* __restrict__ adst,
                                                      const int* __restrict__ offsets,
                                                      const int* __restrict__ src_csr,
                                                      const float* __restrict__ bias,
                                                      const float* __restrict__ g,
                                                      const float* __restrict__ be,
                                                      float* __restrict__ out, int n) {
  int wid = threadIdx.x >> 6, lane = threadIdx.x & 63;
  int node = blockIdx.x * 2 + wid;
  if (node >= n) return;
  int start = offsets[node], end = offsets[node + 1];
  int qi = lane >> 4;
  int ql = lane & 15;
  float adh = adst[node];
  const uint2* h2 = (const uint2*)h16;
  const half2v ones = {(_Float16)1.f, (_Float16)1.f};
  float acc[4] = {0.f, 0.f, 0.f, 0.f};
  float denom = 0.f;
  int i = start + qi;
  for (; i + 12 < end; i += 16) {
    int s0 = src_csr[i], s1 = src_csr[i + 4], s2 = src_csr[i + 8], s3 = src_csr[i + 12];
    uint2 x0 = h2[(size_t)s0 * 16 + ql];
    uint2 x1 = h2[(size_t)s1 * 16 + ql];
    uint2 x2 = h2[(size_t)s2 * 16 + ql];
    uint2 x3 = h2[(size_t)s3 * 16 + ql];
    float sc0 = asrc[s0] + adh;
    float sc1 = asrc[s1] + adh;
    float sc2 = asrc[s2] + adh;
    float sc3 = asrc[s3] + adh;
    sc0 = fmaxf(sc0, 0.2f * sc0);
    sc1 = fmaxf(sc1, 0.2f * sc1);
    sc2 = fmaxf(sc2, 0.2f * sc2);
    sc3 = fmaxf(sc3, 0.2f * sc3);
    half2v wa = pack_rtz(__expf(sc0), __expf(sc1));
    half2v wb = pack_rtz(__expf(sc2), __expf(sc3));
    denom = __builtin_amdgcn_fdot2(wa, ones, denom, false);
    denom = __builtin_amdgcn_fdot2(wb, ones, denom, false);
    acc[0] = dot2(wa, x1.x, x0.x, 0x05040100u, acc[0]);
    acc[1] = dot2(wa, x1.x, x0.x, 0x07060302u, acc[1]);
    acc[2] = dot2(wa, x1.y, x0.y, 0x05040100u, acc[2]);
    acc[3] = dot2(wa, x1.y, x0.y, 0x07060302u, acc[3]);
    acc[0] = dot2(wb, x3.x, x2.x, 0x05040100u, acc[0]);
    acc[1] = dot2(wb, x3.x, x2.x, 0x07060302u, acc[1]);
    acc[2] = dot2(wb, x3.y, x2.y, 0x05040100u, acc[2]);
    acc[3] = dot2(wb, x3.y, x2.y, 0x07060302u, acc[3]);
  }
  for (; i + 4 < end; i += 8) {
    int s0 = src_csr[i], s1 = src_csr[i + 4];
    uint2 x0 = h2[(size_t)s0 * 16 + ql];
    uint2 x1 = h2[(size_t)s1 * 16 + ql];
    float sc0 = asrc[s0] + adh;
    float sc1 = asrc[s1] + adh;
    sc0 = fmaxf(sc0, 0.2f * sc0);
    sc1 = fmaxf(sc1, 0.2f * sc1);
    half2v wa = pack_rtz(__expf(sc0), __expf(sc1));
    denom = __builtin_amdgcn_fdot2(wa, ones, denom, false);
    acc[0] = dot2(wa, x1.x, x0.x, 0x05040100u, acc[0]);
    acc[1] = dot2(wa, x1.x, x0.x, 0x07060302u, acc[1]);
    acc[2] = dot2(wa, x1.y, x0.y, 0x05040100u, acc[2]);
    acc[3] = dot2(wa, x1.y, x0.y, 0x07060302u, acc[3]);
  }
  if (i < end) {
    int s0 = src_csr[i];
    uint2 x0 = h2[(size_t)s0 * 16 + ql];
    float sc0 = asrc[s0] + adh;
    sc0 = fmaxf(sc0, 0.2f * sc0);
    half2v wa = pack_rtz(__expf(sc0), 0.f);
    denom = __builtin_amdgcn_fdot2(wa, ones, denom, false);
    acc[0] = dot2(wa, x0.x, x0.x, 0x05040100u, acc[0]);
    acc[1] = dot2(wa, x0.x, x0.x, 0x07060302u, acc[1]);
    acc[2] = dot2(wa, x0.y, x0.y, 0x05040100u, acc[2]);
    acc[3] = dot2(wa, x0.y, x0.y, 0x07060302u, acc[3]);
  }
  #pragma unroll
  for (int off = 32; off >= 16; off >>= 1) {
    #pragma unroll
    for (int j = 0; j < 4; ++j) acc[j] += __shfl_xor(acc[j], off);
    denom += __shfl_xor(denom, off);
  }
  float inv = 1.f / denom;
  float4 b4 = *(const float4*)&bias[ql * 4];
  float o[4];
  o[0] = acc[0] * inv + b4.x; o[1] = acc[1] * inv + b4.y;
  o[2] = acc[2] * inv + b4.z; o[3] = acc[3] * inv + b4.w;
  float s = o[0] + o[1] + o[2] + o[3];
  #pragma unroll
  for (int off = 8; off; off >>= 1) s += __shfl_xor(s, off);
  float mu = s * (1.f / 64.f);
  float var = 0.f;
  #pragma unroll
  for (int j = 0; j < 4; ++j) { float d = o[j] - mu; var += d * d; }
  #pragma unroll
  for (int off = 8; off; off >>= 1) var += __shfl_xor(var, off);
  float r = rsqrtf(var * (1.f / 64.f) + 1e-5f);
  float4 g4 = *(const float4*)&g[ql * 4];
  float4 e4 = *(const float4*)&be[ql * 4];
  float gg[4] = {g4.x, g4.y, g4.z, g4.w};
  float ee[4] = {e4.x, e4.y, e4.z, e4.w};
  float y[4];
  #pragma unroll
  for (int j = 0; j < 4; ++j) {
    float t = (o[j] - mu) * r * gg[j] + ee[j];
    y[j] = (t > 0.f) ? t : expm1f(t);
  }
  if (qi == 0) {
    *(float4*)&out[(size_t)node * 64 + ql * 4] = make_float4(y[0], y[1], y[2], y[3]);
  }
}

// ---------------- fused pool + MLP head (batch sorted; 1024-thr pool) --------
__global__ __launch_bounds__(1024) void graph_head_kernel(const float* __restrict__ h,
                                                          const int* __restrict__ batch, int N,
                                                          const float* __restrict__ Wg,
                                                          const float* __restrict__ bg,
                                                          const float* __restrict__ Wg2,
                                                          const float* __restrict__ bg2,
                                                          const float* __restrict__ Wo,
                                                          const float* __restrict__ bo,
                                                          float* __restrict__ out) {
  __shared__ int bounds[2];
  __shared__ float part[64][16][4];   // [sub][cq][j] = 16 KB
  __shared__ float gm[64];
  __shared__ float z1[128];
  __shared__ float z2[64];
  int g = blockIdx.x;
  int tid = threadIdx.x;
  if (tid < 2) {
    int target = g + tid;
    int lo = 0, hi = N;
    while (lo < hi) {
      int mid = (lo + hi) >> 1;
      if (batch[mid] < target) lo = mid + 1; else hi = mid;
    }
    bounds[tid] = lo;
  }
  __syncthreads();
  int lo = bounds[0], hi = bounds[1];
  int sub = tid >> 4, cq = tid & 15;
  float4 acc = make_float4(0.f, 0.f, 0.f, 0.f);
  for (int r = lo + sub; r < hi; r += 64) {
    float4 v = *(const float4*)&h[(size_t)r * 64 + cq * 4];
    acc.x += v.x; acc.y += v.y; acc.z += v.z; acc.w += v.w;
  }
  part[sub][cq][0] = acc.x; part[sub][cq][1] = acc.y;
  part[sub][cq][2] = acc.z; part[sub][cq][3] = acc.w;
  __syncthreads();
  #pragma unroll
  for (int st = 32; st >= 1; st >>= 1) {
    if (sub < st) {
      #pragma unroll
      for (int j = 0; j < 4; ++j) part[sub][cq][j] += part[sub + st][cq][j];
    }
    __syncthreads();
  }
  if (tid < 16) {
    float invc = 1.f / fmaxf((float)(hi - lo), 1.f);
    #pragma unroll
    for (int j = 0; j < 4; ++j) gm[tid * 4 + j] = part[0][tid][j] * invc;
  }
  __syncthreads();
  if (tid < 128) {
    float a = bg[tid];
    for (int k = 0; k < 64; ++k) a += gm[k] * Wg[k * 128 + tid];
    z1[tid] = fmaxf(a, 0.f);
  }
  __syncthreads();
  if (tid < 64) {
    float a = bg2[tid];
    for (int k = 0; k < 128; ++k) a += z1[k] * Wg2[k * 64 + tid];
    z2[tid] = fmaxf(a, 0.f);
  }
  __syncthreads();
  if (tid < 5) {
    float a = bo[tid];
    for (int k = 0; k < 64; ++k) a += z2[k] * Wo[k * 5 + tid];
    out[g * 5 + tid] = a;
  }
}

// ---------------- launch ----------------
extern "C" void kernel_launch(void* const* d_in, const int* in_sizes, int n_in,
                              void* d_out, int out_size, void* d_ws, size_t ws_size,
                              hipStream_t stream) {
  const float* x   = (const float*)d_in[0];
  const int* ei    = (const int*)d_in[1];
  const int* batch = (const int*)d_in[2];
  const float* W1  = (const float*)d_in[3];
  const float* a1s = (const float*)d_in[4];
  const float* a1d = (const float*)d_in[5];
  const float* b1  = (const float*)d_in[6];
  const float* g1  = (const float*)d_in[7];
  const float* be1 = (const float*)d_in[8];
  const float* W2  = (const float*)d_in[9];
  const float* a2s = (const float*)d_in[10];
  const float* a2d = (const float*)d_in[11];
  const float* b2  = (const float*)d_in[12];
  const float* g2  = (const float*)d_in[13];
  const float* be2 = (const float*)d_in[14];
  const float* W3  = (const float*)d_in[15];
  const float* a3s = (const float*)d_in[16];
  const float* a3d = (const float*)d_in[17];
  const float* b3  = (const float*)d_in[18];
  const float* g3  = (const float*)d_in[19];
  const float* be3 = (const float*)d_in[20];
  const float* Wg  = (const float*)d_in[21];
  const float* bg  = (const float*)d_in[22];
  const float* Wg2 = (const float*)d_in[23];
  const float* bg2 = (const float*)d_in[24];
  const float* Wo  = (const float*)d_in[25];
  const float* bo  = (const float*)d_in[26];

  const int N = in_sizes[2];
  const int E = in_sizes[1] / 2;
  const int ET = E + N;  // with self-loops
  const int G = 64;
  const int NB = (N + 1023) / 1024;

  // workspace carve-up (256B aligned)
  char* ws = (char*)d_ws;
  size_t off = 0;
  auto carve = [&](size_t bytes) {
    void* p = ws + off;
    off = (off + bytes + 255) & ~(size_t)255;
    return p;
  };
  int* counts    = (int*)carve((size_t)N * 4);
  int* offsets   = (int*)carve((size_t)(N + 1) * 4);
  int* cursor    = (int*)carve((size_t)N * 4);
  int* blocksums = (int*)carve((size_t)NB * 4);
  int* src_csr   = (int*)carve((size_t)ET * 4);
  float* asrc    = (float*)carve((size_t)N * 4 * 4);
  float* adst    = (float*)carve((size_t)N * 4 * 4);
  _Float16* x16  = (_Float16*)carve((size_t)N * 128 * 2);
  _Float16* a16  = (_Float16*)carve((size_t)N * 256 * 2);
  _Float16* h16  = (_Float16*)carve((size_t)N * 256 * 2);
  float* buf3    = (float*)carve((size_t)N * 64 * 4);
  _Float16* Wt1  = (_Float16*)carve((size_t)128 * 256 * 2);
  _Float16* Wt2  = (_Float16*)carve((size_t)256 * 256 * 2);
  _Float16* Wt3  = (_Float16*)carve((size_t)256 * 64 * 2);
  (void)ws_size;

  const int egrid = (ET + 255) / 256;
  const int ngrid2 = (N + 1) / 2;
  const int mblocks = (N + 127) / 128;
  const int ncvt = (N * 16 + 255) / 256;

  // --- memset, then fused pre-pass (W transposes + x16 + edge count) ---
  hipMemsetAsync(counts, 0, (size_t)N * 4, stream);
  prep_kernel<<<576 + ncvt + egrid, 256, 0, stream>>>(W1, W2, W3, x, Wt1, Wt2, Wt3,
                                                      x16, N * 16, ei, E, N, counts, ncvt);

  // --- CSR (dst-sorted src list) ---
  scan1_kernel<<<NB, 1024, 0, stream>>>(counts, offsets, blocksums, N);
  scan2_kernel<<<1, 1024, 0, stream>>>(blocksums, offsets, NB, N);
  scan3_kernel<<<(N + 255) / 256, 256, 0, stream>>>(offsets, cursor, blocksums, N);
  scatter_kernel<<<egrid, 256, 0, stream>>>(ei, E, N, cursor, src_csr);

  // --- layer 1 ---
  gemm16_kernel<16, 4><<<mblocks, 256, 0, stream>>>(x16, Wt1, a1s, a1d, h16, asrc, adst, N, 128);
  agg4_ln_kernel<<<ngrid2, 128, 0, stream>>>(h16, asrc, adst, offsets, src_csr, b1, g1, be1, a16, N);

  // --- layer 2 ---
  gemm16_kernel<16, 4><<<mblocks, 256, 0, stream>>>(a16, Wt2, a2s, a2d, h16, asrc, adst, N, 256);
  agg4_ln_kernel<<<ngrid2, 128, 0, stream>>>(h16, asrc, adst, offsets, src_csr, b2, g2, be2, a16, N);

  // --- layer 3 (H=1, C=64) ---
  gemm16_kernel<4, 1><<<mblocks, 256, 0, stream>>>(a16, Wt3, a3s, a3d, h16, asrc, adst, N, 256);
  agg1_ln_kernel<<<ngrid2, 128, 0, stream>>>(h16, asrc, adst, offsets, src_csr, b3, g3, be3, buf3, N);

  // --- fused pool + MLP head ---
  graph_head_kernel<<<G, 1024, 0, stream>>>(buf3, batch, N, Wg, bg, Wg2, bg2, Wo, bo,
                                            (float*)d_out);
}